// Round 14
// baseline (2035.693 us; speedup 1.0000x reference)
//
#include <hip/hip_runtime.h>
#include <hip/hip_fp16.h>
#include <math.h>

namespace {

constexpr int NATOMS = 1000000;
constexpr int NBATCH = 32768;
constexpr int kCounts[11] = {10000,250000,300000,250000,120000,40000,15000,8000,4000,2000,1000};
constexpr int kStarts[11] = {0,10000,260000,560000,810000,930000,970000,985000,993000,997000,999000};
constexpr int X16S = 80;   // padded fp16 row stride for x (75 ch -> 80, 160B rows)

struct AdjPtrs { const int* p[10]; };

__device__ __forceinline__ unsigned enc_f32(float x) {
    unsigned u = __float_as_uint(x);
    return (u & 0x80000000u) ? ~u : (u | 0x80000000u);
}
__device__ __forceinline__ float dec_f32(unsigned u) {
    return (u & 0x80000000u) ? __uint_as_float(u & 0x7FFFFFFFu) : __uint_as_float(~u);
}

// dense_seg/fd0 64-wide fp32 tiles (row stride 64 -> bank=col&31):
__device__ __forceinline__ int swzS64d(int row, int k) { return row ^ (((k >> 2) & 7) << 2); }

// conv tiles [k][64] staged at half2 granularity (lane owns channels 2h,2h+1):
//  self: 16 lanes/row, 4 rows/wave: col = row ^ ((h&7)<<2)  -> 32 banks, 2-way
//  rel:   8 lanes/atom, 8 atoms/wave: col = ai ^ ((h&3)<<3) -> 32 banks, 2-way
// compute (per-lane, a=0..63): colS = a^(((k>>1)&7)<<2), colR = a^(((k>>1)&3)<<3)

// ---------------------------------------------------------------------------
// x fp32 [1M][75] -> x16 fp16 [1M][80] (zero-padded), one-time streaming pass.
// ---------------------------------------------------------------------------
__global__ __launch_bounds__(256) void cvt_kernel(const float* __restrict__ x,
                                                  __half* __restrict__ x16)
{
    const long long n = (long long)NATOMS * X16S;
    for (long long i = (long long)blockIdx.x * 256 + threadIdx.x; i < n;
         i += (long long)gridDim.x * 256) {
        const int row = (int)(i / X16S);
        const int c = (int)(i - (long long)row * X16S);
        const float v = (c < 75) ? x[(size_t)row * 75 + c] : 0.f;
        x16[i] = __float2half(v);
    }
}

// ---------------------------------------------------------------------------
// rel-staging bodies (8 lanes per atom; fp16 gathers, fp32 LDS)
// ---------------------------------------------------------------------------
template<int D>
__device__ __forceinline__ void stage_rel64_h(const __half* __restrict__ x16,
                                              const int* __restrict__ ad,
                                              int j0, int ai, int g8, float* __restrict__ s_rel)
{
    int idxs[D];
    #pragma unroll
    for (int n = 0; n < D; ++n) idxs[n] = ad[(size_t)(j0 + ai) * D + n];
    float2 r[4];
    #pragma unroll
    for (int q = 0; q < 4; ++q) r[q] = make_float2(0.f, 0.f);
    for (int n = 0; n < D; ++n) {
        const __half2* __restrict__ xr = reinterpret_cast<const __half2*>(x16 + (size_t)idxs[n] * 64);
        #pragma unroll
        for (int q = 0; q < 4; ++q) {
            const float2 v = __half22float2(xr[g8 + 8 * q]);
            r[q].x += v.x; r[q].y += v.y;
        }
    }
    const int col = ai ^ ((g8 & 3) << 3);
    #pragma unroll
    for (int q = 0; q < 4; ++q) {
        const int k0 = (g8 + 8 * q) * 2;
        s_rel[(k0 + 0) * 64 + col] = r[q].x;
        s_rel[(k0 + 1) * 64 + col] = r[q].y;
    }
}

__device__ __forceinline__ void stage_rel64_rt_h(const __half* __restrict__ x16,
                                                 const int* __restrict__ ad, int d,
                                                 int j0, int ai, int g8, float* __restrict__ s_rel)
{
    int idxs[10];
    for (int n = 0; n < d; ++n) idxs[n] = ad[(size_t)(j0 + ai) * d + n];
    float2 r[4];
    #pragma unroll
    for (int q = 0; q < 4; ++q) r[q] = make_float2(0.f, 0.f);
    for (int n = 0; n < d; ++n) {
        const __half2* __restrict__ xr = reinterpret_cast<const __half2*>(x16 + (size_t)idxs[n] * 64);
        #pragma unroll
        for (int q = 0; q < 4; ++q) {
            const float2 v = __half22float2(xr[g8 + 8 * q]);
            r[q].x += v.x; r[q].y += v.y;
        }
    }
    const int col = ai ^ ((g8 & 3) << 3);
    #pragma unroll
    for (int q = 0; q < 4; ++q) {
        const int k0 = (g8 + 8 * q) * 2;
        s_rel[(k0 + 0) * 64 + col] = r[q].x;
        s_rel[(k0 + 1) * 64 + col] = r[q].y;
    }
}

template<int D>
__device__ __forceinline__ void stage_rel75_h(const __half* __restrict__ x16,
                                              const int* __restrict__ ad,
                                              int j0, int ai, int g8, float* __restrict__ s_rel)
{
    int idxs[D];
    #pragma unroll
    for (int n = 0; n < D; ++n) idxs[n] = ad[(size_t)(j0 + ai) * D + n];
    float2 r[5];
    #pragma unroll
    for (int q = 0; q < 5; ++q) r[q] = make_float2(0.f, 0.f);
    for (int n = 0; n < D; ++n) {
        const __half2* __restrict__ xr = reinterpret_cast<const __half2*>(x16 + (size_t)idxs[n] * X16S);
        #pragma unroll
        for (int q = 0; q < 5; ++q) {
            const float2 v = __half22float2(xr[g8 + 8 * q]);
            r[q].x += v.x; r[q].y += v.y;
        }
    }
    const int col = ai ^ ((g8 & 3) << 3);
    #pragma unroll
    for (int q = 0; q < 5; ++q) {
        const int h = g8 + 8 * q;
        const int k0 = h * 2;
        if (k0 < 75)     s_rel[(k0 + 0) * 64 + col] = r[q].x;
        if (k0 + 1 < 75) s_rel[(k0 + 1) * 64 + col] = r[q].y;
    }
}

__device__ __forceinline__ void stage_rel75_rt_h(const __half* __restrict__ x16,
                                                 const int* __restrict__ ad, int d,
                                                 int j0, int ai, int g8, float* __restrict__ s_rel)
{
    int idxs[10];
    for (int n = 0; n < d; ++n) idxs[n] = ad[(size_t)(j0 + ai) * d + n];
    float2 r[5];
    #pragma unroll
    for (int q = 0; q < 5; ++q) r[q] = make_float2(0.f, 0.f);
    for (int n = 0; n < d; ++n) {
        const __half2* __restrict__ xr = reinterpret_cast<const __half2*>(x16 + (size_t)idxs[n] * X16S);
        #pragma unroll
        for (int q = 0; q < 5; ++q) {
            const float2 v = __half22float2(xr[g8 + 8 * q]);
            r[q].x += v.x; r[q].y += v.y;
        }
    }
    const int col = ai ^ ((g8 & 3) << 3);
    #pragma unroll
    for (int q = 0; q < 5; ++q) {
        const int k0 = (g8 + 8 * q) * 2;
        if (k0 < 75)     s_rel[(k0 + 0) * 64 + col] = r[q].x;
        if (k0 + 1 < 75) s_rel[(k0 + 1) * 64 + col] = r[q].y;
    }
}

// ---------------------------------------------------------------------------
// Merged conv layer: 64-atom tile, 512 threads, fp16 gathers (one 128B line
// per gathered row for CI=64; 160B rows for x16). Scalar weights (r10), fp32
// accumulate, fp16 output. Rounds 7-13 proved the gather path is saturated
// independent of occupancy/compute form -> halve its bytes & line-requests.
// ---------------------------------------------------------------------------
template<int CI>
__global__ __launch_bounds__(512) void conv_all_kernel(
    const __half* __restrict__ xin, AdjPtrs adj,
    const float* __restrict__ W, const float* __restrict__ B,
    const float* __restrict__ bng, const float* __restrict__ bnb,
    const float* __restrict__ bnm, const float* __restrict__ bnv,
    __half* __restrict__ out)
{
    constexpr int XS = (CI == 64) ? 64 : X16S;
    constexpr int SM = (2 * CI * 64 > 64 * 65) ? 2 * CI * 64 : 64 * 65;
    __shared__ __align__(16) float smem[SM];
    float* s_self = smem;            // [CI][64]
    float* s_rel  = smem + CI * 64;  // [CI][64]

    int d = 0, rem = blockIdx.x;
    for (;;) { const int nb = (kCounts[d] + 63) >> 6; if (rem < nb) break; rem -= nb; ++d; }
    const int j0 = rem << 6;
    const int nA = min(64, kCounts[d] - j0);
    const int a0 = kStarts[d] + j0;
    const int t = threadIdx.x;

    // ---- stage self rows (coalesced fp16, <=2-way LDS) ----
    {
        constexpr int NQ = (CI == 64) ? 2 : 3;
        for (int v = t; v < 1024; v += 512) {
            const int row = v >> 4, l16 = v & 15;
            if (row < nA) {
                const __half2* __restrict__ xr =
                    reinterpret_cast<const __half2*>(xin + (size_t)(a0 + row) * XS);
                #pragma unroll
                for (int q = 0; q < NQ; ++q) {
                    const int h = l16 + 16 * q;
                    if (h * 2 < CI) {
                        const float2 f = __half22float2(xr[h]);
                        const int col = row ^ ((h & 7) << 2);
                        s_self[(2 * h) * 64 + col] = f.x;
                        if (2 * h + 1 < CI) s_self[(2 * h + 1) * 64 + col] = f.y;
                    }
                }
            }
        }
    }

    // ---- stage neighbor sums (8 lanes/atom, full row, single-fetch) ----
    if (d > 0) {
        const int ai = t >> 3, g8 = t & 7;
        if (ai < nA) {
            const int* __restrict__ adp = adj.p[d - 1];
            if constexpr (CI == 64) {
                switch (d) {
                case 1: stage_rel64_h<1>(xin, adp, j0, ai, g8, s_rel); break;
                case 2: stage_rel64_h<2>(xin, adp, j0, ai, g8, s_rel); break;
                case 3: stage_rel64_h<3>(xin, adp, j0, ai, g8, s_rel); break;
                case 4: stage_rel64_h<4>(xin, adp, j0, ai, g8, s_rel); break;
                default: stage_rel64_rt_h(xin, adp, d, j0, ai, g8, s_rel); break;
                }
            } else {
                switch (d) {
                case 1: stage_rel75_h<1>(xin, adp, j0, ai, g8, s_rel); break;
                case 2: stage_rel75_h<2>(xin, adp, j0, ai, g8, s_rel); break;
                case 3: stage_rel75_h<3>(xin, adp, j0, ai, g8, s_rel); break;
                case 4: stage_rel75_h<4>(xin, adp, j0, ai, g8, s_rel); break;
                default: stage_rel75_rt_h(xin, adp, d, j0, ai, g8, s_rel); break;
                }
            }
        }
    }
    __syncthreads();

    // ---- compute: atom-per-lane, 8 channels/thread, scalar weights ----
    const int a  = t & 63;
    const int c0 = __builtin_amdgcn_readfirstlane(t >> 6) * 8;   // wave-uniform

    float acc[8];
    #pragma unroll
    for (int j = 0; j < 8; ++j) acc[j] = 0.f;

    if (d == 0) {
        const float* __restrict__ Ws = W + (size_t)(2 * 10) * CI * 64;
        #pragma unroll
        for (int k = 0; k < CI; ++k) {
            const float xs = s_self[k * 64 + (a ^ (((k >> 1) & 7) << 2))];
            #pragma unroll
            for (int j = 0; j < 8; ++j)
                acc[j] = fmaf(xs, Ws[k * 64 + c0 + j], acc[j]);
        }
    } else {
        const float* __restrict__ Wr = W + (size_t)(2 * (d - 1)) * CI * 64;
        const float* __restrict__ Ws = W + (size_t)(2 * d - 1) * CI * 64;
        #pragma unroll
        for (int k = 0; k < CI; ++k) {
            const float xs = s_self[k * 64 + (a ^ (((k >> 1) & 7) << 2))];
            const float xr = s_rel [k * 64 + (a ^ (((k >> 1) & 3) << 3))];
            #pragma unroll
            for (int j = 0; j < 8; ++j)
                acc[j] = fmaf(xs, Ws[k * 64 + c0 + j],
                              fmaf(xr, Wr[k * 64 + c0 + j], acc[j]));
        }
    }

    // ---- epilogue: scalar bias/BN, rotated-LDS transpose, fp16 store ----
    __syncthreads();
    float* vout = smem;       // [64][65]
    #pragma unroll
    for (int j = 0; j < 8; ++j) {
        const int c = c0 + j;                               // wave-uniform
        const float bias = (d == 0) ? B[20 * 64 + c]
                                    : (B[(2 * (d - 1)) * 64 + c] + B[(2 * d - 1) * 64 + c]);
        const float scl = rsqrtf(bnv[c] + 1e-3f) * bng[c];
        const float sht = bnb[c] - bnm[c] * scl;
        vout[a * 65 + c] = fmaf(fmaxf(acc[j] + bias, 0.f), scl, sht);
    }
    __syncthreads();
    const int cc = t & 63, g = t >> 6;
    #pragma unroll
    for (int i = 0; i < 8; ++i) {
        const int row = g * 8 + i;
        if (row < nA) out[(size_t)(a0 + row) * 64 + cc] = __float2half(vout[row * 65 + cc]);
    }
}

// ---------------------------------------------------------------------------
// Merged pool layer (fp16 in/out): gathered rows are one 128B line each.
// ---------------------------------------------------------------------------
template<int D>
__device__ __forceinline__ float pool_body(const __half* __restrict__ z,
                                           const int* __restrict__ ad, int j, int c, float v)
{
    int idxs[D];
    #pragma unroll
    for (int n = 0; n < D; ++n) idxs[n] = ad[(size_t)j * D + n];
    #pragma unroll
    for (int n = 0; n < D; ++n) v = fmaxf(v, __half2float(z[(size_t)idxs[n] * 64 + c]));
    return v;
}

__global__ __launch_bounds__(256) void pool_all_kernel(
    const __half* __restrict__ z, AdjPtrs adj, __half* __restrict__ p)
{
    int d = 0, rem = blockIdx.x;
    for (;;) { const int nb = (kCounts[d] + 3) >> 2; if (rem < nb) break; rem -= nb; ++d; }
    const int t = threadIdx.x;
    const int j = rem * 4 + (t >> 6);
    if (j >= kCounts[d]) return;
    const int c = t & 63;
    const int a = kStarts[d] + j;
    float v = __half2float(z[(size_t)a * 64 + c]);
    if (d > 0) {
        const int* __restrict__ ad = adj.p[d - 1];
        switch (d) {
        case 1:  v = pool_body<1 >(z, ad, j, c, v); break;
        case 2:  v = pool_body<2 >(z, ad, j, c, v); break;
        case 3:  v = pool_body<3 >(z, ad, j, c, v); break;
        case 4:  v = pool_body<4 >(z, ad, j, c, v); break;
        case 5:  v = pool_body<5 >(z, ad, j, c, v); break;
        case 6:  v = pool_body<6 >(z, ad, j, c, v); break;
        case 7:  v = pool_body<7 >(z, ad, j, c, v); break;
        case 8:  v = pool_body<8 >(z, ad, j, c, v); break;
        case 9:  v = pool_body<9 >(z, ad, j, c, v); break;
        default: v = pool_body<10>(z, ad, j, c, v); break;
        }
    }
    p[(size_t)a * 64 + c] = __float2half(v);
}

// ---------------------------------------------------------------------------
// Counting sort by membership: hist -> scan -> scatter (+ per-position seg id).
// ---------------------------------------------------------------------------
__global__ __launch_bounds__(256) void hist_kernel(const int* __restrict__ mem,
                                                   int* __restrict__ cnt)
{
    const int a = blockIdx.x * 256 + threadIdx.x;
    if (a < NATOMS) atomicAdd(&cnt[mem[a]], 1);
}

__global__ __launch_bounds__(512) void scan_kernel(const int* __restrict__ cnt,
                                                   int* __restrict__ off,
                                                   int* __restrict__ cur)
{
    __shared__ int part[512];
    const int t = threadIdx.x;
    const int base = t * 64;
    int s = 0;
    #pragma unroll 8
    for (int i = 0; i < 64; ++i) s += cnt[base + i];
    part[t] = s;
    __syncthreads();
    for (int o = 1; o < 512; o <<= 1) {
        int v = (t >= o) ? part[t - o] : 0;
        __syncthreads();
        part[t] += v;
        __syncthreads();
    }
    int run = (t == 0) ? 0 : part[t - 1];
    for (int i = 0; i < 64; ++i) {
        off[base + i] = run;
        cur[base + i] = run;
        run += cnt[base + i];
    }
}

__global__ __launch_bounds__(256) void scatter_kernel(const int* __restrict__ mem,
                                                      int* __restrict__ cur,
                                                      int* __restrict__ sorted,
                                                      int* __restrict__ sid)
{
    const int a = blockIdx.x * 256 + threadIdx.x;
    if (a < NATOMS) {
        const int m = mem[a];
        const int pos = atomicAdd(&cur[m], 1);
        sorted[pos] = a;
        sid[pos] = m;
    }
}

__global__ void seg_init_kernel(float* __restrict__ segS, unsigned* __restrict__ segM)
{
    const int n = NBATCH * 128;
    for (int i = blockIdx.x * blockDim.x + threadIdx.x; i < n; i += gridDim.x * blockDim.x) {
        segS[i] = 0.f;
        segM[i] = 0x007FFFFFu; // enc(-inf)
    }
}

// ---------------------------------------------------------------------------
// Dense 64->128 + ReLU + BN2 over SORTED atoms (fp16 input rows = 1 line),
// tiled GEMM + fused segmented sum/max epilogue.
// ---------------------------------------------------------------------------
__global__ __launch_bounds__(256) void dense_seg_sorted_kernel(
    const __half* __restrict__ p,
    const int* __restrict__ sorted, const int* __restrict__ sid,
    const float* __restrict__ Wd, const float* __restrict__ bd,
    const float* __restrict__ bng, const float* __restrict__ bnb,
    const float* __restrict__ bnm, const float* __restrict__ bnv,
    float* __restrict__ segS, unsigned* __restrict__ segM)
{
    __shared__ __align__(16) float s_p[64][64];   // staging; reused as v-buffer
    __shared__ int s_idx[64];
    __shared__ int s_sid[64];

    const int t = threadIdx.x;
    const int pos0 = blockIdx.x * 64;   // NATOMS = 15625 * 64 exactly

    if (t < 64) {
        s_idx[t] = sorted[pos0 + t];
        s_sid[t] = sid[pos0 + t];
    }
    __syncthreads();

    for (int v = t; v < 1024; v += 256) {
        const int row = v >> 4, k0 = (v & 15) * 4;
        const __half2* __restrict__ pr =
            reinterpret_cast<const __half2*>(p + (size_t)s_idx[row] * 64);
        const float2 fa = __half22float2(pr[(v & 15) * 2]);
        const float2 fb = __half22float2(pr[(v & 15) * 2 + 1]);
        const int col = swzS64d(row, k0);   // same col for k0..k0+3
        s_p[k0 + 0][col] = fa.x;
        s_p[k0 + 1][col] = fa.y;
        s_p[k0 + 2][col] = fb.x;
        s_p[k0 + 3][col] = fb.y;
    }
    __syncthreads();

    const int ccol = (t & 31) * 4;   // 4 consecutive output channels
    const int rgrp = t >> 5;         // 8 rows: rgrp*8 .. rgrp*8+7

    float acc[8][4];
    #pragma unroll
    for (int i = 0; i < 8; ++i)
        #pragma unroll
        for (int j = 0; j < 4; ++j) acc[i][j] = 0.f;

    for (int k = 0; k < 64; ++k) {
        const float4 w = *reinterpret_cast<const float4*>(Wd + (size_t)k * 128 + ccol);
        const int sw = ((k >> 2) & 7) << 2;
        #pragma unroll
        for (int h = 0; h < 2; ++h) {
            const float4 rv = *reinterpret_cast<const float4*>(&s_p[k][(rgrp * 8 + h * 4) ^ sw]);
            const float rr[4] = {rv.x, rv.y, rv.z, rv.w};
            #pragma unroll
            for (int j = 0; j < 4; ++j) {
                acc[h*4+j][0] = fmaf(rr[j], w.x, acc[h*4+j][0]);
                acc[h*4+j][1] = fmaf(rr[j], w.y, acc[h*4+j][1]);
                acc[h*4+j][2] = fmaf(rr[j], w.z, acc[h*4+j][2]);
                acc[h*4+j][3] = fmaf(rr[j], w.w, acc[h*4+j][3]);
            }
        }
    }

    {
        const float4 bb = *reinterpret_cast<const float4*>(bd + ccol);
        const float4 gg = *reinterpret_cast<const float4*>(bng + ccol);
        const float4 be = *reinterpret_cast<const float4*>(bnb + ccol);
        const float4 mm = *reinterpret_cast<const float4*>(bnm + ccol);
        const float4 vv = *reinterpret_cast<const float4*>(bnv + ccol);
        const float bia[4] = {bb.x, bb.y, bb.z, bb.w};
        float sc[4], sh[4];
        sc[0] = rsqrtf(vv.x + 1e-3f) * gg.x; sh[0] = be.x - mm.x * sc[0];
        sc[1] = rsqrtf(vv.y + 1e-3f) * gg.y; sh[1] = be.y - mm.y * sc[1];
        sc[2] = rsqrtf(vv.z + 1e-3f) * gg.z; sh[2] = be.z - mm.z * sc[2];
        sc[3] = rsqrtf(vv.w + 1e-3f) * gg.w; sh[3] = be.w - mm.w * sc[3];
        #pragma unroll
        for (int i = 0; i < 8; ++i)
            #pragma unroll
            for (int j = 0; j < 4; ++j)
                acc[i][j] = fmaf(fmaxf(acc[i][j] + bia[j], 0.f), sc[j], sh[j]);
    }

    __syncthreads();   // all GEMM reads of s_p complete -> safe to overwrite

    float (*vbuf)[64] = s_p;
    const int halfSel = ccol >> 6;
    const int cc = ccol & 63;

    #pragma unroll
    for (int half = 0; half < 2; ++half) {
        if (halfSel == half) {
            #pragma unroll
            for (int i = 0; i < 8; ++i) {
                float4 o = make_float4(acc[i][0], acc[i][1], acc[i][2], acc[i][3]);
                *reinterpret_cast<float4*>(&vbuf[rgrp * 8 + i][cc]) = o;
            }
        }
        __syncthreads();

        const int c = t & 63;
        const int rbase = (t >> 6) * 16;
        const int gch = half * 64 + c;
        int cur = s_sid[rbase];
        float s = 0.f, mx = -INFINITY;
        for (int r = rbase; r < rbase + 16; ++r) {
            const int sd = s_sid[r];
            if (sd != cur) {
                atomicAdd(&segS[(size_t)cur * 128 + gch], s);
                atomicMax(&segM[(size_t)cur * 128 + gch], enc_f32(mx));
                cur = sd; s = 0.f; mx = -INFINITY;
            }
            const float v = vbuf[r][c];
            s += v;
            mx = fmaxf(mx, v);
        }
        atomicAdd(&segS[(size_t)cur * 128 + gch], s);
        atomicMax(&segM[(size_t)cur * 128 + gch], enc_f32(mx));
        __syncthreads();
    }
}

__global__ void nf_fin_kernel(const float* __restrict__ segS,
                              const unsigned* __restrict__ segM,
                              float* __restrict__ nf)
{
    const int i = blockIdx.x * blockDim.x + threadIdx.x; // < NBATCH*128
    const int m = i >> 7, c = i & 127;
    nf[(size_t)m * 256 + c]       = tanhf(segS[i]);
    nf[(size_t)m * 256 + 128 + c] = tanhf(dec_f32(segM[i]));
}

// fd0: h = relu(nf @ W + b), 32768x256 @ 256x256. 64x64 tile per block.
__global__ __launch_bounds__(256) void fd0_kernel(
    const float* __restrict__ nf, const float* __restrict__ W, const float* __restrict__ b,
    float* __restrict__ h)
{
    __shared__ __align__(16) float sx[256][64];
    const int t = threadIdx.x;
    const int r0 = (blockIdx.x >> 2) * 64;
    const int c0 = (blockIdx.x & 3) * 64;
    for (int ch = 0; ch < 4; ++ch) {
        for (int v = t; v < 1024; v += 256) {
            const int row = v >> 4, k0 = (v & 15) * 4 + ch * 64;
            const float4 r = *reinterpret_cast<const float4*>(nf + (size_t)(r0 + row) * 256 + k0);
            sx[k0 + 0][swzS64d(row, k0 + 0)] = r.x;
            sx[k0 + 1][swzS64d(row, k0 + 1)] = r.y;
            sx[k0 + 2][swzS64d(row, k0 + 2)] = r.z;
            sx[k0 + 3][swzS64d(row, k0 + 3)] = r.w;
        }
    }
    __syncthreads();

    const int c4 = (t & 15) * 4;
    const int a4 = (t >> 4) * 4;

    float acc[4][4];
    #pragma unroll
    for (int i = 0; i < 4; ++i)
        #pragma unroll
        for (int j = 0; j < 4; ++j) acc[i][j] = 0.f;

    for (int k = 0; k < 256; ++k) {
        const int sw = ((k >> 2) & 7) << 2;
        const float4 sv = *reinterpret_cast<const float4*>(&sx[k][a4 ^ sw]);
        const float4 w = *reinterpret_cast<const float4*>(W + (size_t)k * 256 + c0 + c4);
        const float ss[4] = {sv.x, sv.y, sv.z, sv.w};
        #pragma unroll
        for (int i = 0; i < 4; ++i) {
            acc[i][0] = fmaf(ss[i], w.x, acc[i][0]);
            acc[i][1] = fmaf(ss[i], w.y, acc[i][1]);
            acc[i][2] = fmaf(ss[i], w.z, acc[i][2]);
            acc[i][3] = fmaf(ss[i], w.w, acc[i][3]);
        }
    }

    const float4 bb = *reinterpret_cast<const float4*>(b + c0 + c4);
    const float bi[4] = {bb.x, bb.y, bb.z, bb.w};
    #pragma unroll
    for (int i = 0; i < 4; ++i) {
        float4 o;
        o.x = fmaxf(acc[i][0] + bi[0], 0.f);
        o.y = fmaxf(acc[i][1] + bi[1], 0.f);
        o.z = fmaxf(acc[i][2] + bi[2], 0.f);
        o.w = fmaxf(acc[i][3] + bi[3], 0.f);
        *reinterpret_cast<float4*>(h + (size_t)(r0 + a4 + i) * 256 + c0 + c4) = o;
    }
}

// rd: logits = h @ W + b (256->24), then pairwise softmax.
__global__ __launch_bounds__(384) void rd_kernel(
    const float* __restrict__ h, const float* __restrict__ W, const float* __restrict__ b,
    float* __restrict__ outP, float* __restrict__ outL)
{
    __shared__ float sh[32][257];
    const int t = threadIdx.x;
    const int r0 = blockIdx.x * 32;
    for (int e = t; e < 32 * 256; e += 384) {
        const int ri = e >> 8, k = e & 255;
        sh[ri][k] = h[(size_t)(r0 + ri) * 256 + k];
    }
    __syncthreads();
    const int r = t / 12, pj = t % 12;
    float a0 = b[2 * pj], a1 = b[2 * pj + 1];
    for (int k = 0; k < 256; ++k) {
        const float hv = sh[r][k];
        a0 = fmaf(hv, W[k * 24 + 2 * pj],     a0);
        a1 = fmaf(hv, W[k * 24 + 2 * pj + 1], a1);
    }
    const size_t m = (size_t)(r0 + r);
    outL[m * 24 + 2 * pj]     = a0;
    outL[m * 24 + 2 * pj + 1] = a1;
    const float mx = fmaxf(a0, a1);
    const float e0 = expf(a0 - mx), e1 = expf(a1 - mx);
    const float inv = 1.f / (e0 + e1);
    outP[m * 24 + 2 * pj]     = e0 * inv;
    outP[m * 24 + 2 * pj + 1] = e1 * inv;
}

} // namespace

extern "C" void kernel_launch(void* const* d_in, const int* in_sizes, int n_in,
                              void* d_out, int out_size, void* d_ws, size_t ws_size,
                              hipStream_t stream)
{
    const float* x       = (const float*)d_in[0];
    const int*   mem     = (const int*)d_in[2];
    AdjPtrs adj;
    for (int d = 0; d < 10; ++d) adj.p[d] = (const int*)d_in[4 + d];
    const float* gc0_W = (const float*)d_in[14];
    const float* gc0_b = (const float*)d_in[15];
    const float* gc1_W = (const float*)d_in[16];
    const float* gc1_b = (const float*)d_in[17];
    const float* bn0g = (const float*)d_in[18], *bn0b = (const float*)d_in[19];
    const float* bn0m = (const float*)d_in[20], *bn0v = (const float*)d_in[21];
    const float* bn1g = (const float*)d_in[22], *bn1b = (const float*)d_in[23];
    const float* bn1m = (const float*)d_in[24], *bn1v = (const float*)d_in[25];
    const float* bn2g = (const float*)d_in[26], *bn2b = (const float*)d_in[27];
    const float* bn2m = (const float*)d_in[28], *bn2v = (const float*)d_in[29];
    const float* dW   = (const float*)d_in[30], *db   = (const float*)d_in[31];
    const float* fW   = (const float*)d_in[32], *fb   = (const float*)d_in[33];
    const float* rW   = (const float*)d_in[34], *rb   = (const float*)d_in[35];

    __half* z16 = (__half*)d_ws;                               // 1M x 64
    __half* p16 = z16 + (size_t)NATOMS * 64;                   // 1M x 64
    __half* x16 = p16 + (size_t)NATOMS * 64;                   // 1M x 80
    float*  hbuf = (float*)(x16 + (size_t)NATOMS * X16S);
    float*  segS = hbuf + (size_t)NBATCH * 256;
    unsigned* segM = (unsigned*)(segS + (size_t)NBATCH * 128);
    int*    cnt    = (int*)(segM + (size_t)NBATCH * 128);
    int*    offp   = cnt + NBATCH;
    int*    cur    = offp + NBATCH;
    int*    sorted = cur + NBATCH;
    int*    sid    = sorted + NATOMS;

    float* outP = (float*)d_out;
    float* outL = outP + (size_t)NBATCH * 24;
    float* nfb  = outL + (size_t)NBATCH * 24;

    int convBlocks = 0, poolBlocks = 0;
    for (int d = 0; d <= 10; ++d) {
        convBlocks += (kCounts[d] + 63) >> 6;
        poolBlocks += (kCounts[d] + 3) >> 2;
    }

    // one-time fp16 conversion of x (padded rows)
    cvt_kernel<<<8192, 256, 0, stream>>>(x, x16);

    // counting sort by membership + segment accumulator init
    hipMemsetAsync(cnt, 0, NBATCH * sizeof(int), stream);
    hist_kernel<<<(NATOMS + 255) / 256, 256, 0, stream>>>(mem, cnt);
    scan_kernel<<<1, 512, 0, stream>>>(cnt, offp, cur);
    scatter_kernel<<<(NATOMS + 255) / 256, 256, 0, stream>>>(mem, cur, sorted, sid);
    seg_init_kernel<<<2048, 256, 0, stream>>>(segS, segM);

    // layer 1: conv(75->64)+relu+bn0 -> pool
    conv_all_kernel<75><<<convBlocks, 512, 0, stream>>>(x16, adj, gc0_W, gc0_b,
                                                        bn0g, bn0b, bn0m, bn0v, z16);
    pool_all_kernel<<<poolBlocks, 256, 0, stream>>>(z16, adj, p16);

    // layer 2: conv(64->64)+relu+bn1 -> pool
    conv_all_kernel<64><<<convBlocks, 512, 0, stream>>>(p16, adj, gc1_W, gc1_b,
                                                        bn1g, bn1b, bn1m, bn1v, z16);
    pool_all_kernel<<<poolBlocks, 256, 0, stream>>>(z16, adj, p16);

    // dense+relu+bn2 over sorted atoms with fused segmented sum/max
    dense_seg_sorted_kernel<<<NATOMS / 64, 256, 0, stream>>>(
        p16, sorted, sid, dW, db, bn2g, bn2b, bn2m, bn2v, segS, segM);
    // nf = tanh(concat(sum, max))
    nf_fin_kernel<<<(NBATCH * 128) / 256, 256, 0, stream>>>(segS, segM, nfb);
    // h = relu(nf @ fd0_W + fd0_b)
    fd0_kernel<<<(NBATCH / 64) * 4, 256, 0, stream>>>(nfb, fW, fb, hbuf);
    // logits + softmax
    rd_kernel<<<NBATCH / 32, 384, 0, stream>>>(hbuf, rW, rb, outP, outL);
}

// Round 15
// 1731.997 us; speedup vs baseline: 1.1753x; 1.1753x over previous
//
#include <hip/hip_runtime.h>
#include <hip/hip_fp16.h>
#include <math.h>

namespace {

constexpr int NATOMS = 1000000;
constexpr int NBATCH = 32768;
constexpr int kCounts[11] = {10000,250000,300000,250000,120000,40000,15000,8000,4000,2000,1000};
constexpr int kStarts[11] = {0,10000,260000,560000,810000,930000,970000,985000,993000,997000,999000};
constexpr int X16S = 80;   // padded fp16 row stride for x (75 ch -> 160B rows)

struct AdjPtrs { const int* p[10]; };

__device__ __forceinline__ unsigned enc_f32(float x) {
    unsigned u = __float_as_uint(x);
    return (u & 0x80000000u) ? ~u : (u | 0x80000000u);
}
__device__ __forceinline__ float dec_f32(unsigned u) {
    return (u & 0x80000000u) ? __uint_as_float(u & 0x7FFFFFFFu) : __uint_as_float(~u);
}

// dense_seg/fd0 64-wide fp32 tiles (row stride 64 -> bank=col&31):
__device__ __forceinline__ int swzS64d(int row, int k) { return row ^ (((k >> 2) & 7) << 2); }

// Conv LDS layout (unified, [k][64] fp32, row stride 64 -> bank = col&31):
//   col(k, a) = a ^ (((k>>3)&7)<<3)
// Staging writes (8 lanes per row/atom, lane l8 owns channels 8*l8..8*l8+7):
//   per-j instruction: 64 lanes = 8 rows x 8 l8 -> bank = row(3b) ^ ((l8&3)<<3)
//   -> 32 banks, 2-way (free).
// Compute reads (per-lane a=0..63): col bijective -> 2-way (free).

// ---------------------------------------------------------------------------
// x fp32 [1M][75] -> x16 fp16 [1M][80] (zero-padded). 16 rows per block.
// ---------------------------------------------------------------------------
__global__ __launch_bounds__(256) void cvt_kernel(const float* __restrict__ x,
                                                  __half* __restrict__ x16)
{
    const int row = blockIdx.x * 16 + (threadIdx.x >> 4);
    const int l16 = threadIdx.x & 15;
    if (row >= NATOMS) return;
    const float* __restrict__ xr = x + (size_t)row * 75;
    __half* __restrict__ xo = x16 + (size_t)row * X16S;
    #pragma unroll
    for (int q = 0; q < 5; ++q) {
        const int c = l16 + 16 * q;
        xo[c] = __float2half((c < 75) ? xr[c] : 0.f);
    }
}

// ---------------------------------------------------------------------------
// rel-staging: 8 lanes/atom; ONE float4 (8 halves) per lane per neighbor row
// (+1 partial for the 160B x16 rows). 4x fewer gather instructions than r14.
// ---------------------------------------------------------------------------
template<int D>
__device__ __forceinline__ void stage_rel64_v(const __half* __restrict__ xin,
                                              const int* __restrict__ ad,
                                              int j0, int ai, int g8, float* __restrict__ s_rel)
{
    int idxs[D];
    #pragma unroll
    for (int n = 0; n < D; ++n) idxs[n] = ad[(size_t)(j0 + ai) * D + n];
    float2 r[4];
    #pragma unroll
    for (int q = 0; q < 4; ++q) r[q] = make_float2(0.f, 0.f);
    for (int n = 0; n < D; ++n) {
        const float4 f4 = *reinterpret_cast<const float4*>(xin + (size_t)idxs[n] * 64 + g8 * 8);
        const __half2* h2 = reinterpret_cast<const __half2*>(&f4);
        #pragma unroll
        for (int q = 0; q < 4; ++q) {
            const float2 v = __half22float2(h2[q]);
            r[q].x += v.x; r[q].y += v.y;
        }
    }
    const int col = ai ^ (g8 << 3);
    #pragma unroll
    for (int q = 0; q < 4; ++q) {
        const int k = 8 * g8 + 2 * q;
        s_rel[(k + 0) * 64 + col] = r[q].x;
        s_rel[(k + 1) * 64 + col] = r[q].y;
    }
}

__device__ __forceinline__ void stage_rel64_rt_v(const __half* __restrict__ xin,
                                                 const int* __restrict__ ad, int d,
                                                 int j0, int ai, int g8, float* __restrict__ s_rel)
{
    int idxs[10];
    for (int n = 0; n < d; ++n) idxs[n] = ad[(size_t)(j0 + ai) * d + n];
    float2 r[4];
    #pragma unroll
    for (int q = 0; q < 4; ++q) r[q] = make_float2(0.f, 0.f);
    for (int n = 0; n < d; ++n) {
        const float4 f4 = *reinterpret_cast<const float4*>(xin + (size_t)idxs[n] * 64 + g8 * 8);
        const __half2* h2 = reinterpret_cast<const __half2*>(&f4);
        #pragma unroll
        for (int q = 0; q < 4; ++q) {
            const float2 v = __half22float2(h2[q]);
            r[q].x += v.x; r[q].y += v.y;
        }
    }
    const int col = ai ^ (g8 << 3);
    #pragma unroll
    for (int q = 0; q < 4; ++q) {
        const int k = 8 * g8 + 2 * q;
        s_rel[(k + 0) * 64 + col] = r[q].x;
        s_rel[(k + 1) * 64 + col] = r[q].y;
    }
}

template<int D>
__device__ __forceinline__ void stage_rel75_v(const __half* __restrict__ xin,
                                              const int* __restrict__ ad,
                                              int j0, int ai, int g8, float* __restrict__ s_rel)
{
    int idxs[D];
    #pragma unroll
    for (int n = 0; n < D; ++n) idxs[n] = ad[(size_t)(j0 + ai) * D + n];
    float2 r[4], r2[4];
    #pragma unroll
    for (int q = 0; q < 4; ++q) { r[q] = make_float2(0.f, 0.f); r2[q] = make_float2(0.f, 0.f); }
    for (int n = 0; n < D; ++n) {
        const __half* __restrict__ xr = xin + (size_t)idxs[n] * X16S;
        const float4 f4 = *reinterpret_cast<const float4*>(xr + g8 * 8);
        const __half2* h2 = reinterpret_cast<const __half2*>(&f4);
        #pragma unroll
        for (int q = 0; q < 4; ++q) {
            const float2 v = __half22float2(h2[q]);
            r[q].x += v.x; r[q].y += v.y;
        }
        if (g8 < 2) {
            const float4 g4 = *reinterpret_cast<const float4*>(xr + 64 + g8 * 8);
            const __half2* t2 = reinterpret_cast<const __half2*>(&g4);
            #pragma unroll
            for (int q = 0; q < 4; ++q) {
                const float2 v = __half22float2(t2[q]);
                r2[q].x += v.x; r2[q].y += v.y;
            }
        }
    }
    const int col = ai ^ (g8 << 3);
    #pragma unroll
    for (int q = 0; q < 4; ++q) {
        const int k = 8 * g8 + 2 * q;
        s_rel[(k + 0) * 64 + col] = r[q].x;
        s_rel[(k + 1) * 64 + col] = r[q].y;
    }
    if (g8 < 2) {
        #pragma unroll
        for (int q = 0; q < 4; ++q) {
            const int k = 64 + 8 * g8 + 2 * q;
            if (k < 75)     s_rel[(k + 0) * 64 + col] = r2[q].x;
            if (k + 1 < 75) s_rel[(k + 1) * 64 + col] = r2[q].y;
        }
    }
}

__device__ __forceinline__ void stage_rel75_rt_v(const __half* __restrict__ xin,
                                                 const int* __restrict__ ad, int d,
                                                 int j0, int ai, int g8, float* __restrict__ s_rel)
{
    int idxs[10];
    for (int n = 0; n < d; ++n) idxs[n] = ad[(size_t)(j0 + ai) * d + n];
    float2 r[4], r2[4];
    #pragma unroll
    for (int q = 0; q < 4; ++q) { r[q] = make_float2(0.f, 0.f); r2[q] = make_float2(0.f, 0.f); }
    for (int n = 0; n < d; ++n) {
        const __half* __restrict__ xr = xin + (size_t)idxs[n] * X16S;
        const float4 f4 = *reinterpret_cast<const float4*>(xr + g8 * 8);
        const __half2* h2 = reinterpret_cast<const __half2*>(&f4);
        #pragma unroll
        for (int q = 0; q < 4; ++q) {
            const float2 v = __half22float2(h2[q]);
            r[q].x += v.x; r[q].y += v.y;
        }
        if (g8 < 2) {
            const float4 g4 = *reinterpret_cast<const float4*>(xr + 64 + g8 * 8);
            const __half2* t2 = reinterpret_cast<const __half2*>(&g4);
            #pragma unroll
            for (int q = 0; q < 4; ++q) {
                const float2 v = __half22float2(t2[q]);
                r2[q].x += v.x; r2[q].y += v.y;
            }
        }
    }
    const int col = ai ^ (g8 << 3);
    #pragma unroll
    for (int q = 0; q < 4; ++q) {
        const int k = 8 * g8 + 2 * q;
        s_rel[(k + 0) * 64 + col] = r[q].x;
        s_rel[(k + 1) * 64 + col] = r[q].y;
    }
    if (g8 < 2) {
        #pragma unroll
        for (int q = 0; q < 4; ++q) {
            const int k = 64 + 8 * g8 + 2 * q;
            if (k < 75)     s_rel[(k + 0) * 64 + col] = r2[q].x;
            if (k + 1 < 75) s_rel[(k + 1) * 64 + col] = r2[q].y;
        }
    }
}

// ---------------------------------------------------------------------------
// Merged conv layer: 64-atom tile, 512 threads, ONE 16B fp16 load per lane per
// gathered row (r7-r14 established the gather path is request-rate bound:
// time invariant to bytes/occupancy/compute form; r14's half2 gathers kept
// the r13 request count and the time did not move -> cut requests 4x).
// Scalar weights, fp32 accumulate, fp16 activations.
// ---------------------------------------------------------------------------
template<int CI>
__global__ __launch_bounds__(512) void conv_all_kernel(
    const __half* __restrict__ xin, AdjPtrs adj,
    const float* __restrict__ W, const float* __restrict__ B,
    const float* __restrict__ bng, const float* __restrict__ bnb,
    const float* __restrict__ bnm, const float* __restrict__ bnv,
    __half* __restrict__ out)
{
    constexpr int XS = (CI == 64) ? 64 : X16S;
    constexpr int SM = (2 * CI * 64 > 64 * 65) ? 2 * CI * 64 : 64 * 65;
    __shared__ __align__(16) float smem[SM];
    float* s_self = smem;            // [CI][64]
    float* s_rel  = smem + CI * 64;  // [CI][64]

    int d = 0, rem = blockIdx.x;
    for (;;) { const int nb = (kCounts[d] + 63) >> 6; if (rem < nb) break; rem -= nb; ++d; }
    const int j0 = rem << 6;
    const int nA = min(64, kCounts[d] - j0);
    const int a0 = kStarts[d] + j0;
    const int t = threadIdx.x;

    // ---- stage self rows: 8 lanes/row, one float4 (+tail) each ----
    {
        const int row = t >> 3, l8 = t & 7;
        if (row < nA) {
            const __half* __restrict__ xr = xin + (size_t)(a0 + row) * XS;
            const float4 f4 = *reinterpret_cast<const float4*>(xr + l8 * 8);
            const __half2* h2 = reinterpret_cast<const __half2*>(&f4);
            const int col = row ^ (l8 << 3);
            #pragma unroll
            for (int q = 0; q < 4; ++q) {
                const float2 f = __half22float2(h2[q]);
                const int k = 8 * l8 + 2 * q;
                s_self[(k + 0) * 64 + col] = f.x;
                s_self[(k + 1) * 64 + col] = f.y;
            }
            if (CI == 75 && l8 < 2) {
                const float4 g4 = *reinterpret_cast<const float4*>(xr + 64 + l8 * 8);
                const __half2* t2 = reinterpret_cast<const __half2*>(&g4);
                #pragma unroll
                for (int q = 0; q < 4; ++q) {
                    const float2 f = __half22float2(t2[q]);
                    const int k = 64 + 8 * l8 + 2 * q;
                    if (k < 75)     s_self[(k + 0) * 64 + col] = f.x;
                    if (k + 1 < 75) s_self[(k + 1) * 64 + col] = f.y;
                }
            }
        }
    }

    // ---- stage neighbor sums (8 lanes/atom, one 16B load per row) ----
    if (d > 0) {
        const int ai = t >> 3, g8 = t & 7;
        if (ai < nA) {
            const int* __restrict__ adp = adj.p[d - 1];
            if constexpr (CI == 64) {
                switch (d) {
                case 1: stage_rel64_v<1>(xin, adp, j0, ai, g8, s_rel); break;
                case 2: stage_rel64_v<2>(xin, adp, j0, ai, g8, s_rel); break;
                case 3: stage_rel64_v<3>(xin, adp, j0, ai, g8, s_rel); break;
                case 4: stage_rel64_v<4>(xin, adp, j0, ai, g8, s_rel); break;
                default: stage_rel64_rt_v(xin, adp, d, j0, ai, g8, s_rel); break;
                }
            } else {
                switch (d) {
                case 1: stage_rel75_v<1>(xin, adp, j0, ai, g8, s_rel); break;
                case 2: stage_rel75_v<2>(xin, adp, j0, ai, g8, s_rel); break;
                case 3: stage_rel75_v<3>(xin, adp, j0, ai, g8, s_rel); break;
                case 4: stage_rel75_v<4>(xin, adp, j0, ai, g8, s_rel); break;
                default: stage_rel75_rt_v(xin, adp, d, j0, ai, g8, s_rel); break;
                }
            }
        }
    }
    __syncthreads();

    // ---- compute: atom-per-lane, 8 channels/thread, scalar weights ----
    const int a  = t & 63;
    const int c0 = __builtin_amdgcn_readfirstlane(t >> 6) * 8;   // wave-uniform

    float acc[8];
    #pragma unroll
    for (int j = 0; j < 8; ++j) acc[j] = 0.f;

    if (d == 0) {
        const float* __restrict__ Ws = W + (size_t)(2 * 10) * CI * 64;
        #pragma unroll
        for (int k = 0; k < CI; ++k) {
            const float xs = s_self[k * 64 + (a ^ (((k >> 3) & 7) << 3))];
            #pragma unroll
            for (int j = 0; j < 8; ++j)
                acc[j] = fmaf(xs, Ws[k * 64 + c0 + j], acc[j]);
        }
    } else {
        const float* __restrict__ Wr = W + (size_t)(2 * (d - 1)) * CI * 64;
        const float* __restrict__ Ws = W + (size_t)(2 * d - 1) * CI * 64;
        #pragma unroll
        for (int k = 0; k < CI; ++k) {
            const int col = a ^ (((k >> 3) & 7) << 3);
            const float xs = s_self[k * 64 + col];
            const float xr = s_rel [k * 64 + col];
            #pragma unroll
            for (int j = 0; j < 8; ++j)
                acc[j] = fmaf(xs, Ws[k * 64 + c0 + j],
                              fmaf(xr, Wr[k * 64 + c0 + j], acc[j]));
        }
    }

    // ---- epilogue: scalar bias/BN, rotated-LDS transpose, fp16 store ----
    __syncthreads();
    float* vout = smem;       // [64][65]
    #pragma unroll
    for (int j = 0; j < 8; ++j) {
        const int c = c0 + j;                               // wave-uniform
        const float bias = (d == 0) ? B[20 * 64 + c]
                                    : (B[(2 * (d - 1)) * 64 + c] + B[(2 * d - 1) * 64 + c]);
        const float scl = rsqrtf(bnv[c] + 1e-3f) * bng[c];
        const float sht = bnb[c] - bnm[c] * scl;
        vout[a * 65 + c] = fmaf(fmaxf(acc[j] + bias, 0.f), scl, sht);
    }
    __syncthreads();
    const int cc = t & 63, g = t >> 6;
    #pragma unroll
    for (int i = 0; i < 8; ++i) {
        const int row = g * 8 + i;
        if (row < nA) out[(size_t)(a0 + row) * 64 + cc] = __float2half(vout[row * 65 + cc]);
    }
}

// ---------------------------------------------------------------------------
// Merged pool layer (fp16): one wave per atom, per-neighbor row = 1 instr/line.
// ---------------------------------------------------------------------------
template<int D>
__device__ __forceinline__ float pool_body(const __half* __restrict__ z,
                                           const int* __restrict__ ad, int j, int c, float v)
{
    int idxs[D];
    #pragma unroll
    for (int n = 0; n < D; ++n) idxs[n] = ad[(size_t)j * D + n];
    #pragma unroll
    for (int n = 0; n < D; ++n) v = fmaxf(v, __half2float(z[(size_t)idxs[n] * 64 + c]));
    return v;
}

__global__ __launch_bounds__(256) void pool_all_kernel(
    const __half* __restrict__ z, AdjPtrs adj, __half* __restrict__ p)
{
    int d = 0, rem = blockIdx.x;
    for (;;) { const int nb = (kCounts[d] + 3) >> 2; if (rem < nb) break; rem -= nb; ++d; }
    const int t = threadIdx.x;
    const int j = rem * 4 + (t >> 6);
    if (j >= kCounts[d]) return;
    const int c = t & 63;
    const int a = kStarts[d] + j;
    float v = __half2float(z[(size_t)a * 64 + c]);
    if (d > 0) {
        const int* __restrict__ ad = adj.p[d - 1];
        switch (d) {
        case 1:  v = pool_body<1 >(z, ad, j, c, v); break;
        case 2:  v = pool_body<2 >(z, ad, j, c, v); break;
        case 3:  v = pool_body<3 >(z, ad, j, c, v); break;
        case 4:  v = pool_body<4 >(z, ad, j, c, v); break;
        case 5:  v = pool_body<5 >(z, ad, j, c, v); break;
        case 6:  v = pool_body<6 >(z, ad, j, c, v); break;
        case 7:  v = pool_body<7 >(z, ad, j, c, v); break;
        case 8:  v = pool_body<8 >(z, ad, j, c, v); break;
        case 9:  v = pool_body<9 >(z, ad, j, c, v); break;
        default: v = pool_body<10>(z, ad, j, c, v); break;
        }
    }
    p[(size_t)a * 64 + c] = __float2half(v);
}

// ---------------------------------------------------------------------------
// Counting sort by membership: hist -> scan -> scatter (+ per-position seg id).
// ---------------------------------------------------------------------------
__global__ __launch_bounds__(256) void hist_kernel(const int* __restrict__ mem,
                                                   int* __restrict__ cnt)
{
    const int a = blockIdx.x * 256 + threadIdx.x;
    if (a < NATOMS) atomicAdd(&cnt[mem[a]], 1);
}

__global__ __launch_bounds__(512) void scan_kernel(const int* __restrict__ cnt,
                                                   int* __restrict__ off,
                                                   int* __restrict__ cur)
{
    __shared__ int part[512];
    const int t = threadIdx.x;
    const int base = t * 64;
    int s = 0;
    #pragma unroll 8
    for (int i = 0; i < 64; ++i) s += cnt[base + i];
    part[t] = s;
    __syncthreads();
    for (int o = 1; o < 512; o <<= 1) {
        int v = (t >= o) ? part[t - o] : 0;
        __syncthreads();
        part[t] += v;
        __syncthreads();
    }
    int run = (t == 0) ? 0 : part[t - 1];
    for (int i = 0; i < 64; ++i) {
        off[base + i] = run;
        cur[base + i] = run;
        run += cnt[base + i];
    }
}

__global__ __launch_bounds__(256) void scatter_kernel(const int* __restrict__ mem,
                                                      int* __restrict__ cur,
                                                      int* __restrict__ sorted,
                                                      int* __restrict__ sid)
{
    const int a = blockIdx.x * 256 + threadIdx.x;
    if (a < NATOMS) {
        const int m = mem[a];
        const int pos = atomicAdd(&cur[m], 1);
        sorted[pos] = a;
        sid[pos] = m;
    }
}

__global__ void seg_init_kernel(float* __restrict__ segS, unsigned* __restrict__ segM)
{
    const int n = NBATCH * 128;
    for (int i = blockIdx.x * blockDim.x + threadIdx.x; i < n; i += gridDim.x * blockDim.x) {
        segS[i] = 0.f;
        segM[i] = 0x007FFFFFu; // enc(-inf)
    }
}

// ---------------------------------------------------------------------------
// Dense 64->128 + ReLU + BN2 over SORTED atoms (fp16 rows, 8 lanes/row 16B
// gather loads) + fused segmented sum/max epilogue.
// ---------------------------------------------------------------------------
__global__ __launch_bounds__(256) void dense_seg_sorted_kernel(
    const __half* __restrict__ p,
    const int* __restrict__ sorted, const int* __restrict__ sid,
    const float* __restrict__ Wd, const float* __restrict__ bd,
    const float* __restrict__ bng, const float* __restrict__ bnb,
    const float* __restrict__ bnm, const float* __restrict__ bnv,
    float* __restrict__ segS, unsigned* __restrict__ segM)
{
    __shared__ __align__(16) float s_p[64][64];   // staging; reused as v-buffer
    __shared__ int s_idx[64];
    __shared__ int s_sid[64];

    const int t = threadIdx.x;
    const int pos0 = blockIdx.x * 64;   // NATOMS = 15625 * 64 exactly

    if (t < 64) {
        s_idx[t] = sorted[pos0 + t];
        s_sid[t] = sid[pos0 + t];
    }
    __syncthreads();

    // 8 lanes/row, one float4 (8 halves) each; two row-groups of 32
    {
        const int row = t >> 3, l8 = t & 7;   // rows 0..31
        #pragma unroll
        for (int half = 0; half < 2; ++half) {
            const int rr = row + half * 32;
            const float4 f4 = *reinterpret_cast<const float4*>(p + (size_t)s_idx[rr] * 64 + l8 * 8);
            const __half2* h2 = reinterpret_cast<const __half2*>(&f4);
            // layout must match GEMM reads below: swzS64d(row, k) with k groups of 4
            #pragma unroll
            for (int q = 0; q < 4; ++q) {
                const float2 f = __half22float2(h2[q]);
                const int k = 8 * l8 + 2 * q;
                s_p[k + 0][swzS64d(rr, k + 0)] = f.x;
                s_p[k + 1][swzS64d(rr, k + 1)] = f.y;
            }
        }
    }
    __syncthreads();

    const int ccol = (t & 31) * 4;   // 4 consecutive output channels
    const int rgrp = t >> 5;         // 8 rows: rgrp*8 .. rgrp*8+7

    float acc[8][4];
    #pragma unroll
    for (int i = 0; i < 8; ++i)
        #pragma unroll
        for (int j = 0; j < 4; ++j) acc[i][j] = 0.f;

    for (int k = 0; k < 64; ++k) {
        const float4 w = *reinterpret_cast<const float4*>(Wd + (size_t)k * 128 + ccol);
        const int sw = ((k >> 2) & 7) << 2;
        #pragma unroll
        for (int h = 0; h < 2; ++h) {
            const float4 rv = *reinterpret_cast<const float4*>(&s_p[k][(rgrp * 8 + h * 4) ^ sw]);
            const float rr[4] = {rv.x, rv.y, rv.z, rv.w};
            #pragma unroll
            for (int j = 0; j < 4; ++j) {
                acc[h*4+j][0] = fmaf(rr[j], w.x, acc[h*4+j][0]);
                acc[h*4+j][1] = fmaf(rr[j], w.y, acc[h*4+j][1]);
                acc[h*4+j][2] = fmaf(rr[j], w.z, acc[h*4+j][2]);
                acc[h*4+j][3] = fmaf(rr[j], w.w, acc[h*4+j][3]);
            }
        }
    }

    {
        const float4 bb = *reinterpret_cast<const float4*>(bd + ccol);
        const float4 gg = *reinterpret_cast<const float4*>(bng + ccol);
        const float4 be = *reinterpret_cast<const float4*>(bnb + ccol);
        const float4 mm = *reinterpret_cast<const float4*>(bnm + ccol);
        const float4 vv = *reinterpret_cast<const float4*>(bnv + ccol);
        const float bia[4] = {bb.x, bb.y, bb.z, bb.w};
        float sc[4], sh[4];
        sc[0] = rsqrtf(vv.x + 1e-3f) * gg.x; sh[0] = be.x - mm.x * sc[0];
        sc[1] = rsqrtf(vv.y + 1e-3f) * gg.y; sh[1] = be.y - mm.y * sc[1];
        sc[2] = rsqrtf(vv.z + 1e-3f) * gg.z; sh[2] = be.z - mm.z * sc[2];
        sc[3] = rsqrtf(vv.w + 1e-3f) * gg.w; sh[3] = be.w - mm.w * sc[3];
        #pragma unroll
        for (int i = 0; i < 8; ++i)
            #pragma unroll
            for (int j = 0; j < 4; ++j)
                acc[i][j] = fmaf(fmaxf(acc[i][j] + bia[j], 0.f), sc[j], sh[j]);
    }

    __syncthreads();   // all GEMM reads of s_p complete -> safe to overwrite

    float (*vbuf)[64] = s_p;
    const int halfSel = ccol >> 6;
    const int cc = ccol & 63;

    #pragma unroll
    for (int half = 0; half < 2; ++half) {
        if (halfSel == half) {
            #pragma unroll
            for (int i = 0; i < 8; ++i) {
                float4 o = make_float4(acc[i][0], acc[i][1], acc[i][2], acc[i][3]);
                *reinterpret_cast<float4*>(&vbuf[rgrp * 8 + i][cc]) = o;
            }
        }
        __syncthreads();

        const int c = t & 63;
        const int rbase = (t >> 6) * 16;
        const int gch = half * 64 + c;
        int cur = s_sid[rbase];
        float s = 0.f, mx = -INFINITY;
        for (int r = rbase; r < rbase + 16; ++r) {
            const int sd = s_sid[r];
            if (sd != cur) {
                atomicAdd(&segS[(size_t)cur * 128 + gch], s);
                atomicMax(&segM[(size_t)cur * 128 + gch], enc_f32(mx));
                cur = sd; s = 0.f; mx = -INFINITY;
            }
            const float v = vbuf[r][c];
            s += v;
            mx = fmaxf(mx, v);
        }
        atomicAdd(&segS[(size_t)cur * 128 + gch], s);
        atomicMax(&segM[(size_t)cur * 128 + gch], enc_f32(mx));
        __syncthreads();
    }
}

__global__ void nf_fin_kernel(const float* __restrict__ segS,
                              const unsigned* __restrict__ segM,
                              float* __restrict__ nf)
{
    const int i = blockIdx.x * blockDim.x + threadIdx.x; // < NBATCH*128
    const int m = i >> 7, c = i & 127;
    nf[(size_t)m * 256 + c]       = tanhf(segS[i]);
    nf[(size_t)m * 256 + 128 + c] = tanhf(dec_f32(segM[i]));
}

// fd0: h = relu(nf @ W + b), 32768x256 @ 256x256. 64x64 tile per block.
__global__ __launch_bounds__(256) void fd0_kernel(
    const float* __restrict__ nf, const float* __restrict__ W, const float* __restrict__ b,
    float* __restrict__ h)
{
    __shared__ __align__(16) float sx[256][64];
    const int t = threadIdx.x;
    const int r0 = (blockIdx.x >> 2) * 64;
    const int c0 = (blockIdx.x & 3) * 64;
    for (int ch = 0; ch < 4; ++ch) {
        for (int v = t; v < 1024; v += 256) {
            const int row = v >> 4, k0 = (v & 15) * 4 + ch * 64;
            const float4 r = *reinterpret_cast<const float4*>(nf + (size_t)(r0 + row) * 256 + k0);
            sx[k0 + 0][swzS64d(row, k0 + 0)] = r.x;
            sx[k0 + 1][swzS64d(row, k0 + 1)] = r.y;
            sx[k0 + 2][swzS64d(row, k0 + 2)] = r.z;
            sx[k0 + 3][swzS64d(row, k0 + 3)] = r.w;
        }
    }
    __syncthreads();

    const int c4 = (t & 15) * 4;
    const int a4 = (t >> 4) * 4;

    float acc[4][4];
    #pragma unroll
    for (int i = 0; i < 4; ++i)
        #pragma unroll
        for (int j = 0; j < 4; ++j) acc[i][j] = 0.f;

    for (int k = 0; k < 256; ++k) {
        const int sw = ((k >> 2) & 7) << 2;
        const float4 sv = *reinterpret_cast<const float4*>(&sx[k][a4 ^ sw]);
        const float4 w = *reinterpret_cast<const float4*>(W + (size_t)k * 256 + c0 + c4);
        const float ss[4] = {sv.x, sv.y, sv.z, sv.w};
        #pragma unroll
        for (int i = 0; i < 4; ++i) {
            acc[i][0] = fmaf(ss[i], w.x, acc[i][0]);
            acc[i][1] = fmaf(ss[i], w.y, acc[i][1]);
            acc[i][2] = fmaf(ss[i], w.z, acc[i][2]);
            acc[i][3] = fmaf(ss[i], w.w, acc[i][3]);
        }
    }

    const float4 bb = *reinterpret_cast<const float4*>(b + c0 + c4);
    const float bi[4] = {bb.x, bb.y, bb.z, bb.w};
    #pragma unroll
    for (int i = 0; i < 4; ++i) {
        float4 o;
        o.x = fmaxf(acc[i][0] + bi[0], 0.f);
        o.y = fmaxf(acc[i][1] + bi[1], 0.f);
        o.z = fmaxf(acc[i][2] + bi[2], 0.f);
        o.w = fmaxf(acc[i][3] + bi[3], 0.f);
        *reinterpret_cast<float4*>(h + (size_t)(r0 + a4 + i) * 256 + c0 + c4) = o;
    }
}

// rd: logits = h @ W + b (256->24), then pairwise softmax.
__global__ __launch_bounds__(384) void rd_kernel(
    const float* __restrict__ h, const float* __restrict__ W, const float* __restrict__ b,
    float* __restrict__ outP, float* __restrict__ outL)
{
    __shared__ float sh[32][257];
    const int t = threadIdx.x;
    const int r0 = blockIdx.x * 32;
    for (int e = t; e < 32 * 256; e += 384) {
        const int ri = e >> 8, k = e & 255;
        sh[ri][k] = h[(size_t)(r0 + ri) * 256 + k];
    }
    __syncthreads();
    const int r = t / 12, pj = t % 12;
    float a0 = b[2 * pj], a1 = b[2 * pj + 1];
    for (int k = 0; k < 256; ++k) {
        const float hv = sh[r][k];
        a0 = fmaf(hv, W[k * 24 + 2 * pj],     a0);
        a1 = fmaf(hv, W[k * 24 + 2 * pj + 1], a1);
    }
    const size_t m = (size_t)(r0 + r);
    outL[m * 24 + 2 * pj]     = a0;
    outL[m * 24 + 2 * pj + 1] = a1;
    const float mx = fmaxf(a0, a1);
    const float e0 = expf(a0 - mx), e1 = expf(a1 - mx);
    const float inv = 1.f / (e0 + e1);
    outP[m * 24 + 2 * pj]     = e0 * inv;
    outP[m * 24 + 2 * pj + 1] = e1 * inv;
}

} // namespace

extern "C" void kernel_launch(void* const* d_in, const int* in_sizes, int n_in,
                              void* d_out, int out_size, void* d_ws, size_t ws_size,
                              hipStream_t stream)
{
    const float* x       = (const float*)d_in[0];
    const int*   mem     = (const int*)d_in[2];
    AdjPtrs adj;
    for (int d = 0; d < 10; ++d) adj.p[d] = (const int*)d_in[4 + d];
    const float* gc0_W = (const float*)d_in[14];
    const float* gc0_b = (const float*)d_in[15];
    const float* gc1_W = (const float*)d_in[16];
    const float* gc1_b = (const float*)d_in[17];
    const float* bn0g = (const float*)d_in[18], *bn0b = (const float*)d_in[19];
    const float* bn0m = (const float*)d_in[20], *bn0v = (const float*)d_in[21];
    const float* bn1g = (const float*)d_in[22], *bn1b = (const float*)d_in[23];
    const float* bn1m = (const float*)d_in[24], *bn1v = (const float*)d_in[25];
    const float* bn2g = (const float*)d_in[26], *bn2b = (const float*)d_in[27];
    const float* bn2m = (const float*)d_in[28], *bn2v = (const float*)d_in[29];
    const float* dW   = (const float*)d_in[30], *db   = (const float*)d_in[31];
    const float* fW   = (const float*)d_in[32], *fb   = (const float*)d_in[33];
    const float* rW   = (const float*)d_in[34], *rb   = (const float*)d_in[35];

    __half* z16 = (__half*)d_ws;                               // 1M x 64
    __half* p16 = z16 + (size_t)NATOMS * 64;                   // 1M x 64
    __half* x16 = p16 + (size_t)NATOMS * 64;                   // 1M x 80
    float*  hbuf = (float*)(x16 + (size_t)NATOMS * X16S);
    float*  segS = hbuf + (size_t)NBATCH * 256;
    unsigned* segM = (unsigned*)(segS + (size_t)NBATCH * 128);
    int*    cnt    = (int*)(segM + (size_t)NBATCH * 128);
    int*    offp   = cnt + NBATCH;
    int*    cur    = offp + NBATCH;
    int*    sorted = cur + NBATCH;
    int*    sid    = sorted + NATOMS;

    float* outP = (float*)d_out;
    float* outL = outP + (size_t)NBATCH * 24;
    float* nfb  = outL + (size_t)NBATCH * 24;

    int convBlocks = 0, poolBlocks = 0;
    for (int d = 0; d <= 10; ++d) {
        convBlocks += (kCounts[d] + 63) >> 6;
        poolBlocks += (kCounts[d] + 3) >> 2;
    }

    // one-time fp16 conversion of x (padded rows)
    cvt_kernel<<<(NATOMS + 15) / 16, 256, 0, stream>>>(x, x16);

    // counting sort by membership + segment accumulator init
    hipMemsetAsync(cnt, 0, NBATCH * sizeof(int), stream);
    hist_kernel<<<(NATOMS + 255) / 256, 256, 0, stream>>>(mem, cnt);
    scan_kernel<<<1, 512, 0, stream>>>(cnt, offp, cur);
    scatter_kernel<<<(NATOMS + 255) / 256, 256, 0, stream>>>(mem, cur, sorted, sid);
    seg_init_kernel<<<2048, 256, 0, stream>>>(segS, segM);

    // layer 1: conv(75->64)+relu+bn0 -> pool
    conv_all_kernel<75><<<convBlocks, 512, 0, stream>>>(x16, adj, gc0_W, gc0_b,
                                                        bn0g, bn0b, bn0m, bn0v, z16);
    pool_all_kernel<<<poolBlocks, 256, 0, stream>>>(z16, adj, p16);

    // layer 2: conv(64->64)+relu+bn1 -> pool
    conv_all_kernel<64><<<convBlocks, 512, 0, stream>>>(p16, adj, gc1_W, gc1_b,
                                                        bn1g, bn1b, bn1m, bn1v, z16);
    pool_all_kernel<<<poolBlocks, 256, 0, stream>>>(z16, adj, p16);

    // dense+relu+bn2 over sorted atoms with fused segmented sum/max
    dense_seg_sorted_kernel<<<NATOMS / 64, 256, 0, stream>>>(
        p16, sorted, sid, dW, db, bn2g, bn2b, bn2m, bn2v, segS, segM);
    // nf = tanh(concat(sum, max))
    nf_fin_kernel<<<(NBATCH * 128) / 256, 256, 0, stream>>>(segS, segM, nfb);
    // h = relu(nf @ fd0_W + fd0_b)
    fd0_kernel<<<(NBATCH / 64) * 4, 256, 0, stream>>>(nfb, fW, fb, hbuf);
    // logits + softmax
    rd_kernel<<<NBATCH / 32, 384, 0, stream>>>(hbuf, rW, rb, outP, outL);
}

// Round 16
// 1441.908 us; speedup vs baseline: 1.4118x; 1.2012x over previous
//
#include <hip/hip_runtime.h>
#include <hip/hip_fp16.h>
#include <math.h>

namespace {

constexpr int NATOMS = 1000000;
constexpr int NBATCH = 32768;
constexpr int kCounts[11] = {10000,250000,300000,250000,120000,40000,15000,8000,4000,2000,1000};
constexpr int kStarts[11] = {0,10000,260000,560000,810000,930000,970000,985000,993000,997000,999000};
constexpr int X16S = 80;   // padded fp16 row stride for x (75 ch -> 160B rows)

struct AdjPtrs { const int* p[10]; };

__device__ __forceinline__ unsigned enc_f32(float x) {
    unsigned u = __float_as_uint(x);
    return (u & 0x80000000u) ? ~u : (u | 0x80000000u);
}
__device__ __forceinline__ float dec_f32(unsigned u) {
    return (u & 0x80000000u) ? __uint_as_float(u & 0x7FFFFFFFu) : __uint_as_float(~u);
}

// dense_seg/fd0 64-wide fp32 tiles (row stride 64 -> bank=col&31):
__device__ __forceinline__ int swzS64d(int row, int k) { return row ^ (((k >> 2) & 7) << 2); }

// Conv LDS layout ([k][64] fp32): col(k,a) = a ^ (((k>>3)&7)<<3).
// Staging (8 lanes/row): bank = row(3b) ^ ((l8&3)<<3) -> 32 banks, 2-way.
// Compute reads: bijective per-lane -> 2-way.

// ---------------------------------------------------------------------------
// x fp32 [1M][75] -> x16 fp16 [1M][80] (zero-padded). 16 rows per block.
// ---------------------------------------------------------------------------
__global__ __launch_bounds__(256) void cvt_kernel(const float* __restrict__ x,
                                                  __half* __restrict__ x16)
{
    const int row = blockIdx.x * 16 + (threadIdx.x >> 4);
    const int l16 = threadIdx.x & 15;
    if (row >= NATOMS) return;
    const float* __restrict__ xr = x + (size_t)row * 75;
    __half* __restrict__ xo = x16 + (size_t)row * X16S;
    #pragma unroll
    for (int q = 0; q < 5; ++q) {
        const int c = l16 + 16 * q;
        xo[c] = __float2half((c < 75) ? xr[c] : 0.f);
    }
}

// ---------------------------------------------------------------------------
// rel-staging: 8 lanes/atom; ONE float4 (8 halves) per lane per neighbor row.
// ---------------------------------------------------------------------------
template<int D>
__device__ __forceinline__ void stage_rel64_v(const __half* __restrict__ xin,
                                              const int* __restrict__ ad,
                                              int j0, int ai, int g8, float* __restrict__ s_rel)
{
    int idxs[D];
    #pragma unroll
    for (int n = 0; n < D; ++n) idxs[n] = ad[(size_t)(j0 + ai) * D + n];
    float2 r[4];
    #pragma unroll
    for (int q = 0; q < 4; ++q) r[q] = make_float2(0.f, 0.f);
    for (int n = 0; n < D; ++n) {
        const float4 f4 = *reinterpret_cast<const float4*>(xin + (size_t)idxs[n] * 64 + g8 * 8);
        const __half2* h2 = reinterpret_cast<const __half2*>(&f4);
        #pragma unroll
        for (int q = 0; q < 4; ++q) {
            const float2 v = __half22float2(h2[q]);
            r[q].x += v.x; r[q].y += v.y;
        }
    }
    const int col = ai ^ (g8 << 3);
    #pragma unroll
    for (int q = 0; q < 4; ++q) {
        const int k = 8 * g8 + 2 * q;
        s_rel[(k + 0) * 64 + col] = r[q].x;
        s_rel[(k + 1) * 64 + col] = r[q].y;
    }
}

__device__ __forceinline__ void stage_rel64_rt_v(const __half* __restrict__ xin,
                                                 const int* __restrict__ ad, int d,
                                                 int j0, int ai, int g8, float* __restrict__ s_rel)
{
    int idxs[10];
    for (int n = 0; n < d; ++n) idxs[n] = ad[(size_t)(j0 + ai) * d + n];
    float2 r[4];
    #pragma unroll
    for (int q = 0; q < 4; ++q) r[q] = make_float2(0.f, 0.f);
    for (int n = 0; n < d; ++n) {
        const float4 f4 = *reinterpret_cast<const float4*>(xin + (size_t)idxs[n] * 64 + g8 * 8);
        const __half2* h2 = reinterpret_cast<const __half2*>(&f4);
        #pragma unroll
        for (int q = 0; q < 4; ++q) {
            const float2 v = __half22float2(h2[q]);
            r[q].x += v.x; r[q].y += v.y;
        }
    }
    const int col = ai ^ (g8 << 3);
    #pragma unroll
    for (int q = 0; q < 4; ++q) {
        const int k = 8 * g8 + 2 * q;
        s_rel[(k + 0) * 64 + col] = r[q].x;
        s_rel[(k + 1) * 64 + col] = r[q].y;
    }
}

template<int D>
__device__ __forceinline__ void stage_rel75_v(const __half* __restrict__ xin,
                                              const int* __restrict__ ad,
                                              int j0, int ai, int g8, float* __restrict__ s_rel)
{
    int idxs[D];
    #pragma unroll
    for (int n = 0; n < D; ++n) idxs[n] = ad[(size_t)(j0 + ai) * D + n];
    float2 r[4], r2[4];
    #pragma unroll
    for (int q = 0; q < 4; ++q) { r[q] = make_float2(0.f, 0.f); r2[q] = make_float2(0.f, 0.f); }
    for (int n = 0; n < D; ++n) {
        const __half* __restrict__ xr = xin + (size_t)idxs[n] * X16S;
        const float4 f4 = *reinterpret_cast<const float4*>(xr + g8 * 8);
        const __half2* h2 = reinterpret_cast<const __half2*>(&f4);
        #pragma unroll
        for (int q = 0; q < 4; ++q) {
            const float2 v = __half22float2(h2[q]);
            r[q].x += v.x; r[q].y += v.y;
        }
        if (g8 < 2) {
            const float4 g4 = *reinterpret_cast<const float4*>(xr + 64 + g8 * 8);
            const __half2* t2 = reinterpret_cast<const __half2*>(&g4);
            #pragma unroll
            for (int q = 0; q < 4; ++q) {
                const float2 v = __half22float2(t2[q]);
                r2[q].x += v.x; r2[q].y += v.y;
            }
        }
    }
    const int col = ai ^ (g8 << 3);
    #pragma unroll
    for (int q = 0; q < 4; ++q) {
        const int k = 8 * g8 + 2 * q;
        s_rel[(k + 0) * 64 + col] = r[q].x;
        s_rel[(k + 1) * 64 + col] = r[q].y;
    }
    if (g8 < 2) {
        #pragma unroll
        for (int q = 0; q < 4; ++q) {
            const int k = 64 + 8 * g8 + 2 * q;
            if (k < 75)     s_rel[(k + 0) * 64 + col] = r2[q].x;
            if (k + 1 < 75) s_rel[(k + 1) * 64 + col] = r2[q].y;
        }
    }
}

__device__ __forceinline__ void stage_rel75_rt_v(const __half* __restrict__ xin,
                                                 const int* __restrict__ ad, int d,
                                                 int j0, int ai, int g8, float* __restrict__ s_rel)
{
    int idxs[10];
    for (int n = 0; n < d; ++n) idxs[n] = ad[(size_t)(j0 + ai) * d + n];
    float2 r[4], r2[4];
    #pragma unroll
    for (int q = 0; q < 4; ++q) { r[q] = make_float2(0.f, 0.f); r2[q] = make_float2(0.f, 0.f); }
    for (int n = 0; n < d; ++n) {
        const __half* __restrict__ xr = xin + (size_t)idxs[n] * X16S;
        const float4 f4 = *reinterpret_cast<const float4*>(xr + g8 * 8);
        const __half2* h2 = reinterpret_cast<const __half2*>(&f4);
        #pragma unroll
        for (int q = 0; q < 4; ++q) {
            const float2 v = __half22float2(h2[q]);
            r[q].x += v.x; r[q].y += v.y;
        }
        if (g8 < 2) {
            const float4 g4 = *reinterpret_cast<const float4*>(xr + 64 + g8 * 8);
            const __half2* t2 = reinterpret_cast<const __half2*>(&g4);
            #pragma unroll
            for (int q = 0; q < 4; ++q) {
                const float2 v = __half22float2(t2[q]);
                r2[q].x += v.x; r2[q].y += v.y;
            }
        }
    }
    const int col = ai ^ (g8 << 3);
    #pragma unroll
    for (int q = 0; q < 4; ++q) {
        const int k = 8 * g8 + 2 * q;
        s_rel[(k + 0) * 64 + col] = r[q].x;
        s_rel[(k + 1) * 64 + col] = r[q].y;
    }
    if (g8 < 2) {
        #pragma unroll
        for (int q = 0; q < 4; ++q) {
            const int k = 64 + 8 * g8 + 2 * q;
            if (k < 75)     s_rel[(k + 0) * 64 + col] = r2[q].x;
            if (k + 1 < 75) s_rel[(k + 1) * 64 + col] = r2[q].y;
        }
    }
}

// ---------------------------------------------------------------------------
// Merged conv layer: 64-atom tile, 512 threads, ONE 16B fp16 load per lane
// per gathered row (request-rate bound path: r15 confirmed 4x fewer gather
// instructions -> 505->360us). Scalar weights, fp32 accumulate, fp16 act.
// ---------------------------------------------------------------------------
template<int CI>
__global__ __launch_bounds__(512) void conv_all_kernel(
    const __half* __restrict__ xin, AdjPtrs adj,
    const float* __restrict__ W, const float* __restrict__ B,
    const float* __restrict__ bng, const float* __restrict__ bnb,
    const float* __restrict__ bnm, const float* __restrict__ bnv,
    __half* __restrict__ out)
{
    constexpr int XS = (CI == 64) ? 64 : X16S;
    constexpr int SM = (2 * CI * 64 > 64 * 65) ? 2 * CI * 64 : 64 * 65;
    __shared__ __align__(16) float smem[SM];
    float* s_self = smem;            // [CI][64]
    float* s_rel  = smem + CI * 64;  // [CI][64]

    int d = 0, rem = blockIdx.x;
    for (;;) { const int nb = (kCounts[d] + 63) >> 6; if (rem < nb) break; rem -= nb; ++d; }
    const int j0 = rem << 6;
    const int nA = min(64, kCounts[d] - j0);
    const int a0 = kStarts[d] + j0;
    const int t = threadIdx.x;

    // ---- stage self rows: 8 lanes/row, one float4 (+tail) each ----
    {
        const int row = t >> 3, l8 = t & 7;
        if (row < nA) {
            const __half* __restrict__ xr = xin + (size_t)(a0 + row) * XS;
            const float4 f4 = *reinterpret_cast<const float4*>(xr + l8 * 8);
            const __half2* h2 = reinterpret_cast<const __half2*>(&f4);
            const int col = row ^ (l8 << 3);
            #pragma unroll
            for (int q = 0; q < 4; ++q) {
                const float2 f = __half22float2(h2[q]);
                const int k = 8 * l8 + 2 * q;
                s_self[(k + 0) * 64 + col] = f.x;
                s_self[(k + 1) * 64 + col] = f.y;
            }
            if (CI == 75 && l8 < 2) {
                const float4 g4 = *reinterpret_cast<const float4*>(xr + 64 + l8 * 8);
                const __half2* t2 = reinterpret_cast<const __half2*>(&g4);
                #pragma unroll
                for (int q = 0; q < 4; ++q) {
                    const float2 f = __half22float2(t2[q]);
                    const int k = 64 + 8 * l8 + 2 * q;
                    if (k < 75)     s_self[(k + 0) * 64 + col] = f.x;
                    if (k + 1 < 75) s_self[(k + 1) * 64 + col] = f.y;
                }
            }
        }
    }

    // ---- stage neighbor sums (8 lanes/atom, one 16B load per row) ----
    if (d > 0) {
        const int ai = t >> 3, g8 = t & 7;
        if (ai < nA) {
            const int* __restrict__ adp = adj.p[d - 1];
            if constexpr (CI == 64) {
                switch (d) {
                case 1: stage_rel64_v<1>(xin, adp, j0, ai, g8, s_rel); break;
                case 2: stage_rel64_v<2>(xin, adp, j0, ai, g8, s_rel); break;
                case 3: stage_rel64_v<3>(xin, adp, j0, ai, g8, s_rel); break;
                case 4: stage_rel64_v<4>(xin, adp, j0, ai, g8, s_rel); break;
                default: stage_rel64_rt_v(xin, adp, d, j0, ai, g8, s_rel); break;
                }
            } else {
                switch (d) {
                case 1: stage_rel75_v<1>(xin, adp, j0, ai, g8, s_rel); break;
                case 2: stage_rel75_v<2>(xin, adp, j0, ai, g8, s_rel); break;
                case 3: stage_rel75_v<3>(xin, adp, j0, ai, g8, s_rel); break;
                case 4: stage_rel75_v<4>(xin, adp, j0, ai, g8, s_rel); break;
                default: stage_rel75_rt_v(xin, adp, d, j0, ai, g8, s_rel); break;
                }
            }
        }
    }
    __syncthreads();

    // ---- compute: atom-per-lane, 8 channels/thread, scalar weights ----
    const int a  = t & 63;
    const int c0 = __builtin_amdgcn_readfirstlane(t >> 6) * 8;   // wave-uniform

    float acc[8];
    #pragma unroll
    for (int j = 0; j < 8; ++j) acc[j] = 0.f;

    if (d == 0) {
        const float* __restrict__ Ws = W + (size_t)(2 * 10) * CI * 64;
        #pragma unroll
        for (int k = 0; k < CI; ++k) {
            const float xs = s_self[k * 64 + (a ^ (((k >> 3) & 7) << 3))];
            #pragma unroll
            for (int j = 0; j < 8; ++j)
                acc[j] = fmaf(xs, Ws[k * 64 + c0 + j], acc[j]);
        }
    } else {
        const float* __restrict__ Wr = W + (size_t)(2 * (d - 1)) * CI * 64;
        const float* __restrict__ Ws = W + (size_t)(2 * d - 1) * CI * 64;
        #pragma unroll
        for (int k = 0; k < CI; ++k) {
            const int col = a ^ (((k >> 3) & 7) << 3);
            const float xs = s_self[k * 64 + col];
            const float xr = s_rel [k * 64 + col];
            #pragma unroll
            for (int j = 0; j < 8; ++j)
                acc[j] = fmaf(xs, Ws[k * 64 + c0 + j],
                              fmaf(xr, Wr[k * 64 + c0 + j], acc[j]));
        }
    }

    // ---- epilogue: scalar bias/BN, rotated-LDS transpose, fp16 store ----
    __syncthreads();
    float* vout = smem;       // [64][65]
    #pragma unroll
    for (int j = 0; j < 8; ++j) {
        const int c = c0 + j;                               // wave-uniform
        const float bias = (d == 0) ? B[20 * 64 + c]
                                    : (B[(2 * (d - 1)) * 64 + c] + B[(2 * d - 1) * 64 + c]);
        const float scl = rsqrtf(bnv[c] + 1e-3f) * bng[c];
        const float sht = bnb[c] - bnm[c] * scl;
        vout[a * 65 + c] = fmaf(fmaxf(acc[j] + bias, 0.f), scl, sht);
    }
    __syncthreads();
    const int cc = t & 63, g = t >> 6;
    #pragma unroll
    for (int i = 0; i < 8; ++i) {
        const int row = g * 8 + i;
        if (row < nA) out[(size_t)(a0 + row) * 64 + cc] = __float2half(vout[row * 65 + cc]);
    }
}

// ---------------------------------------------------------------------------
// Merged pool layer (fp16), conv-style gather: 8 lanes/atom, ONE float4
// (8 halves) per lane per row -> one VMEM instruction covers 8 rows (r15's
// old layout used 1 instruction PER row: 8x more requests on the proven
// request-rate-bound path). 32 atoms per 256-thread block; packed stores.
// ---------------------------------------------------------------------------
template<int D>
__device__ __forceinline__ void pool_rows(const __half* __restrict__ z,
                                          const int* __restrict__ ad, int j, int g8,
                                          float2 mx[4])
{
    int idxs[D];
    #pragma unroll
    for (int n = 0; n < D; ++n) idxs[n] = ad[(size_t)j * D + n];
    for (int n = 0; n < D; ++n) {
        const float4 f4 = *reinterpret_cast<const float4*>(z + (size_t)idxs[n] * 64 + g8 * 8);
        const __half2* h2 = reinterpret_cast<const __half2*>(&f4);
        #pragma unroll
        for (int q = 0; q < 4; ++q) {
            const float2 v = __half22float2(h2[q]);
            mx[q].x = fmaxf(mx[q].x, v.x);
            mx[q].y = fmaxf(mx[q].y, v.y);
        }
    }
}

__device__ __forceinline__ void pool_rows_rt(const __half* __restrict__ z,
                                             const int* __restrict__ ad, int d, int j, int g8,
                                             float2 mx[4])
{
    int idxs[10];
    for (int n = 0; n < d; ++n) idxs[n] = ad[(size_t)j * d + n];
    for (int n = 0; n < d; ++n) {
        const float4 f4 = *reinterpret_cast<const float4*>(z + (size_t)idxs[n] * 64 + g8 * 8);
        const __half2* h2 = reinterpret_cast<const __half2*>(&f4);
        #pragma unroll
        for (int q = 0; q < 4; ++q) {
            const float2 v = __half22float2(h2[q]);
            mx[q].x = fmaxf(mx[q].x, v.x);
            mx[q].y = fmaxf(mx[q].y, v.y);
        }
    }
}

__global__ __launch_bounds__(256) void pool_all_kernel(
    const __half* __restrict__ z, AdjPtrs adj, __half* __restrict__ p)
{
    int d = 0, rem = blockIdx.x;
    for (;;) { const int nb = (kCounts[d] + 31) >> 5; if (rem < nb) break; rem -= nb; ++d; }
    const int t = threadIdx.x;
    const int j = rem * 32 + (t >> 3);
    if (j >= kCounts[d]) return;
    const int g8 = t & 7;
    const int a = kStarts[d] + j;

    const float4 s4 = *reinterpret_cast<const float4*>(z + (size_t)a * 64 + g8 * 8);
    const __half2* sh2 = reinterpret_cast<const __half2*>(&s4);
    float2 mx[4];
    #pragma unroll
    for (int q = 0; q < 4; ++q) mx[q] = __half22float2(sh2[q]);

    if (d > 0) {
        const int* __restrict__ ad = adj.p[d - 1];
        switch (d) {
        case 1:  pool_rows<1 >(z, ad, j, g8, mx); break;
        case 2:  pool_rows<2 >(z, ad, j, g8, mx); break;
        case 3:  pool_rows<3 >(z, ad, j, g8, mx); break;
        case 4:  pool_rows<4 >(z, ad, j, g8, mx); break;
        default: pool_rows_rt(z, ad, d, j, g8, mx); break;
        }
    }

    union { __half2 h[4]; float4 f; } u;
    #pragma unroll
    for (int q = 0; q < 4; ++q) u.h[q] = __floats2half2_rn(mx[q].x, mx[q].y);
    *reinterpret_cast<float4*>(p + (size_t)a * 64 + g8 * 8) = u.f;
}

// ---------------------------------------------------------------------------
// Counting sort by membership: hist -> scan -> scatter (+ per-position seg id).
// ---------------------------------------------------------------------------
__global__ __launch_bounds__(256) void hist_kernel(const int* __restrict__ mem,
                                                   int* __restrict__ cnt)
{
    const int a = blockIdx.x * 256 + threadIdx.x;
    if (a < NATOMS) atomicAdd(&cnt[mem[a]], 1);
}

__global__ __launch_bounds__(512) void scan_kernel(const int* __restrict__ cnt,
                                                   int* __restrict__ off,
                                                   int* __restrict__ cur)
{
    __shared__ int part[512];
    const int t = threadIdx.x;
    const int base = t * 64;
    int s = 0;
    #pragma unroll 8
    for (int i = 0; i < 64; ++i) s += cnt[base + i];
    part[t] = s;
    __syncthreads();
    for (int o = 1; o < 512; o <<= 1) {
        int v = (t >= o) ? part[t - o] : 0;
        __syncthreads();
        part[t] += v;
        __syncthreads();
    }
    int run = (t == 0) ? 0 : part[t - 1];
    for (int i = 0; i < 64; ++i) {
        off[base + i] = run;
        cur[base + i] = run;
        run += cnt[base + i];
    }
}

__global__ __launch_bounds__(256) void scatter_kernel(const int* __restrict__ mem,
                                                      int* __restrict__ cur,
                                                      int* __restrict__ sorted,
                                                      int* __restrict__ sid)
{
    const int a = blockIdx.x * 256 + threadIdx.x;
    if (a < NATOMS) {
        const int m = mem[a];
        const int pos = atomicAdd(&cur[m], 1);
        sorted[pos] = a;
        sid[pos] = m;
    }
}

__global__ void seg_init_kernel(float* __restrict__ segS, unsigned* __restrict__ segM)
{
    const int n = NBATCH * 128;
    for (int i = blockIdx.x * blockDim.x + threadIdx.x; i < n; i += gridDim.x * blockDim.x) {
        segS[i] = 0.f;
        segM[i] = 0x007FFFFFu; // enc(-inf)
    }
}

// ---------------------------------------------------------------------------
// Dense 64->128 + ReLU + BN2 over SORTED atoms (fp16 rows, 8 lanes/row 16B
// gather loads) + fused segmented sum/max epilogue.
// ---------------------------------------------------------------------------
__global__ __launch_bounds__(256) void dense_seg_sorted_kernel(
    const __half* __restrict__ p,
    const int* __restrict__ sorted, const int* __restrict__ sid,
    const float* __restrict__ Wd, const float* __restrict__ bd,
    const float* __restrict__ bng, const float* __restrict__ bnb,
    const float* __restrict__ bnm, const float* __restrict__ bnv,
    float* __restrict__ segS, unsigned* __restrict__ segM)
{
    __shared__ __align__(16) float s_p[64][64];   // staging; reused as v-buffer
    __shared__ int s_idx[64];
    __shared__ int s_sid[64];

    const int t = threadIdx.x;
    const int pos0 = blockIdx.x * 64;   // NATOMS = 15625 * 64 exactly

    if (t < 64) {
        s_idx[t] = sorted[pos0 + t];
        s_sid[t] = sid[pos0 + t];
    }
    __syncthreads();

    {
        const int row = t >> 3, l8 = t & 7;   // rows 0..31
        #pragma unroll
        for (int half = 0; half < 2; ++half) {
            const int rr = row + half * 32;
            const float4 f4 = *reinterpret_cast<const float4*>(p + (size_t)s_idx[rr] * 64 + l8 * 8);
            const __half2* h2 = reinterpret_cast<const __half2*>(&f4);
            #pragma unroll
            for (int q = 0; q < 4; ++q) {
                const float2 f = __half22float2(h2[q]);
                const int k = 8 * l8 + 2 * q;
                s_p[k + 0][swzS64d(rr, k + 0)] = f.x;
                s_p[k + 1][swzS64d(rr, k + 1)] = f.y;
            }
        }
    }
    __syncthreads();

    const int ccol = (t & 31) * 4;   // 4 consecutive output channels
    const int rgrp = t >> 5;         // 8 rows: rgrp*8 .. rgrp*8+7

    float acc[8][4];
    #pragma unroll
    for (int i = 0; i < 8; ++i)
        #pragma unroll
        for (int j = 0; j < 4; ++j) acc[i][j] = 0.f;

    for (int k = 0; k < 64; ++k) {
        const float4 w = *reinterpret_cast<const float4*>(Wd + (size_t)k * 128 + ccol);
        const int sw = ((k >> 2) & 7) << 2;
        #pragma unroll
        for (int h = 0; h < 2; ++h) {
            const float4 rv = *reinterpret_cast<const float4*>(&s_p[k][(rgrp * 8 + h * 4) ^ sw]);
            const float rr[4] = {rv.x, rv.y, rv.z, rv.w};
            #pragma unroll
            for (int j = 0; j < 4; ++j) {
                acc[h*4+j][0] = fmaf(rr[j], w.x, acc[h*4+j][0]);
                acc[h*4+j][1] = fmaf(rr[j], w.y, acc[h*4+j][1]);
                acc[h*4+j][2] = fmaf(rr[j], w.z, acc[h*4+j][2]);
                acc[h*4+j][3] = fmaf(rr[j], w.w, acc[h*4+j][3]);
            }
        }
    }

    {
        const float4 bb = *reinterpret_cast<const float4*>(bd + ccol);
        const float4 gg = *reinterpret_cast<const float4*>(bng + ccol);
        const float4 be = *reinterpret_cast<const float4*>(bnb + ccol);
        const float4 mm = *reinterpret_cast<const float4*>(bnm + ccol);
        const float4 vv = *reinterpret_cast<const float4*>(bnv + ccol);
        const float bia[4] = {bb.x, bb.y, bb.z, bb.w};
        float sc[4], sh[4];
        sc[0] = rsqrtf(vv.x + 1e-3f) * gg.x; sh[0] = be.x - mm.x * sc[0];
        sc[1] = rsqrtf(vv.y + 1e-3f) * gg.y; sh[1] = be.y - mm.y * sc[1];
        sc[2] = rsqrtf(vv.z + 1e-3f) * gg.z; sh[2] = be.z - mm.z * sc[2];
        sc[3] = rsqrtf(vv.w + 1e-3f) * gg.w; sh[3] = be.w - mm.w * sc[3];
        #pragma unroll
        for (int i = 0; i < 8; ++i)
            #pragma unroll
            for (int j = 0; j < 4; ++j)
                acc[i][j] = fmaf(fmaxf(acc[i][j] + bia[j], 0.f), sc[j], sh[j]);
    }

    __syncthreads();   // all GEMM reads of s_p complete -> safe to overwrite

    float (*vbuf)[64] = s_p;
    const int halfSel = ccol >> 6;
    const int cc = ccol & 63;

    #pragma unroll
    for (int half = 0; half < 2; ++half) {
        if (halfSel == half) {
            #pragma unroll
            for (int i = 0; i < 8; ++i) {
                float4 o = make_float4(acc[i][0], acc[i][1], acc[i][2], acc[i][3]);
                *reinterpret_cast<float4*>(&vbuf[rgrp * 8 + i][cc]) = o;
            }
        }
        __syncthreads();

        const int c = t & 63;
        const int rbase = (t >> 6) * 16;
        const int gch = half * 64 + c;
        int cur = s_sid[rbase];
        float s = 0.f, mx = -INFINITY;
        for (int r = rbase; r < rbase + 16; ++r) {
            const int sd = s_sid[r];
            if (sd != cur) {
                atomicAdd(&segS[(size_t)cur * 128 + gch], s);
                atomicMax(&segM[(size_t)cur * 128 + gch], enc_f32(mx));
                cur = sd; s = 0.f; mx = -INFINITY;
            }
            const float v = vbuf[r][c];
            s += v;
            mx = fmaxf(mx, v);
        }
        atomicAdd(&segS[(size_t)cur * 128 + gch], s);
        atomicMax(&segM[(size_t)cur * 128 + gch], enc_f32(mx));
        __syncthreads();
    }
}

__global__ void nf_fin_kernel(const float* __restrict__ segS,
                              const unsigned* __restrict__ segM,
                              float* __restrict__ nf)
{
    const int i = blockIdx.x * blockDim.x + threadIdx.x; // < NBATCH*128
    const int m = i >> 7, c = i & 127;
    nf[(size_t)m * 256 + c]       = tanhf(segS[i]);
    nf[(size_t)m * 256 + 128 + c] = tanhf(dec_f32(segM[i]));
}

// fd0: h = relu(nf @ W + b), 32768x256 @ 256x256. 64x64 tile per block.
__global__ __launch_bounds__(256) void fd0_kernel(
    const float* __restrict__ nf, const float* __restrict__ W, const float* __restrict__ b,
    float* __restrict__ h)
{
    __shared__ __align__(16) float sx[256][64];
    const int t = threadIdx.x;
    const int r0 = (blockIdx.x >> 2) * 64;
    const int c0 = (blockIdx.x & 3) * 64;
    for (int ch = 0; ch < 4; ++ch) {
        for (int v = t; v < 1024; v += 256) {
            const int row = v >> 4, k0 = (v & 15) * 4 + ch * 64;
            const float4 r = *reinterpret_cast<const float4*>(nf + (size_t)(r0 + row) * 256 + k0);
            sx[k0 + 0][swzS64d(row, k0 + 0)] = r.x;
            sx[k0 + 1][swzS64d(row, k0 + 1)] = r.y;
            sx[k0 + 2][swzS64d(row, k0 + 2)] = r.z;
            sx[k0 + 3][swzS64d(row, k0 + 3)] = r.w;
        }
    }
    __syncthreads();

    const int c4 = (t & 15) * 4;
    const int a4 = (t >> 4) * 4;

    float acc[4][4];
    #pragma unroll
    for (int i = 0; i < 4; ++i)
        #pragma unroll
        for (int j = 0; j < 4; ++j) acc[i][j] = 0.f;

    for (int k = 0; k < 256; ++k) {
        const int sw = ((k >> 2) & 7) << 2;
        const float4 sv = *reinterpret_cast<const float4*>(&sx[k][a4 ^ sw]);
        const float4 w = *reinterpret_cast<const float4*>(W + (size_t)k * 256 + c0 + c4);
        const float ss[4] = {sv.x, sv.y, sv.z, sv.w};
        #pragma unroll
        for (int i = 0; i < 4; ++i) {
            acc[i][0] = fmaf(ss[i], w.x, acc[i][0]);
            acc[i][1] = fmaf(ss[i], w.y, acc[i][1]);
            acc[i][2] = fmaf(ss[i], w.z, acc[i][2]);
            acc[i][3] = fmaf(ss[i], w.w, acc[i][3]);
        }
    }

    const float4 bb = *reinterpret_cast<const float4*>(b + c0 + c4);
    const float bi[4] = {bb.x, bb.y, bb.z, bb.w};
    #pragma unroll
    for (int i = 0; i < 4; ++i) {
        float4 o;
        o.x = fmaxf(acc[i][0] + bi[0], 0.f);
        o.y = fmaxf(acc[i][1] + bi[1], 0.f);
        o.z = fmaxf(acc[i][2] + bi[2], 0.f);
        o.w = fmaxf(acc[i][3] + bi[3], 0.f);
        *reinterpret_cast<float4*>(h + (size_t)(r0 + a4 + i) * 256 + c0 + c4) = o;
    }
}

// rd: logits = h @ W + b (256->24), then pairwise softmax.
__global__ __launch_bounds__(384) void rd_kernel(
    const float* __restrict__ h, const float* __restrict__ W, const float* __restrict__ b,
    float* __restrict__ outP, float* __restrict__ outL)
{
    __shared__ float sh[32][257];
    const int t = threadIdx.x;
    const int r0 = blockIdx.x * 32;
    for (int e = t; e < 32 * 256; e += 384) {
        const int ri = e >> 8, k = e & 255;
        sh[ri][k] = h[(size_t)(r0 + ri) * 256 + k];
    }
    __syncthreads();
    const int r = t / 12, pj = t % 12;
    float a0 = b[2 * pj], a1 = b[2 * pj + 1];
    for (int k = 0; k < 256; ++k) {
        const float hv = sh[r][k];
        a0 = fmaf(hv, W[k * 24 + 2 * pj],     a0);
        a1 = fmaf(hv, W[k * 24 + 2 * pj + 1], a1);
    }
    const size_t m = (size_t)(r0 + r);
    outL[m * 24 + 2 * pj]     = a0;
    outL[m * 24 + 2 * pj + 1] = a1;
    const float mx = fmaxf(a0, a1);
    const float e0 = expf(a0 - mx), e1 = expf(a1 - mx);
    const float inv = 1.f / (e0 + e1);
    outP[m * 24 + 2 * pj]     = e0 * inv;
    outP[m * 24 + 2 * pj + 1] = e1 * inv;
}

} // namespace

extern "C" void kernel_launch(void* const* d_in, const int* in_sizes, int n_in,
                              void* d_out, int out_size, void* d_ws, size_t ws_size,
                              hipStream_t stream)
{
    const float* x       = (const float*)d_in[0];
    const int*   mem     = (const int*)d_in[2];
    AdjPtrs adj;
    for (int d = 0; d < 10; ++d) adj.p[d] = (const int*)d_in[4 + d];
    const float* gc0_W = (const float*)d_in[14];
    const float* gc0_b = (const float*)d_in[15];
    const float* gc1_W = (const float*)d_in[16];
    const float* gc1_b = (const float*)d_in[17];
    const float* bn0g = (const float*)d_in[18], *bn0b = (const float*)d_in[19];
    const float* bn0m = (const float*)d_in[20], *bn0v = (const float*)d_in[21];
    const float* bn1g = (const float*)d_in[22], *bn1b = (const float*)d_in[23];
    const float* bn1m = (const float*)d_in[24], *bn1v = (const float*)d_in[25];
    const float* bn2g = (const float*)d_in[26], *bn2b = (const float*)d_in[27];
    const float* bn2m = (const float*)d_in[28], *bn2v = (const float*)d_in[29];
    const float* dW   = (const float*)d_in[30], *db   = (const float*)d_in[31];
    const float* fW   = (const float*)d_in[32], *fb   = (const float*)d_in[33];
    const float* rW   = (const float*)d_in[34], *rb   = (const float*)d_in[35];

    __half* z16 = (__half*)d_ws;                               // 1M x 64
    __half* p16 = z16 + (size_t)NATOMS * 64;                   // 1M x 64
    __half* x16 = p16 + (size_t)NATOMS * 64;                   // 1M x 80
    float*  hbuf = (float*)(x16 + (size_t)NATOMS * X16S);
    float*  segS = hbuf + (size_t)NBATCH * 256;
    unsigned* segM = (unsigned*)(segS + (size_t)NBATCH * 128);
    int*    cnt    = (int*)(segM + (size_t)NBATCH * 128);
    int*    offp   = cnt + NBATCH;
    int*    cur    = offp + NBATCH;
    int*    sorted = cur + NBATCH;
    int*    sid    = sorted + NATOMS;

    float* outP = (float*)d_out;
    float* outL = outP + (size_t)NBATCH * 24;
    float* nfb  = outL + (size_t)NBATCH * 24;

    int convBlocks = 0, poolBlocks = 0;
    for (int d = 0; d <= 10; ++d) {
        convBlocks += (kCounts[d] + 63) >> 6;
        poolBlocks += (kCounts[d] + 31) >> 5;
    }

    // one-time fp16 conversion of x (padded rows)
    cvt_kernel<<<(NATOMS + 15) / 16, 256, 0, stream>>>(x, x16);

    // counting sort by membership + segment accumulator init
    hipMemsetAsync(cnt, 0, NBATCH * sizeof(int), stream);
    hist_kernel<<<(NATOMS + 255) / 256, 256, 0, stream>>>(mem, cnt);
    scan_kernel<<<1, 512, 0, stream>>>(cnt, offp, cur);
    scatter_kernel<<<(NATOMS + 255) / 256, 256, 0, stream>>>(mem, cur, sorted, sid);
    seg_init_kernel<<<2048, 256, 0, stream>>>(segS, segM);

    // layer 1: conv(75->64)+relu+bn0 -> pool
    conv_all_kernel<75><<<convBlocks, 512, 0, stream>>>(x16, adj, gc0_W, gc0_b,
                                                        bn0g, bn0b, bn0m, bn0v, z16);
    pool_all_kernel<<<poolBlocks, 256, 0, stream>>>(z16, adj, p16);

    // layer 2: conv(64->64)+relu+bn1 -> pool
    conv_all_kernel<64><<<convBlocks, 512, 0, stream>>>(p16, adj, gc1_W, gc1_b,
                                                        bn1g, bn1b, bn1m, bn1v, z16);
    pool_all_kernel<<<poolBlocks, 256, 0, stream>>>(z16, adj, p16);

    // dense+relu+bn2 over sorted atoms with fused segmented sum/max
    dense_seg_sorted_kernel<<<NATOMS / 64, 256, 0, stream>>>(
        p16, sorted, sid, dW, db, bn2g, bn2b, bn2m, bn2v, segS, segM);
    // nf = tanh(concat(sum, max))
    nf_fin_kernel<<<(NBATCH * 128) / 256, 256, 0, stream>>>(segS, segM, nfb);
    // h = relu(nf @ fd0_W + fd0_b)
    fd0_kernel<<<(NBATCH / 64) * 4, 256, 0, stream>>>(nfb, fW, fb, hbuf);
    // logits + softmax
    rd_kernel<<<NBATCH / 32, 384, 0, stream>>>(hbuf, rW, rb, outP, outL);
}

// Round 17
// 1317.349 us; speedup vs baseline: 1.5453x; 1.0946x over previous
//
#include <hip/hip_runtime.h>
#include <hip/hip_fp16.h>
#include <math.h>

namespace {

constexpr int NATOMS = 1000000;
constexpr int NBATCH = 32768;
constexpr int kCounts[11] = {10000,250000,300000,250000,120000,40000,15000,8000,4000,2000,1000};
constexpr int kStarts[11] = {0,10000,260000,560000,810000,930000,970000,985000,993000,997000,999000};
constexpr int X16S = 80;   // padded fp16 row stride for x (75 ch -> 160B rows)

struct AdjPtrs { const int* p[10]; };

typedef _Float16 h2 __attribute__((ext_vector_type(2)));
union U32H2 { unsigned u; h2 h; };

__device__ __forceinline__ unsigned enc_f32(float x) {
    unsigned u = __float_as_uint(x);
    return (u & 0x80000000u) ? ~u : (u | 0x80000000u);
}
__device__ __forceinline__ float dec_f32(unsigned u) {
    return (u & 0x80000000u) ? __uint_as_float(u & 0x7FFFFFFFu) : __uint_as_float(~u);
}

// dense_seg/fd0 64-wide fp32 tiles (row stride 64 -> bank=col&31):
__device__ __forceinline__ int swzS64d(int row, int k) { return row ^ (((k >> 2) & 7) << 2); }

// Conv LDS (half2 tiles [k2][64] u32, row stride 64 words -> bank = col&31):
//   col(k2, a) = a ^ (((k2>>2)&7)<<3)
// Staging (8 lanes/row, lane l8 owns k2 = 4*l8..4*l8+3): bank = row(3b) ^
// ((l8&3)<<3) -> 32 banks, 2-way. Compute reads bijective -> 2-way.

// ---------------------------------------------------------------------------
// x fp32 [1M][75] -> x16 fp16 [1M][80] (zero-padded). 16 rows per block.
// ---------------------------------------------------------------------------
__global__ __launch_bounds__(256) void cvt_kernel(const float* __restrict__ x,
                                                  __half* __restrict__ x16)
{
    const int row = blockIdx.x * 16 + (threadIdx.x >> 4);
    const int l16 = threadIdx.x & 15;
    if (row >= NATOMS) return;
    const float* __restrict__ xr = x + (size_t)row * 75;
    __half* __restrict__ xo = x16 + (size_t)row * X16S;
    #pragma unroll
    for (int q = 0; q < 5; ++q) {
        const int c = l16 + 16 * q;
        xo[c] = __float2half((c < 75) ? xr[c] : 0.f);
    }
}

// ---------------------------------------------------------------------------
// Weights fp32 [21][CI][64] -> half2 k-pairs [21][K2][64] (zero-pad odd CI).
// ---------------------------------------------------------------------------
__global__ __launch_bounds__(256) void cvtW_kernel(const float* __restrict__ W,
                                                   unsigned* __restrict__ Wh,
                                                   int CI, int K2)
{
    const int total = 21 * K2 * 64;
    for (int i = blockIdx.x * 256 + threadIdx.x; i < total; i += gridDim.x * 256) {
        const int m = i / (K2 * 64);
        const int r = i - m * (K2 * 64);
        const int k2 = r >> 6, c = r & 63;
        const float a = W[((size_t)m * CI + 2 * k2) * 64 + c];
        const float b = (2 * k2 + 1 < CI) ? W[((size_t)m * CI + 2 * k2 + 1) * 64 + c] : 0.f;
        U32H2 u;
        u.h = h2{(_Float16)a, (_Float16)b};
        Wh[i] = u.u;
    }
}

// ---------------------------------------------------------------------------
// rel-staging: 8 lanes/atom; ONE float4 (8 halves = 4 k-pairs) per lane per
// neighbor row; fp32 accumulate, half2 LDS store.
// ---------------------------------------------------------------------------
template<int D>
__device__ __forceinline__ void stage_rel64_v(const __half* __restrict__ xin,
                                              const int* __restrict__ ad,
                                              int j0, int ai, int g8, unsigned* __restrict__ s_rel)
{
    int idxs[D];
    #pragma unroll
    for (int n = 0; n < D; ++n) idxs[n] = ad[(size_t)(j0 + ai) * D + n];
    float2 r[4];
    #pragma unroll
    for (int q = 0; q < 4; ++q) r[q] = make_float2(0.f, 0.f);
    for (int n = 0; n < D; ++n) {
        const float4 f4 = *reinterpret_cast<const float4*>(xin + (size_t)idxs[n] * 64 + g8 * 8);
        const __half2* hh = reinterpret_cast<const __half2*>(&f4);
        #pragma unroll
        for (int q = 0; q < 4; ++q) {
            const float2 v = __half22float2(hh[q]);
            r[q].x += v.x; r[q].y += v.y;
        }
    }
    const int col = ai ^ (g8 << 3);
    #pragma unroll
    for (int q = 0; q < 4; ++q) {
        U32H2 u; u.h = h2{(_Float16)r[q].x, (_Float16)r[q].y};
        s_rel[(4 * g8 + q) * 64 + col] = u.u;
    }
}

__device__ __forceinline__ void stage_rel64_rt_v(const __half* __restrict__ xin,
                                                 const int* __restrict__ ad, int d,
                                                 int j0, int ai, int g8, unsigned* __restrict__ s_rel)
{
    int idxs[10];
    for (int n = 0; n < d; ++n) idxs[n] = ad[(size_t)(j0 + ai) * d + n];
    float2 r[4];
    #pragma unroll
    for (int q = 0; q < 4; ++q) r[q] = make_float2(0.f, 0.f);
    for (int n = 0; n < d; ++n) {
        const float4 f4 = *reinterpret_cast<const float4*>(xin + (size_t)idxs[n] * 64 + g8 * 8);
        const __half2* hh = reinterpret_cast<const __half2*>(&f4);
        #pragma unroll
        for (int q = 0; q < 4; ++q) {
            const float2 v = __half22float2(hh[q]);
            r[q].x += v.x; r[q].y += v.y;
        }
    }
    const int col = ai ^ (g8 << 3);
    #pragma unroll
    for (int q = 0; q < 4; ++q) {
        U32H2 u; u.h = h2{(_Float16)r[q].x, (_Float16)r[q].y};
        s_rel[(4 * g8 + q) * 64 + col] = u.u;
    }
}

template<int D>
__device__ __forceinline__ void stage_rel75_v(const __half* __restrict__ xin,
                                              const int* __restrict__ ad,
                                              int j0, int ai, int g8, unsigned* __restrict__ s_rel)
{
    int idxs[D];
    #pragma unroll
    for (int n = 0; n < D; ++n) idxs[n] = ad[(size_t)(j0 + ai) * D + n];
    float2 r[4], r2[4];
    #pragma unroll
    for (int q = 0; q < 4; ++q) { r[q] = make_float2(0.f, 0.f); r2[q] = make_float2(0.f, 0.f); }
    for (int n = 0; n < D; ++n) {
        const __half* __restrict__ xr = xin + (size_t)idxs[n] * X16S;
        const float4 f4 = *reinterpret_cast<const float4*>(xr + g8 * 8);
        const __half2* hh = reinterpret_cast<const __half2*>(&f4);
        #pragma unroll
        for (int q = 0; q < 4; ++q) {
            const float2 v = __half22float2(hh[q]);
            r[q].x += v.x; r[q].y += v.y;
        }
        if (g8 < 2) {
            const float4 g4 = *reinterpret_cast<const float4*>(xr + 64 + g8 * 8);
            const __half2* t2 = reinterpret_cast<const __half2*>(&g4);
            #pragma unroll
            for (int q = 0; q < 4; ++q) {
                const float2 v = __half22float2(t2[q]);
                r2[q].x += v.x; r2[q].y += v.y;
            }
        }
    }
    const int col = ai ^ (g8 << 3);
    #pragma unroll
    for (int q = 0; q < 4; ++q) {
        U32H2 u; u.h = h2{(_Float16)r[q].x, (_Float16)r[q].y};
        s_rel[(4 * g8 + q) * 64 + col] = u.u;
    }
    if (g8 < 2) {
        #pragma unroll
        for (int q = 0; q < 4; ++q) {
            const int k2 = 32 + 4 * g8 + q;
            if (k2 < 38) {
                U32H2 u; u.h = h2{(_Float16)r2[q].x, (_Float16)r2[q].y};
                s_rel[k2 * 64 + col] = u.u;
            }
        }
    }
}

__device__ __forceinline__ void stage_rel75_rt_v(const __half* __restrict__ xin,
                                                 const int* __restrict__ ad, int d,
                                                 int j0, int ai, int g8, unsigned* __restrict__ s_rel)
{
    int idxs[10];
    for (int n = 0; n < d; ++n) idxs[n] = ad[(size_t)(j0 + ai) * d + n];
    float2 r[4], r2[4];
    #pragma unroll
    for (int q = 0; q < 4; ++q) { r[q] = make_float2(0.f, 0.f); r2[q] = make_float2(0.f, 0.f); }
    for (int n = 0; n < d; ++n) {
        const __half* __restrict__ xr = xin + (size_t)idxs[n] * X16S;
        const float4 f4 = *reinterpret_cast<const float4*>(xr + g8 * 8);
        const __half2* hh = reinterpret_cast<const __half2*>(&f4);
        #pragma unroll
        for (int q = 0; q < 4; ++q) {
            const float2 v = __half22float2(hh[q]);
            r[q].x += v.x; r[q].y += v.y;
        }
        if (g8 < 2) {
            const float4 g4 = *reinterpret_cast<const float4*>(xr + 64 + g8 * 8);
            const __half2* t2 = reinterpret_cast<const __half2*>(&g4);
            #pragma unroll
            for (int q = 0; q < 4; ++q) {
                const float2 v = __half22float2(t2[q]);
                r2[q].x += v.x; r2[q].y += v.y;
            }
        }
    }
    const int col = ai ^ (g8 << 3);
    #pragma unroll
    for (int q = 0; q < 4; ++q) {
        U32H2 u; u.h = h2{(_Float16)r[q].x, (_Float16)r[q].y};
        s_rel[(4 * g8 + q) * 64 + col] = u.u;
    }
    if (g8 < 2) {
        #pragma unroll
        for (int q = 0; q < 4; ++q) {
            const int k2 = 32 + 4 * g8 + q;
            if (k2 < 38) {
                U32H2 u; u.h = h2{(_Float16)r2[q].x, (_Float16)r2[q].y};
                s_rel[k2 * 64 + col] = u.u;
            }
        }
    }
}

// ---------------------------------------------------------------------------
// Merged conv layer: 64-atom tile, 512 threads, fp16 gathers (1 load/lane/row)
// + v_dot2_f32_f16 compute (2 MACs/instr, fp32 accumulate): halves VALU
// instruction count vs r16 (conv was ~50/50 gather-floor/VALU). half2 LDS
// halves tile to 19.4KB -> 32 waves/CU wave-cap.
// ---------------------------------------------------------------------------
template<int CI>
__global__ __launch_bounds__(512) void conv_all_kernel(
    const __half* __restrict__ xin, AdjPtrs adj,
    const unsigned* __restrict__ Wh, const float* __restrict__ B,
    const float* __restrict__ bng, const float* __restrict__ bnb,
    const float* __restrict__ bnm, const float* __restrict__ bnv,
    __half* __restrict__ out)
{
    constexpr int XS = (CI == 64) ? 64 : X16S;
    constexpr int K2 = (CI + 1) / 2;          // 38 / 32
    constexpr int SM = (2 * K2 * 64 > 64 * 65) ? 2 * K2 * 64 : 64 * 65;
    __shared__ __align__(16) unsigned smem[SM];
    unsigned* s_self = smem;             // [K2][64] half2
    unsigned* s_rel  = smem + K2 * 64;   // [K2][64] half2

    int d = 0, rem = blockIdx.x;
    for (;;) { const int nb = (kCounts[d] + 63) >> 6; if (rem < nb) break; rem -= nb; ++d; }
    const int j0 = rem << 6;
    const int nA = min(64, kCounts[d] - j0);
    const int a0 = kStarts[d] + j0;
    const int t = threadIdx.x;

    // ---- stage self rows: 8 lanes/row, one float4 (+tail) each ----
    {
        const int row = t >> 3, l8 = t & 7;
        if (row < nA) {
            const __half* __restrict__ xr = xin + (size_t)(a0 + row) * XS;
            const float4 f4 = *reinterpret_cast<const float4*>(xr + l8 * 8);
            const __half2* hh = reinterpret_cast<const __half2*>(&f4);
            const int col = row ^ (l8 << 3);
            #pragma unroll
            for (int q = 0; q < 4; ++q)
                s_self[(4 * l8 + q) * 64 + col] = reinterpret_cast<const unsigned*>(hh)[q];
            if (CI == 75 && l8 < 2) {
                const float4 g4 = *reinterpret_cast<const float4*>(xr + 64 + l8 * 8);
                #pragma unroll
                for (int q = 0; q < 4; ++q) {
                    const int k2 = 32 + 4 * l8 + q;
                    if (k2 < K2)
                        s_self[k2 * 64 + col] = reinterpret_cast<const unsigned*>(&g4)[q];
                }
            }
        }
    }

    // ---- stage neighbor sums (8 lanes/atom, one 16B load per row) ----
    if (d > 0) {
        const int ai = t >> 3, g8 = t & 7;
        if (ai < nA) {
            const int* __restrict__ adp = adj.p[d - 1];
            if constexpr (CI == 64) {
                switch (d) {
                case 1: stage_rel64_v<1>(xin, adp, j0, ai, g8, s_rel); break;
                case 2: stage_rel64_v<2>(xin, adp, j0, ai, g8, s_rel); break;
                case 3: stage_rel64_v<3>(xin, adp, j0, ai, g8, s_rel); break;
                case 4: stage_rel64_v<4>(xin, adp, j0, ai, g8, s_rel); break;
                default: stage_rel64_rt_v(xin, adp, d, j0, ai, g8, s_rel); break;
                }
            } else {
                switch (d) {
                case 1: stage_rel75_v<1>(xin, adp, j0, ai, g8, s_rel); break;
                case 2: stage_rel75_v<2>(xin, adp, j0, ai, g8, s_rel); break;
                case 3: stage_rel75_v<3>(xin, adp, j0, ai, g8, s_rel); break;
                case 4: stage_rel75_v<4>(xin, adp, j0, ai, g8, s_rel); break;
                default: stage_rel75_rt_v(xin, adp, d, j0, ai, g8, s_rel); break;
                }
            }
        }
    }
    __syncthreads();

    // ---- compute: atom-per-lane, 8 channels/thread, fdot2 scalar weights ----
    const int a  = t & 63;
    const int c0 = __builtin_amdgcn_readfirstlane(t >> 6) * 8;   // wave-uniform

    float acc[8];
    #pragma unroll
    for (int j = 0; j < 8; ++j) acc[j] = 0.f;

    if (d == 0) {
        const unsigned* __restrict__ Ws = Wh + (size_t)(2 * 10) * K2 * 64;
        #pragma unroll
        for (int k2 = 0; k2 < K2; ++k2) {
            U32H2 xs; xs.u = s_self[k2 * 64 + (a ^ (((k2 >> 2) & 7) << 3))];
            #pragma unroll
            for (int j = 0; j < 8; ++j) {
                U32H2 w; w.u = Ws[k2 * 64 + c0 + j];
                acc[j] = __builtin_amdgcn_fdot2(xs.h, w.h, acc[j], false);
            }
        }
    } else {
        const unsigned* __restrict__ Wr = Wh + (size_t)(2 * (d - 1)) * K2 * 64;
        const unsigned* __restrict__ Ws = Wh + (size_t)(2 * d - 1) * K2 * 64;
        #pragma unroll
        for (int k2 = 0; k2 < K2; ++k2) {
            const int col = a ^ (((k2 >> 2) & 7) << 3);
            U32H2 xs; xs.u = s_self[k2 * 64 + col];
            U32H2 xr; xr.u = s_rel [k2 * 64 + col];
            #pragma unroll
            for (int j = 0; j < 8; ++j) {
                U32H2 ws; ws.u = Ws[k2 * 64 + c0 + j];
                U32H2 wr; wr.u = Wr[k2 * 64 + c0 + j];
                acc[j] = __builtin_amdgcn_fdot2(xr.h, wr.h,
                          __builtin_amdgcn_fdot2(xs.h, ws.h, acc[j], false), false);
            }
        }
    }

    // ---- epilogue: scalar bias/BN, rotated-LDS transpose, fp16 store ----
    __syncthreads();
    float* vout = reinterpret_cast<float*>(smem);   // [64][65]
    #pragma unroll
    for (int j = 0; j < 8; ++j) {
        const int c = c0 + j;                               // wave-uniform
        const float bias = (d == 0) ? B[20 * 64 + c]
                                    : (B[(2 * (d - 1)) * 64 + c] + B[(2 * d - 1) * 64 + c]);
        const float scl = rsqrtf(bnv[c] + 1e-3f) * bng[c];
        const float sht = bnb[c] - bnm[c] * scl;
        vout[a * 65 + c] = fmaf(fmaxf(acc[j] + bias, 0.f), scl, sht);
    }
    __syncthreads();
    const int cc = t & 63, g = t >> 6;
    #pragma unroll
    for (int i = 0; i < 8; ++i) {
        const int row = g * 8 + i;
        if (row < nA) out[(size_t)(a0 + row) * 64 + cc] = __float2half(vout[row * 65 + cc]);
    }
}

// ---------------------------------------------------------------------------
// Merged pool layer (fp16), conv-style gather: 8 lanes/atom, ONE float4
// per lane per row; 32 atoms per block; packed fp16 stores.
// ---------------------------------------------------------------------------
template<int D>
__device__ __forceinline__ void pool_rows(const __half* __restrict__ z,
                                          const int* __restrict__ ad, int j, int g8,
                                          float2 mx[4])
{
    int idxs[D];
    #pragma unroll
    for (int n = 0; n < D; ++n) idxs[n] = ad[(size_t)j * D + n];
    for (int n = 0; n < D; ++n) {
        const float4 f4 = *reinterpret_cast<const float4*>(z + (size_t)idxs[n] * 64 + g8 * 8);
        const __half2* hh = reinterpret_cast<const __half2*>(&f4);
        #pragma unroll
        for (int q = 0; q < 4; ++q) {
            const float2 v = __half22float2(hh[q]);
            mx[q].x = fmaxf(mx[q].x, v.x);
            mx[q].y = fmaxf(mx[q].y, v.y);
        }
    }
}

__device__ __forceinline__ void pool_rows_rt(const __half* __restrict__ z,
                                             const int* __restrict__ ad, int d, int j, int g8,
                                             float2 mx[4])
{
    int idxs[10];
    for (int n = 0; n < d; ++n) idxs[n] = ad[(size_t)j * d + n];
    for (int n = 0; n < d; ++n) {
        const float4 f4 = *reinterpret_cast<const float4*>(z + (size_t)idxs[n] * 64 + g8 * 8);
        const __half2* hh = reinterpret_cast<const __half2*>(&f4);
        #pragma unroll
        for (int q = 0; q < 4; ++q) {
            const float2 v = __half22float2(hh[q]);
            mx[q].x = fmaxf(mx[q].x, v.x);
            mx[q].y = fmaxf(mx[q].y, v.y);
        }
    }
}

__global__ __launch_bounds__(256) void pool_all_kernel(
    const __half* __restrict__ z, AdjPtrs adj, __half* __restrict__ p)
{
    int d = 0, rem = blockIdx.x;
    for (;;) { const int nb = (kCounts[d] + 31) >> 5; if (rem < nb) break; rem -= nb; ++d; }
    const int t = threadIdx.x;
    const int j = rem * 32 + (t >> 3);
    if (j >= kCounts[d]) return;
    const int g8 = t & 7;
    const int a = kStarts[d] + j;

    const float4 s4 = *reinterpret_cast<const float4*>(z + (size_t)a * 64 + g8 * 8);
    const __half2* sh2 = reinterpret_cast<const __half2*>(&s4);
    float2 mx[4];
    #pragma unroll
    for (int q = 0; q < 4; ++q) mx[q] = __half22float2(sh2[q]);

    if (d > 0) {
        const int* __restrict__ ad = adj.p[d - 1];
        switch (d) {
        case 1:  pool_rows<1 >(z, ad, j, g8, mx); break;
        case 2:  pool_rows<2 >(z, ad, j, g8, mx); break;
        case 3:  pool_rows<3 >(z, ad, j, g8, mx); break;
        case 4:  pool_rows<4 >(z, ad, j, g8, mx); break;
        default: pool_rows_rt(z, ad, d, j, g8, mx); break;
        }
    }

    union { __half2 h[4]; float4 f; } u;
    #pragma unroll
    for (int q = 0; q < 4; ++q) u.h[q] = __floats2half2_rn(mx[q].x, mx[q].y);
    *reinterpret_cast<float4*>(p + (size_t)a * 64 + g8 * 8) = u.f;
}

// ---------------------------------------------------------------------------
// Counting sort by membership: hist -> scan -> scatter (+ per-position seg id).
// ---------------------------------------------------------------------------
__global__ __launch_bounds__(256) void hist_kernel(const int* __restrict__ mem,
                                                   int* __restrict__ cnt)
{
    const int a = blockIdx.x * 256 + threadIdx.x;
    if (a < NATOMS) atomicAdd(&cnt[mem[a]], 1);
}

__global__ __launch_bounds__(512) void scan_kernel(const int* __restrict__ cnt,
                                                   int* __restrict__ off,
                                                   int* __restrict__ cur)
{
    __shared__ int part[512];
    const int t = threadIdx.x;
    const int base = t * 64;
    int s = 0;
    #pragma unroll 8
    for (int i = 0; i < 64; ++i) s += cnt[base + i];
    part[t] = s;
    __syncthreads();
    for (int o = 1; o < 512; o <<= 1) {
        int v = (t >= o) ? part[t - o] : 0;
        __syncthreads();
        part[t] += v;
        __syncthreads();
    }
    int run = (t == 0) ? 0 : part[t - 1];
    for (int i = 0; i < 64; ++i) {
        off[base + i] = run;
        cur[base + i] = run;
        run += cnt[base + i];
    }
}

__global__ __launch_bounds__(256) void scatter_kernel(const int* __restrict__ mem,
                                                      int* __restrict__ cur,
                                                      int* __restrict__ sorted,
                                                      int* __restrict__ sid)
{
    const int a = blockIdx.x * 256 + threadIdx.x;
    if (a < NATOMS) {
        const int m = mem[a];
        const int pos = atomicAdd(&cur[m], 1);
        sorted[pos] = a;
        sid[pos] = m;
    }
}

__global__ void seg_init_kernel(float* __restrict__ segS, unsigned* __restrict__ segM)
{
    const int n = NBATCH * 128;
    for (int i = blockIdx.x * blockDim.x + threadIdx.x; i < n; i += gridDim.x * blockDim.x) {
        segS[i] = 0.f;
        segM[i] = 0x007FFFFFu; // enc(-inf)
    }
}

// ---------------------------------------------------------------------------
// Dense 64->128 + ReLU + BN2 over SORTED atoms (fp16 rows, 8 lanes/row 16B
// gather loads) + fused segmented sum/max epilogue.
// ---------------------------------------------------------------------------
__global__ __launch_bounds__(256) void dense_seg_sorted_kernel(
    const __half* __restrict__ p,
    const int* __restrict__ sorted, const int* __restrict__ sid,
    const float* __restrict__ Wd, const float* __restrict__ bd,
    const float* __restrict__ bng, const float* __restrict__ bnb,
    const float* __restrict__ bnm, const float* __restrict__ bnv,
    float* __restrict__ segS, unsigned* __restrict__ segM)
{
    __shared__ __align__(16) float s_p[64][64];   // staging; reused as v-buffer
    __shared__ int s_idx[64];
    __shared__ int s_sid[64];

    const int t = threadIdx.x;
    const int pos0 = blockIdx.x * 64;   // NATOMS = 15625 * 64 exactly

    if (t < 64) {
        s_idx[t] = sorted[pos0 + t];
        s_sid[t] = sid[pos0 + t];
    }
    __syncthreads();

    {
        const int row = t >> 3, l8 = t & 7;   // rows 0..31
        #pragma unroll
        for (int half = 0; half < 2; ++half) {
            const int rr = row + half * 32;
            const float4 f4 = *reinterpret_cast<const float4*>(p + (size_t)s_idx[rr] * 64 + l8 * 8);
            const __half2* hh = reinterpret_cast<const __half2*>(&f4);
            #pragma unroll
            for (int q = 0; q < 4; ++q) {
                const float2 f = __half22float2(hh[q]);
                const int k = 8 * l8 + 2 * q;
                s_p[k + 0][swzS64d(rr, k + 0)] = f.x;
                s_p[k + 1][swzS64d(rr, k + 1)] = f.y;
            }
        }
    }
    __syncthreads();

    const int ccol = (t & 31) * 4;   // 4 consecutive output channels
    const int rgrp = t >> 5;         // 8 rows: rgrp*8 .. rgrp*8+7

    float acc[8][4];
    #pragma unroll
    for (int i = 0; i < 8; ++i)
        #pragma unroll
        for (int j = 0; j < 4; ++j) acc[i][j] = 0.f;

    for (int k = 0; k < 64; ++k) {
        const float4 w = *reinterpret_cast<const float4*>(Wd + (size_t)k * 128 + ccol);
        const int sw = ((k >> 2) & 7) << 2;
        #pragma unroll
        for (int h = 0; h < 2; ++h) {
            const float4 rv = *reinterpret_cast<const float4*>(&s_p[k][(rgrp * 8 + h * 4) ^ sw]);
            const float rr[4] = {rv.x, rv.y, rv.z, rv.w};
            #pragma unroll
            for (int j = 0; j < 4; ++j) {
                acc[h*4+j][0] = fmaf(rr[j], w.x, acc[h*4+j][0]);
                acc[h*4+j][1] = fmaf(rr[j], w.y, acc[h*4+j][1]);
                acc[h*4+j][2] = fmaf(rr[j], w.z, acc[h*4+j][2]);
                acc[h*4+j][3] = fmaf(rr[j], w.w, acc[h*4+j][3]);
            }
        }
    }

    {
        const float4 bb = *reinterpret_cast<const float4*>(bd + ccol);
        const float4 gg = *reinterpret_cast<const float4*>(bng + ccol);
        const float4 be = *reinterpret_cast<const float4*>(bnb + ccol);
        const float4 mm = *reinterpret_cast<const float4*>(bnm + ccol);
        const float4 vv = *reinterpret_cast<const float4*>(bnv + ccol);
        const float bia[4] = {bb.x, bb.y, bb.z, bb.w};
        float sc[4], sh[4];
        sc[0] = rsqrtf(vv.x + 1e-3f) * gg.x; sh[0] = be.x - mm.x * sc[0];
        sc[1] = rsqrtf(vv.y + 1e-3f) * gg.y; sh[1] = be.y - mm.y * sc[1];
        sc[2] = rsqrtf(vv.z + 1e-3f) * gg.z; sh[2] = be.z - mm.z * sc[2];
        sc[3] = rsqrtf(vv.w + 1e-3f) * gg.w; sh[3] = be.w - mm.w * sc[3];
        #pragma unroll
        for (int i = 0; i < 8; ++i)
            #pragma unroll
            for (int j = 0; j < 4; ++j)
                acc[i][j] = fmaf(fmaxf(acc[i][j] + bia[j], 0.f), sc[j], sh[j]);
    }

    __syncthreads();   // all GEMM reads of s_p complete -> safe to overwrite

    float (*vbuf)[64] = s_p;
    const int halfSel = ccol >> 6;
    const int cc = ccol & 63;

    #pragma unroll
    for (int half = 0; half < 2; ++half) {
        if (halfSel == half) {
            #pragma unroll
            for (int i = 0; i < 8; ++i) {
                float4 o = make_float4(acc[i][0], acc[i][1], acc[i][2], acc[i][3]);
                *reinterpret_cast<float4*>(&vbuf[rgrp * 8 + i][cc]) = o;
            }
        }
        __syncthreads();

        const int c = t & 63;
        const int rbase = (t >> 6) * 16;
        const int gch = half * 64 + c;
        int cur = s_sid[rbase];
        float s = 0.f, mx = -INFINITY;
        for (int r = rbase; r < rbase + 16; ++r) {
            const int sd = s_sid[r];
            if (sd != cur) {
                atomicAdd(&segS[(size_t)cur * 128 + gch], s);
                atomicMax(&segM[(size_t)cur * 128 + gch], enc_f32(mx));
                cur = sd; s = 0.f; mx = -INFINITY;
            }
            const float v = vbuf[r][c];
            s += v;
            mx = fmaxf(mx, v);
        }
        atomicAdd(&segS[(size_t)cur * 128 + gch], s);
        atomicMax(&segM[(size_t)cur * 128 + gch], enc_f32(mx));
        __syncthreads();
    }
}

__global__ void nf_fin_kernel(const float* __restrict__ segS,
                              const unsigned* __restrict__ segM,
                              float* __restrict__ nf)
{
    const int i = blockIdx.x * blockDim.x + threadIdx.x; // < NBATCH*128
    const int m = i >> 7, c = i & 127;
    nf[(size_t)m * 256 + c]       = tanhf(segS[i]);
    nf[(size_t)m * 256 + 128 + c] = tanhf(dec_f32(segM[i]));
}

// fd0: h = relu(nf @ W + b), 32768x256 @ 256x256. 64x64 tile per block.
__global__ __launch_bounds__(256) void fd0_kernel(
    const float* __restrict__ nf, const float* __restrict__ W, const float* __restrict__ b,
    float* __restrict__ h)
{
    __shared__ __align__(16) float sx[256][64];
    const int t = threadIdx.x;
    const int r0 = (blockIdx.x >> 2) * 64;
    const int c0 = (blockIdx.x & 3) * 64;
    for (int ch = 0; ch < 4; ++ch) {
        for (int v = t; v < 1024; v += 256) {
            const int row = v >> 4, k0 = (v & 15) * 4 + ch * 64;
            const float4 r = *reinterpret_cast<const float4*>(nf + (size_t)(r0 + row) * 256 + k0);
            sx[k0 + 0][swzS64d(row, k0 + 0)] = r.x;
            sx[k0 + 1][swzS64d(row, k0 + 1)] = r.y;
            sx[k0 + 2][swzS64d(row, k0 + 2)] = r.z;
            sx[k0 + 3][swzS64d(row, k0 + 3)] = r.w;
        }
    }
    __syncthreads();

    const int c4 = (t & 15) * 4;
    const int a4 = (t >> 4) * 4;

    float acc[4][4];
    #pragma unroll
    for (int i = 0; i < 4; ++i)
        #pragma unroll
        for (int j = 0; j < 4; ++j) acc[i][j] = 0.f;

    for (int k = 0; k < 256; ++k) {
        const int sw = ((k >> 2) & 7) << 2;
        const float4 sv = *reinterpret_cast<const float4*>(&sx[k][a4 ^ sw]);
        const float4 w = *reinterpret_cast<const float4*>(W + (size_t)k * 256 + c0 + c4);
        const float ss[4] = {sv.x, sv.y, sv.z, sv.w};
        #pragma unroll
        for (int i = 0; i < 4; ++i) {
            acc[i][0] = fmaf(ss[i], w.x, acc[i][0]);
            acc[i][1] = fmaf(ss[i], w.y, acc[i][1]);
            acc[i][2] = fmaf(ss[i], w.z, acc[i][2]);
            acc[i][3] = fmaf(ss[i], w.w, acc[i][3]);
        }
    }

    const float4 bb = *reinterpret_cast<const float4*>(b + c0 + c4);
    const float bi[4] = {bb.x, bb.y, bb.z, bb.w};
    #pragma unroll
    for (int i = 0; i < 4; ++i) {
        float4 o;
        o.x = fmaxf(acc[i][0] + bi[0], 0.f);
        o.y = fmaxf(acc[i][1] + bi[1], 0.f);
        o.z = fmaxf(acc[i][2] + bi[2], 0.f);
        o.w = fmaxf(acc[i][3] + bi[3], 0.f);
        *reinterpret_cast<float4*>(h + (size_t)(r0 + a4 + i) * 256 + c0 + c4) = o;
    }
}

// rd: logits = h @ W + b (256->24), then pairwise softmax.
__global__ __launch_bounds__(384) void rd_kernel(
    const float* __restrict__ h, const float* __restrict__ W, const float* __restrict__ b,
    float* __restrict__ outP, float* __restrict__ outL)
{
    __shared__ float sh[32][257];
    const int t = threadIdx.x;
    const int r0 = blockIdx.x * 32;
    for (int e = t; e < 32 * 256; e += 384) {
        const int ri = e >> 8, k = e & 255;
        sh[ri][k] = h[(size_t)(r0 + ri) * 256 + k];
    }
    __syncthreads();
    const int r = t / 12, pj = t % 12;
    float a0 = b[2 * pj], a1 = b[2 * pj + 1];
    for (int k = 0; k < 256; ++k) {
        const float hv = sh[r][k];
        a0 = fmaf(hv, W[k * 24 + 2 * pj],     a0);
        a1 = fmaf(hv, W[k * 24 + 2 * pj + 1], a1);
    }
    const size_t m = (size_t)(r0 + r);
    outL[m * 24 + 2 * pj]     = a0;
    outL[m * 24 + 2 * pj + 1] = a1;
    const float mx = fmaxf(a0, a1);
    const float e0 = expf(a0 - mx), e1 = expf(a1 - mx);
    const float inv = 1.f / (e0 + e1);
    outP[m * 24 + 2 * pj]     = e0 * inv;
    outP[m * 24 + 2 * pj + 1] = e1 * inv;
}

} // namespace

extern "C" void kernel_launch(void* const* d_in, const int* in_sizes, int n_in,
                              void* d_out, int out_size, void* d_ws, size_t ws_size,
                              hipStream_t stream)
{
    const float* x       = (const float*)d_in[0];
    const int*   mem     = (const int*)d_in[2];
    AdjPtrs adj;
    for (int d = 0; d < 10; ++d) adj.p[d] = (const int*)d_in[4 + d];
    const float* gc0_W = (const float*)d_in[14];
    const float* gc0_b = (const float*)d_in[15];
    const float* gc1_W = (const float*)d_in[16];
    const float* gc1_b = (const float*)d_in[17];
    const float* bn0g = (const float*)d_in[18], *bn0b = (const float*)d_in[19];
    const float* bn0m = (const float*)d_in[20], *bn0v = (const float*)d_in[21];
    const float* bn1g = (const float*)d_in[22], *bn1b = (const float*)d_in[23];
    const float* bn1m = (const float*)d_in[24], *bn1v = (const float*)d_in[25];
    const float* bn2g = (const float*)d_in[26], *bn2b = (const float*)d_in[27];
    const float* bn2m = (const float*)d_in[28], *bn2v = (const float*)d_in[29];
    const float* dW   = (const float*)d_in[30], *db   = (const float*)d_in[31];
    const float* fW   = (const float*)d_in[32], *fb   = (const float*)d_in[33];
    const float* rW   = (const float*)d_in[34], *rb   = (const float*)d_in[35];

    __half* z16 = (__half*)d_ws;                               // 1M x 64
    __half* p16 = z16 + (size_t)NATOMS * 64;                   // 1M x 64
    __half* x16 = p16 + (size_t)NATOMS * 64;                   // 1M x 80
    float*  hbuf = (float*)(x16 + (size_t)NATOMS * X16S);
    float*  segS = hbuf + (size_t)NBATCH * 256;
    unsigned* segM = (unsigned*)(segS + (size_t)NBATCH * 128);
    int*    cnt    = (int*)(segM + (size_t)NBATCH * 128);
    int*    offp   = cnt + NBATCH;
    int*    cur    = offp + NBATCH;
    int*    sorted = cur + NBATCH;
    int*    sid    = sorted + NATOMS;
    unsigned* wh0  = (unsigned*)(sid + NATOMS);                // 21*38*64
    unsigned* wh1  = wh0 + 21 * 38 * 64;                       // 21*32*64

    float* outP = (float*)d_out;
    float* outL = outP + (size_t)NBATCH * 24;
    float* nfb  = outL + (size_t)NBATCH * 24;

    int convBlocks = 0, poolBlocks = 0;
    for (int d = 0; d <= 10; ++d) {
        convBlocks += (kCounts[d] + 63) >> 6;
        poolBlocks += (kCounts[d] + 31) >> 5;
    }

    // one-time conversions: x -> fp16 padded; weights -> half2 k-pairs
    cvt_kernel<<<(NATOMS + 15) / 16, 256, 0, stream>>>(x, x16);
    cvtW_kernel<<<200, 256, 0, stream>>>(gc0_W, wh0, 75, 38);
    cvtW_kernel<<<168, 256, 0, stream>>>(gc1_W, wh1, 64, 32);

    // counting sort by membership + segment accumulator init
    hipMemsetAsync(cnt, 0, NBATCH * sizeof(int), stream);
    hist_kernel<<<(NATOMS + 255) / 256, 256, 0, stream>>>(mem, cnt);
    scan_kernel<<<1, 512, 0, stream>>>(cnt, offp, cur);
    scatter_kernel<<<(NATOMS + 255) / 256, 256, 0, stream>>>(mem, cur, sorted, sid);
    seg_init_kernel<<<2048, 256, 0, stream>>>(segS, segM);

    // layer 1: conv(75->64)+relu+bn0 -> pool
    conv_all_kernel<75><<<convBlocks, 512, 0, stream>>>(x16, adj, wh0, gc0_b,
                                                        bn0g, bn0b, bn0m, bn0v, z16);
    pool_all_kernel<<<poolBlocks, 256, 0, stream>>>(z16, adj, p16);

    // layer 2: conv(64->64)+relu+bn1 -> pool
    conv_all_kernel<64><<<convBlocks, 512, 0, stream>>>(p16, adj, wh1, gc1_b,
                                                        bn1g, bn1b, bn1m, bn1v, z16);
    pool_all_kernel<<<poolBlocks, 256, 0, stream>>>(z16, adj, p16);

    // dense+relu+bn2 over sorted atoms with fused segmented sum/max
    dense_seg_sorted_kernel<<<NATOMS / 64, 256, 0, stream>>>(
        p16, sorted, sid, dW, db, bn2g, bn2b, bn2m, bn2v, segS, segM);
    // nf = tanh(concat(sum, max))
    nf_fin_kernel<<<(NBATCH * 128) / 256, 256, 0, stream>>>(segS, segM, nfb);
    // h = relu(nf @ fd0_W + fd0_b)
    fd0_kernel<<<(NBATCH / 64) * 4, 256, 0, stream>>>(nfb, fW, fb, hbuf);
    // logits + softmax
    rd_kernel<<<NBATCH / 32, 384, 0, stream>>>(hbuf, rW, rb, outP, outL);
}

// Round 18
// 1267.091 us; speedup vs baseline: 1.6066x; 1.0397x over previous
//
#include <hip/hip_runtime.h>
#include <hip/hip_fp16.h>
#include <math.h>

namespace {

constexpr int NATOMS = 1000000;
constexpr int NBATCH = 32768;
constexpr int kCounts[11] = {10000,250000,300000,250000,120000,40000,15000,8000,4000,2000,1000};
constexpr int kStarts[11] = {0,10000,260000,560000,810000,930000,970000,985000,993000,997000,999000};
constexpr int X16S = 80;   // padded fp16 row stride for x (75 ch -> 160B rows)

struct AdjPtrs { const int* p[10]; };

typedef _Float16 h2 __attribute__((ext_vector_type(2)));
union U32H2 { unsigned u; h2 h; };

__device__ __forceinline__ unsigned enc_f32(float x) {
    unsigned u = __float_as_uint(x);
    return (u & 0x80000000u) ? ~u : (u | 0x80000000u);
}
__device__ __forceinline__ float dec_f32(unsigned u) {
    return (u & 0x80000000u) ? __uint_as_float(u & 0x7FFFFFFFu) : __uint_as_float(~u);
}

// fd0 64-wide fp32 tiles (row stride 64 -> bank=col&31):
__device__ __forceinline__ int swzS64d(int row, int k) { return row ^ (((k >> 2) & 7) << 2); }

// ---------------------------------------------------------------------------
// x fp32 [1M][75] -> x16 fp16 [1M][80] (zero-padded). 16 rows per block.
// ---------------------------------------------------------------------------
__global__ __launch_bounds__(256) void cvt_kernel(const float* __restrict__ x,
                                                  __half* __restrict__ x16)
{
    const int row = blockIdx.x * 16 + (threadIdx.x >> 4);
    const int l16 = threadIdx.x & 15;
    if (row >= NATOMS) return;
    const float* __restrict__ xr = x + (size_t)row * 75;
    __half* __restrict__ xo = x16 + (size_t)row * X16S;
    #pragma unroll
    for (int q = 0; q < 5; ++q) {
        const int c = l16 + 16 * q;
        xo[c] = __float2half((c < 75) ? xr[c] : 0.f);
    }
}

// ---------------------------------------------------------------------------
// Conv weights fp32 [21][CI][64] -> half2 k-pairs [21][K2][64].
// ---------------------------------------------------------------------------
__global__ __launch_bounds__(256) void cvtW_kernel(const float* __restrict__ W,
                                                   unsigned* __restrict__ Wh,
                                                   int CI, int K2)
{
    const int total = 21 * K2 * 64;
    for (int i = blockIdx.x * 256 + threadIdx.x; i < total; i += gridDim.x * 256) {
        const int m = i / (K2 * 64);
        const int r = i - m * (K2 * 64);
        const int k2 = r >> 6, c = r & 63;
        const float a = W[((size_t)m * CI + 2 * k2) * 64 + c];
        const float b = (2 * k2 + 1 < CI) ? W[((size_t)m * CI + 2 * k2 + 1) * 64 + c] : 0.f;
        U32H2 u;
        u.h = h2{(_Float16)a, (_Float16)b};
        Wh[i] = u.u;
    }
}

// dense_W fp32 [64][128] -> half2 k-pairs [32][128]
__global__ __launch_bounds__(256) void cvtWd_kernel(const float* __restrict__ Wd,
                                                    unsigned* __restrict__ whd)
{
    const int i = blockIdx.x * 256 + threadIdx.x;   // < 32*128
    if (i >= 32 * 128) return;
    const int k2 = i >> 7, c = i & 127;
    U32H2 u;
    u.h = h2{(_Float16)Wd[(2 * k2) * 128 + c], (_Float16)Wd[(2 * k2 + 1) * 128 + c]};
    whd[i] = u.u;
}

// ---------------------------------------------------------------------------
// rel-staging: 8 lanes/atom; ONE float4 (8 halves = 4 k-pairs) per lane per
// neighbor row; fp32 accumulate, half2 LDS store.
// ---------------------------------------------------------------------------
template<int D>
__device__ __forceinline__ void stage_rel64_v(const __half* __restrict__ xin,
                                              const int* __restrict__ ad,
                                              int j0, int ai, int g8, unsigned* __restrict__ s_rel)
{
    int idxs[D];
    #pragma unroll
    for (int n = 0; n < D; ++n) idxs[n] = ad[(size_t)(j0 + ai) * D + n];
    float2 r[4];
    #pragma unroll
    for (int q = 0; q < 4; ++q) r[q] = make_float2(0.f, 0.f);
    for (int n = 0; n < D; ++n) {
        const float4 f4 = *reinterpret_cast<const float4*>(xin + (size_t)idxs[n] * 64 + g8 * 8);
        const __half2* hh = reinterpret_cast<const __half2*>(&f4);
        #pragma unroll
        for (int q = 0; q < 4; ++q) {
            const float2 v = __half22float2(hh[q]);
            r[q].x += v.x; r[q].y += v.y;
        }
    }
    const int col = ai ^ (g8 << 3);
    #pragma unroll
    for (int q = 0; q < 4; ++q) {
        U32H2 u; u.h = h2{(_Float16)r[q].x, (_Float16)r[q].y};
        s_rel[(4 * g8 + q) * 64 + col] = u.u;
    }
}

__device__ __forceinline__ void stage_rel64_rt_v(const __half* __restrict__ xin,
                                                 const int* __restrict__ ad, int d,
                                                 int j0, int ai, int g8, unsigned* __restrict__ s_rel)
{
    int idxs[10];
    for (int n = 0; n < d; ++n) idxs[n] = ad[(size_t)(j0 + ai) * d + n];
    float2 r[4];
    #pragma unroll
    for (int q = 0; q < 4; ++q) r[q] = make_float2(0.f, 0.f);
    for (int n = 0; n < d; ++n) {
        const float4 f4 = *reinterpret_cast<const float4*>(xin + (size_t)idxs[n] * 64 + g8 * 8);
        const __half2* hh = reinterpret_cast<const __half2*>(&f4);
        #pragma unroll
        for (int q = 0; q < 4; ++q) {
            const float2 v = __half22float2(hh[q]);
            r[q].x += v.x; r[q].y += v.y;
        }
    }
    const int col = ai ^ (g8 << 3);
    #pragma unroll
    for (int q = 0; q < 4; ++q) {
        U32H2 u; u.h = h2{(_Float16)r[q].x, (_Float16)r[q].y};
        s_rel[(4 * g8 + q) * 64 + col] = u.u;
    }
}

template<int D>
__device__ __forceinline__ void stage_rel75_v(const __half* __restrict__ xin,
                                              const int* __restrict__ ad,
                                              int j0, int ai, int g8, unsigned* __restrict__ s_rel)
{
    int idxs[D];
    #pragma unroll
    for (int n = 0; n < D; ++n) idxs[n] = ad[(size_t)(j0 + ai) * D + n];
    float2 r[4], r2[4];
    #pragma unroll
    for (int q = 0; q < 4; ++q) { r[q] = make_float2(0.f, 0.f); r2[q] = make_float2(0.f, 0.f); }
    for (int n = 0; n < D; ++n) {
        const __half* __restrict__ xr = xin + (size_t)idxs[n] * X16S;
        const float4 f4 = *reinterpret_cast<const float4*>(xr + g8 * 8);
        const __half2* hh = reinterpret_cast<const __half2*>(&f4);
        #pragma unroll
        for (int q = 0; q < 4; ++q) {
            const float2 v = __half22float2(hh[q]);
            r[q].x += v.x; r[q].y += v.y;
        }
        if (g8 < 2) {
            const float4 g4 = *reinterpret_cast<const float4*>(xr + 64 + g8 * 8);
            const __half2* t2 = reinterpret_cast<const __half2*>(&g4);
            #pragma unroll
            for (int q = 0; q < 4; ++q) {
                const float2 v = __half22float2(t2[q]);
                r2[q].x += v.x; r2[q].y += v.y;
            }
        }
    }
    const int col = ai ^ (g8 << 3);
    #pragma unroll
    for (int q = 0; q < 4; ++q) {
        U32H2 u; u.h = h2{(_Float16)r[q].x, (_Float16)r[q].y};
        s_rel[(4 * g8 + q) * 64 + col] = u.u;
    }
    if (g8 < 2) {
        #pragma unroll
        for (int q = 0; q < 4; ++q) {
            const int k2 = 32 + 4 * g8 + q;
            if (k2 < 38) {
                U32H2 u; u.h = h2{(_Float16)r2[q].x, (_Float16)r2[q].y};
                s_rel[k2 * 64 + col] = u.u;
            }
        }
    }
}

__device__ __forceinline__ void stage_rel75_rt_v(const __half* __restrict__ xin,
                                                 const int* __restrict__ ad, int d,
                                                 int j0, int ai, int g8, unsigned* __restrict__ s_rel)
{
    int idxs[10];
    for (int n = 0; n < d; ++n) idxs[n] = ad[(size_t)(j0 + ai) * d + n];
    float2 r[4], r2[4];
    #pragma unroll
    for (int q = 0; q < 4; ++q) { r[q] = make_float2(0.f, 0.f); r2[q] = make_float2(0.f, 0.f); }
    for (int n = 0; n < d; ++n) {
        const __half* __restrict__ xr = xin + (size_t)idxs[n] * X16S;
        const float4 f4 = *reinterpret_cast<const float4*>(xr + g8 * 8);
        const __half2* hh = reinterpret_cast<const __half2*>(&f4);
        #pragma unroll
        for (int q = 0; q < 4; ++q) {
            const float2 v = __half22float2(hh[q]);
            r[q].x += v.x; r[q].y += v.y;
        }
        if (g8 < 2) {
            const float4 g4 = *reinterpret_cast<const float4*>(xr + 64 + g8 * 8);
            const __half2* t2 = reinterpret_cast<const __half2*>(&g4);
            #pragma unroll
            for (int q = 0; q < 4; ++q) {
                const float2 v = __half22float2(t2[q]);
                r2[q].x += v.x; r2[q].y += v.y;
            }
        }
    }
    const int col = ai ^ (g8 << 3);
    #pragma unroll
    for (int q = 0; q < 4; ++q) {
        U32H2 u; u.h = h2{(_Float16)r[q].x, (_Float16)r[q].y};
        s_rel[(4 * g8 + q) * 64 + col] = u.u;
    }
    if (g8 < 2) {
        #pragma unroll
        for (int q = 0; q < 4; ++q) {
            const int k2 = 32 + 4 * g8 + q;
            if (k2 < 38) {
                U32H2 u; u.h = h2{(_Float16)r2[q].x, (_Float16)r2[q].y};
                s_rel[k2 * 64 + col] = u.u;
            }
        }
    }
}

// ---------------------------------------------------------------------------
// Merged conv layer: 64-atom tile, 512 threads, fp16 gathers (1 load/lane/row)
// + v_dot2_f32_f16 compute (2 MACs/instr, fp32 accumulate).
// ---------------------------------------------------------------------------
template<int CI>
__global__ __launch_bounds__(512) void conv_all_kernel(
    const __half* __restrict__ xin, AdjPtrs adj,
    const unsigned* __restrict__ Wh, const float* __restrict__ B,
    const float* __restrict__ bng, const float* __restrict__ bnb,
    const float* __restrict__ bnm, const float* __restrict__ bnv,
    __half* __restrict__ out)
{
    constexpr int XS = (CI == 64) ? 64 : X16S;
    constexpr int K2 = (CI + 1) / 2;          // 38 / 32
    constexpr int SM = (2 * K2 * 64 > 64 * 65) ? 2 * K2 * 64 : 64 * 65;
    __shared__ __align__(16) unsigned smem[SM];
    unsigned* s_self = smem;             // [K2][64] half2
    unsigned* s_rel  = smem + K2 * 64;   // [K2][64] half2

    int d = 0, rem = blockIdx.x;
    for (;;) { const int nb = (kCounts[d] + 63) >> 6; if (rem < nb) break; rem -= nb; ++d; }
    const int j0 = rem << 6;
    const int nA = min(64, kCounts[d] - j0);
    const int a0 = kStarts[d] + j0;
    const int t = threadIdx.x;

    // ---- stage self rows: 8 lanes/row, one float4 (+tail) each ----
    {
        const int row = t >> 3, l8 = t & 7;
        if (row < nA) {
            const __half* __restrict__ xr = xin + (size_t)(a0 + row) * XS;
            const float4 f4 = *reinterpret_cast<const float4*>(xr + l8 * 8);
            const unsigned* uu = reinterpret_cast<const unsigned*>(&f4);
            const int col = row ^ (l8 << 3);
            #pragma unroll
            for (int q = 0; q < 4; ++q)
                s_self[(4 * l8 + q) * 64 + col] = uu[q];
            if (CI == 75 && l8 < 2) {
                const float4 g4 = *reinterpret_cast<const float4*>(xr + 64 + l8 * 8);
                #pragma unroll
                for (int q = 0; q < 4; ++q) {
                    const int k2 = 32 + 4 * l8 + q;
                    if (k2 < K2)
                        s_self[k2 * 64 + col] = reinterpret_cast<const unsigned*>(&g4)[q];
                }
            }
        }
    }

    // ---- stage neighbor sums (8 lanes/atom, one 16B load per row) ----
    if (d > 0) {
        const int ai = t >> 3, g8 = t & 7;
        if (ai < nA) {
            const int* __restrict__ adp = adj.p[d - 1];
            if constexpr (CI == 64) {
                switch (d) {
                case 1: stage_rel64_v<1>(xin, adp, j0, ai, g8, s_rel); break;
                case 2: stage_rel64_v<2>(xin, adp, j0, ai, g8, s_rel); break;
                case 3: stage_rel64_v<3>(xin, adp, j0, ai, g8, s_rel); break;
                case 4: stage_rel64_v<4>(xin, adp, j0, ai, g8, s_rel); break;
                default: stage_rel64_rt_v(xin, adp, d, j0, ai, g8, s_rel); break;
                }
            } else {
                switch (d) {
                case 1: stage_rel75_v<1>(xin, adp, j0, ai, g8, s_rel); break;
                case 2: stage_rel75_v<2>(xin, adp, j0, ai, g8, s_rel); break;
                case 3: stage_rel75_v<3>(xin, adp, j0, ai, g8, s_rel); break;
                case 4: stage_rel75_v<4>(xin, adp, j0, ai, g8, s_rel); break;
                default: stage_rel75_rt_v(xin, adp, d, j0, ai, g8, s_rel); break;
                }
            }
        }
    }
    __syncthreads();

    // ---- compute: atom-per-lane, 8 channels/thread, fdot2 scalar weights ----
    const int a  = t & 63;
    const int c0 = __builtin_amdgcn_readfirstlane(t >> 6) * 8;   // wave-uniform

    float acc[8];
    #pragma unroll
    for (int j = 0; j < 8; ++j) acc[j] = 0.f;

    if (d == 0) {
        const unsigned* __restrict__ Ws = Wh + (size_t)(2 * 10) * K2 * 64;
        #pragma unroll
        for (int k2 = 0; k2 < K2; ++k2) {
            U32H2 xs; xs.u = s_self[k2 * 64 + (a ^ (((k2 >> 2) & 7) << 3))];
            #pragma unroll
            for (int j = 0; j < 8; ++j) {
                U32H2 w; w.u = Ws[k2 * 64 + c0 + j];
                acc[j] = __builtin_amdgcn_fdot2(xs.h, w.h, acc[j], false);
            }
        }
    } else {
        const unsigned* __restrict__ Wr = Wh + (size_t)(2 * (d - 1)) * K2 * 64;
        const unsigned* __restrict__ Ws = Wh + (size_t)(2 * d - 1) * K2 * 64;
        #pragma unroll
        for (int k2 = 0; k2 < K2; ++k2) {
            const int col = a ^ (((k2 >> 2) & 7) << 3);
            U32H2 xs; xs.u = s_self[k2 * 64 + col];
            U32H2 xr; xr.u = s_rel [k2 * 64 + col];
            #pragma unroll
            for (int j = 0; j < 8; ++j) {
                U32H2 ws; ws.u = Ws[k2 * 64 + c0 + j];
                U32H2 wr; wr.u = Wr[k2 * 64 + c0 + j];
                acc[j] = __builtin_amdgcn_fdot2(xr.h, wr.h,
                          __builtin_amdgcn_fdot2(xs.h, ws.h, acc[j], false), false);
            }
        }
    }

    // ---- epilogue: scalar bias/BN, rotated-LDS transpose, fp16 store ----
    __syncthreads();
    float* vout = reinterpret_cast<float*>(smem);   // [64][65]
    #pragma unroll
    for (int j = 0; j < 8; ++j) {
        const int c = c0 + j;                               // wave-uniform
        const float bias = (d == 0) ? B[20 * 64 + c]
                                    : (B[(2 * (d - 1)) * 64 + c] + B[(2 * d - 1) * 64 + c]);
        const float scl = rsqrtf(bnv[c] + 1e-3f) * bng[c];
        const float sht = bnb[c] - bnm[c] * scl;
        vout[a * 65 + c] = fmaf(fmaxf(acc[j] + bias, 0.f), scl, sht);
    }
    __syncthreads();
    const int cc = t & 63, g = t >> 6;
    #pragma unroll
    for (int i = 0; i < 8; ++i) {
        const int row = g * 8 + i;
        if (row < nA) out[(size_t)(a0 + row) * 64 + cc] = __float2half(vout[row * 65 + cc]);
    }
}

// ---------------------------------------------------------------------------
// Merged pool layer (fp16), conv-style gather: 8 lanes/atom, ONE float4
// per lane per row; 32 atoms per block; packed fp16 stores.
// ---------------------------------------------------------------------------
template<int D>
__device__ __forceinline__ void pool_rows(const __half* __restrict__ z,
                                          const int* __restrict__ ad, int j, int g8,
                                          float2 mx[4])
{
    int idxs[D];
    #pragma unroll
    for (int n = 0; n < D; ++n) idxs[n] = ad[(size_t)j * D + n];
    for (int n = 0; n < D; ++n) {
        const float4 f4 = *reinterpret_cast<const float4*>(z + (size_t)idxs[n] * 64 + g8 * 8);
        const __half2* hh = reinterpret_cast<const __half2*>(&f4);
        #pragma unroll
        for (int q = 0; q < 4; ++q) {
            const float2 v = __half22float2(hh[q]);
            mx[q].x = fmaxf(mx[q].x, v.x);
            mx[q].y = fmaxf(mx[q].y, v.y);
        }
    }
}

__device__ __forceinline__ void pool_rows_rt(const __half* __restrict__ z,
                                             const int* __restrict__ ad, int d, int j, int g8,
                                             float2 mx[4])
{
    int idxs[10];
    for (int n = 0; n < d; ++n) idxs[n] = ad[(size_t)j * d + n];
    for (int n = 0; n < d; ++n) {
        const float4 f4 = *reinterpret_cast<const float4*>(z + (size_t)idxs[n] * 64 + g8 * 8);
        const __half2* hh = reinterpret_cast<const __half2*>(&f4);
        #pragma unroll
        for (int q = 0; q < 4; ++q) {
            const float2 v = __half22float2(hh[q]);
            mx[q].x = fmaxf(mx[q].x, v.x);
            mx[q].y = fmaxf(mx[q].y, v.y);
        }
    }
}

__global__ __launch_bounds__(256) void pool_all_kernel(
    const __half* __restrict__ z, AdjPtrs adj, __half* __restrict__ p)
{
    int d = 0, rem = blockIdx.x;
    for (;;) { const int nb = (kCounts[d] + 31) >> 5; if (rem < nb) break; rem -= nb; ++d; }
    const int t = threadIdx.x;
    const int j = rem * 32 + (t >> 3);
    if (j >= kCounts[d]) return;
    const int g8 = t & 7;
    const int a = kStarts[d] + j;

    const float4 s4 = *reinterpret_cast<const float4*>(z + (size_t)a * 64 + g8 * 8);
    const __half2* sh2 = reinterpret_cast<const __half2*>(&s4);
    float2 mx[4];
    #pragma unroll
    for (int q = 0; q < 4; ++q) mx[q] = __half22float2(sh2[q]);

    if (d > 0) {
        const int* __restrict__ ad = adj.p[d - 1];
        switch (d) {
        case 1:  pool_rows<1 >(z, ad, j, g8, mx); break;
        case 2:  pool_rows<2 >(z, ad, j, g8, mx); break;
        case 3:  pool_rows<3 >(z, ad, j, g8, mx); break;
        case 4:  pool_rows<4 >(z, ad, j, g8, mx); break;
        default: pool_rows_rt(z, ad, d, j, g8, mx); break;
        }
    }

    union { __half2 h[4]; float4 f; } u;
    #pragma unroll
    for (int q = 0; q < 4; ++q) u.h[q] = __floats2half2_rn(mx[q].x, mx[q].y);
    *reinterpret_cast<float4*>(p + (size_t)a * 64 + g8 * 8) = u.f;
}

// ---------------------------------------------------------------------------
// Counting sort by membership: hist -> scan -> scatter (+ per-position seg id).
// ---------------------------------------------------------------------------
__global__ __launch_bounds__(256) void hist_kernel(const int* __restrict__ mem,
                                                   int* __restrict__ cnt)
{
    const int a = blockIdx.x * 256 + threadIdx.x;
    if (a < NATOMS) atomicAdd(&cnt[mem[a]], 1);
}

__global__ __launch_bounds__(512) void scan_kernel(const int* __restrict__ cnt,
                                                   int* __restrict__ off,
                                                   int* __restrict__ cur)
{
    __shared__ int part[512];
    const int t = threadIdx.x;
    const int base = t * 64;
    int s = 0;
    #pragma unroll 8
    for (int i = 0; i < 64; ++i) s += cnt[base + i];
    part[t] = s;
    __syncthreads();
    for (int o = 1; o < 512; o <<= 1) {
        int v = (t >= o) ? part[t - o] : 0;
        __syncthreads();
        part[t] += v;
        __syncthreads();
    }
    int run = (t == 0) ? 0 : part[t - 1];
    for (int i = 0; i < 64; ++i) {
        off[base + i] = run;
        cur[base + i] = run;
        run += cnt[base + i];
    }
}

__global__ __launch_bounds__(256) void scatter_kernel(const int* __restrict__ mem,
                                                      int* __restrict__ cur,
                                                      int* __restrict__ sorted,
                                                      int* __restrict__ sid)
{
    const int a = blockIdx.x * 256 + threadIdx.x;
    if (a < NATOMS) {
        const int m = mem[a];
        const int pos = atomicAdd(&cur[m], 1);
        sorted[pos] = a;
        sid[pos] = m;
    }
}

__global__ void seg_init_kernel(float* __restrict__ segS, unsigned* __restrict__ segM)
{
    const int n = NBATCH * 128;
    for (int i = blockIdx.x * blockDim.x + threadIdx.x; i < n; i += gridDim.x * blockDim.x) {
        segS[i] = 0.f;
        segM[i] = 0x007FFFFFu; // enc(-inf)
    }
}

// ---------------------------------------------------------------------------
// Dense 64->128 + ReLU + BN2 over SORTED atoms, fdot2 on fp16 k-pairs:
// staging is raw half2 copy (uint4 stores, no conversion); weights pre-packed
// half2 [32][128]; per-thread cost halves vs r17's fp32 path (r17: 269us,
// VALUBusy 72%, FETCH 66MB -> VALU-instruction-bound).
// LDS: staging [64][36] u32 (9KB), vbuf reuses same 16KB buffer.
// ---------------------------------------------------------------------------
__global__ __launch_bounds__(256) void dense_seg_sorted_kernel(
    const __half* __restrict__ p,
    const int* __restrict__ sorted, const int* __restrict__ sid,
    const unsigned* __restrict__ whd, const float* __restrict__ bd,
    const float* __restrict__ bng, const float* __restrict__ bnb,
    const float* __restrict__ bnm, const float* __restrict__ bnv,
    float* __restrict__ segS, unsigned* __restrict__ segM)
{
    __shared__ __align__(16) unsigned s_raw[64 * 64];   // 16KB: staging + vbuf
    __shared__ int s_idx[64];
    __shared__ int s_sid[64];

    unsigned* s_p2 = s_raw;                                        // [64][36] u32
    float (*vbuf)[64] = reinterpret_cast<float(*)[64]>(s_raw);     // [64][64] f32

    const int t = threadIdx.x;
    const int pos0 = blockIdx.x * 64;   // NATOMS = 15625 * 64 exactly

    if (t < 64) {
        s_idx[t] = sorted[pos0 + t];
        s_sid[t] = sid[pos0 + t];
    }
    __syncthreads();

    // stage: 8 lanes/row, one uint4 (4 k-pairs) each; raw fp16 copy
    {
        const int row = t >> 3, l8 = t & 7;   // rows 0..31
        #pragma unroll
        for (int half = 0; half < 2; ++half) {
            const int rr = row + half * 32;
            const uint4 f4 = *reinterpret_cast<const uint4*>(p + (size_t)s_idx[rr] * 64 + l8 * 8);
            *reinterpret_cast<uint4*>(&s_p2[rr * 36 + 4 * l8]) = f4;
        }
    }
    __syncthreads();

    const int ccol = (t & 31) * 4;   // 4 consecutive output channels
    const int rgrp = t >> 5;         // 8 rows: rgrp*8 .. rgrp*8+7

    float acc[8][4];
    #pragma unroll
    for (int i = 0; i < 8; ++i)
        #pragma unroll
        for (int j = 0; j < 4; ++j) acc[i][j] = 0.f;

    #pragma unroll
    for (int k4 = 0; k4 < 32; k4 += 4) {
        uint4 w[4];
        #pragma unroll
        for (int q = 0; q < 4; ++q)
            w[q] = *reinterpret_cast<const uint4*>(&whd[(k4 + q) * 128 + ccol]);
        #pragma unroll
        for (int i = 0; i < 8; ++i) {
            const int row = rgrp * 8 + i;
            const uint4 rv = *reinterpret_cast<const uint4*>(&s_p2[row * 36 + k4]);
            const unsigned* rvu = reinterpret_cast<const unsigned*>(&rv);
            #pragma unroll
            for (int q = 0; q < 4; ++q) {
                U32H2 xv; xv.u = rvu[q];
                const unsigned* wu = reinterpret_cast<const unsigned*>(&w[q]);
                #pragma unroll
                for (int j = 0; j < 4; ++j) {
                    U32H2 wv; wv.u = wu[j];
                    acc[i][j] = __builtin_amdgcn_fdot2(xv.h, wv.h, acc[i][j], false);
                }
            }
        }
    }

    {
        const float4 bb = *reinterpret_cast<const float4*>(bd + ccol);
        const float4 gg = *reinterpret_cast<const float4*>(bng + ccol);
        const float4 be = *reinterpret_cast<const float4*>(bnb + ccol);
        const float4 mm = *reinterpret_cast<const float4*>(bnm + ccol);
        const float4 vv = *reinterpret_cast<const float4*>(bnv + ccol);
        const float bia[4] = {bb.x, bb.y, bb.z, bb.w};
        float sc[4], sh[4];
        sc[0] = rsqrtf(vv.x + 1e-3f) * gg.x; sh[0] = be.x - mm.x * sc[0];
        sc[1] = rsqrtf(vv.y + 1e-3f) * gg.y; sh[1] = be.y - mm.y * sc[1];
        sc[2] = rsqrtf(vv.z + 1e-3f) * gg.z; sh[2] = be.z - mm.z * sc[2];
        sc[3] = rsqrtf(vv.w + 1e-3f) * gg.w; sh[3] = be.w - mm.w * sc[3];
        #pragma unroll
        for (int i = 0; i < 8; ++i)
            #pragma unroll
            for (int j = 0; j < 4; ++j)
                acc[i][j] = fmaf(fmaxf(acc[i][j] + bia[j], 0.f), sc[j], sh[j]);
    }

    __syncthreads();   // all GEMM reads of s_p2 complete -> safe to overwrite

    const int halfSel = ccol >> 6;
    const int cc = ccol & 63;

    #pragma unroll
    for (int half = 0; half < 2; ++half) {
        if (halfSel == half) {
            #pragma unroll
            for (int i = 0; i < 8; ++i) {
                float4 o = make_float4(acc[i][0], acc[i][1], acc[i][2], acc[i][3]);
                *reinterpret_cast<float4*>(&vbuf[rgrp * 8 + i][cc]) = o;
            }
        }
        __syncthreads();

        const int c = t & 63;
        const int rbase = (t >> 6) * 16;
        const int gch = half * 64 + c;
        int cur = s_sid[rbase];
        float s = 0.f, mx = -INFINITY;
        for (int r = rbase; r < rbase + 16; ++r) {
            const int sd = s_sid[r];
            if (sd != cur) {
                atomicAdd(&segS[(size_t)cur * 128 + gch], s);
                atomicMax(&segM[(size_t)cur * 128 + gch], enc_f32(mx));
                cur = sd; s = 0.f; mx = -INFINITY;
            }
            const float v = vbuf[r][c];
            s += v;
            mx = fmaxf(mx, v);
        }
        atomicAdd(&segS[(size_t)cur * 128 + gch], s);
        atomicMax(&segM[(size_t)cur * 128 + gch], enc_f32(mx));
        __syncthreads();
    }
}

__global__ void nf_fin_kernel(const float* __restrict__ segS,
                              const unsigned* __restrict__ segM,
                              float* __restrict__ nf)
{
    const int i = blockIdx.x * blockDim.x + threadIdx.x; // < NBATCH*128
    const int m = i >> 7, c = i & 127;
    nf[(size_t)m * 256 + c]       = tanhf(segS[i]);
    nf[(size_t)m * 256 + 128 + c] = tanhf(dec_f32(segM[i]));
}

// fd0: h = relu(nf @ W + b), 32768x256 @ 256x256. 64x64 tile per block.
__global__ __launch_bounds__(256) void fd0_kernel(
    const float* __restrict__ nf, const float* __restrict__ W, const float* __restrict__ b,
    float* __restrict__ h)
{
    __shared__ __align__(16) float sx[256][64];
    const int t = threadIdx.x;
    const int r0 = (blockIdx.x >> 2) * 64;
    const int c0 = (blockIdx.x & 3) * 64;
    for (int ch = 0; ch < 4; ++ch) {
        for (int v = t; v < 1024; v += 256) {
            const int row = v >> 4, k0 = (v & 15) * 4 + ch * 64;
            const float4 r = *reinterpret_cast<const float4*>(nf + (size_t)(r0 + row) * 256 + k0);
            sx[k0 + 0][swzS64d(row, k0 + 0)] = r.x;
            sx[k0 + 1][swzS64d(row, k0 + 1)] = r.y;
            sx[k0 + 2][swzS64d(row, k0 + 2)] = r.z;
            sx[k0 + 3][swzS64d(row, k0 + 3)] = r.w;
        }
    }
    __syncthreads();

    const int c4 = (t & 15) * 4;
    const int a4 = (t >> 4) * 4;

    float acc[4][4];
    #pragma unroll
    for (int i = 0; i < 4; ++i)
        #pragma unroll
        for (int j = 0; j < 4; ++j) acc[i][j] = 0.f;

    for (int k = 0; k < 256; ++k) {
        const int sw = ((k >> 2) & 7) << 2;
        const float4 sv = *reinterpret_cast<const float4*>(&sx[k][a4 ^ sw]);
        const float4 w = *reinterpret_cast<const float4*>(W + (size_t)k * 256 + c0 + c4);
        const float ss[4] = {sv.x, sv.y, sv.z, sv.w};
        #pragma unroll
        for (int i = 0; i < 4; ++i) {
            acc[i][0] = fmaf(ss[i], w.x, acc[i][0]);
            acc[i][1] = fmaf(ss[i], w.y, acc[i][1]);
            acc[i][2] = fmaf(ss[i], w.z, acc[i][2]);
            acc[i][3] = fmaf(ss[i], w.w, acc[i][3]);
        }
    }

    const float4 bb = *reinterpret_cast<const float4*>(b + c0 + c4);
    const float bi[4] = {bb.x, bb.y, bb.z, bb.w};
    #pragma unroll
    for (int i = 0; i < 4; ++i) {
        float4 o;
        o.x = fmaxf(acc[i][0] + bi[0], 0.f);
        o.y = fmaxf(acc[i][1] + bi[1], 0.f);
        o.z = fmaxf(acc[i][2] + bi[2], 0.f);
        o.w = fmaxf(acc[i][3] + bi[3], 0.f);
        *reinterpret_cast<float4*>(h + (size_t)(r0 + a4 + i) * 256 + c0 + c4) = o;
    }
}

// rd: logits = h @ W + b (256->24), then pairwise softmax.
__global__ __launch_bounds__(384) void rd_kernel(
    const float* __restrict__ h, const float* __restrict__ W, const float* __restrict__ b,
    float* __restrict__ outP, float* __restrict__ outL)
{
    __shared__ float sh[32][257];
    const int t = threadIdx.x;
    const int r0 = blockIdx.x * 32;
    for (int e = t; e < 32 * 256; e += 384) {
        const int ri = e >> 8, k = e & 255;
        sh[ri][k] = h[(size_t)(r0 + ri) * 256 + k];
    }
    __syncthreads();
    const int r = t / 12, pj = t % 12;
    float a0 = b[2 * pj], a1 = b[2 * pj + 1];
    for (int k = 0; k < 256; ++k) {
        const float hv = sh[r][k];
        a0 = fmaf(hv, W[k * 24 + 2 * pj],     a0);
        a1 = fmaf(hv, W[k * 24 + 2 * pj + 1], a1);
    }
    const size_t m = (size_t)(r0 + r);
    outL[m * 24 + 2 * pj]     = a0;
    outL[m * 24 + 2 * pj + 1] = a1;
    const float mx = fmaxf(a0, a1);
    const float e0 = expf(a0 - mx), e1 = expf(a1 - mx);
    const float inv = 1.f / (e0 + e1);
    outP[m * 24 + 2 * pj]     = e0 * inv;
    outP[m * 24 + 2 * pj + 1] = e1 * inv;
}

} // namespace

extern "C" void kernel_launch(void* const* d_in, const int* in_sizes, int n_in,
                              void* d_out, int out_size, void* d_ws, size_t ws_size,
                              hipStream_t stream)
{
    const float* x       = (const float*)d_in[0];
    const int*   mem     = (const int*)d_in[2];
    AdjPtrs adj;
    for (int d = 0; d < 10; ++d) adj.p[d] = (const int*)d_in[4 + d];
    const float* gc0_W = (const float*)d_in[14];
    const float* gc0_b = (const float*)d_in[15];
    const float* gc1_W = (const float*)d_in[16];
    const float* gc1_b = (const float*)d_in[17];
    const float* bn0g = (const float*)d_in[18], *bn0b = (const float*)d_in[19];
    const float* bn0m = (const float*)d_in[20], *bn0v = (const float*)d_in[21];
    const float* bn1g = (const float*)d_in[22], *bn1b = (const float*)d_in[23];
    const float* bn1m = (const float*)d_in[24], *bn1v = (const float*)d_in[25];
    const float* bn2g = (const float*)d_in[26], *bn2b = (const float*)d_in[27];
    const float* bn2m = (const float*)d_in[28], *bn2v = (const float*)d_in[29];
    const float* dW   = (const float*)d_in[30], *db   = (const float*)d_in[31];
    const float* fW   = (const float*)d_in[32], *fb   = (const float*)d_in[33];
    const float* rW   = (const float*)d_in[34], *rb   = (const float*)d_in[35];

    __half* z16 = (__half*)d_ws;                               // 1M x 64
    __half* p16 = z16 + (size_t)NATOMS * 64;                   // 1M x 64
    __half* x16 = p16 + (size_t)NATOMS * 64;                   // 1M x 80
    float*  hbuf = (float*)(x16 + (size_t)NATOMS * X16S);
    float*  segS = hbuf + (size_t)NBATCH * 256;
    unsigned* segM = (unsigned*)(segS + (size_t)NBATCH * 128);
    int*    cnt    = (int*)(segM + (size_t)NBATCH * 128);
    int*    offp   = cnt + NBATCH;
    int*    cur    = offp + NBATCH;
    int*    sorted = cur + NBATCH;
    int*    sid    = sorted + NATOMS;
    unsigned* wh0  = (unsigned*)(sid + NATOMS);                // 21*38*64
    unsigned* wh1  = wh0 + 21 * 38 * 64;                       // 21*32*64
    unsigned* whd  = wh1 + 21 * 32 * 64;                       // 32*128

    float* outP = (float*)d_out;
    float* outL = outP + (size_t)NBATCH * 24;
    float* nfb  = outL + (size_t)NBATCH * 24;

    int convBlocks = 0, poolBlocks = 0;
    for (int d = 0; d <= 10; ++d) {
        convBlocks += (kCounts[d] + 63) >> 6;
        poolBlocks += (kCounts[d] + 31) >> 5;
    }

    // one-time conversions: x -> fp16 padded; weights -> half2 k-pairs
    cvt_kernel<<<(NATOMS + 15) / 16, 256, 0, stream>>>(x, x16);
    cvtW_kernel<<<200, 256, 0, stream>>>(gc0_W, wh0, 75, 38);
    cvtW_kernel<<<168, 256, 0, stream>>>(gc1_W, wh1, 64, 32);
    cvtWd_kernel<<<16, 256, 0, stream>>>(dW, whd);

    // counting sort by membership + segment accumulator init
    hipMemsetAsync(cnt, 0, NBATCH * sizeof(int), stream);
    hist_kernel<<<(NATOMS + 255) / 256, 256, 0, stream>>>(mem, cnt);
    scan_kernel<<<1, 512, 0, stream>>>(cnt, offp, cur);
    scatter_kernel<<<(NATOMS + 255) / 256, 256, 0, stream>>>(mem, cur, sorted, sid);
    seg_init_kernel<<<2048, 256, 0, stream>>>(segS, segM);

    // layer 1: conv(75->64)+relu+bn0 -> pool
    conv_all_kernel<75><<<convBlocks, 512, 0, stream>>>(x16, adj, wh0, gc0_b,
                                                        bn0g, bn0b, bn0m, bn0v, z16);
    pool_all_kernel<<<poolBlocks, 256, 0, stream>>>(z16, adj, p16);

    // layer 2: conv(64->64)+relu+bn1 -> pool
    conv_all_kernel<64><<<convBlocks, 512, 0, stream>>>(p16, adj, wh1, gc1_b,
                                                        bn1g, bn1b, bn1m, bn1v, z16);
    pool_all_kernel<<<poolBlocks, 256, 0, stream>>>(z16, adj, p16);

    // dense+relu+bn2 over sorted atoms with fused segmented sum/max
    dense_seg_sorted_kernel<<<NATOMS / 64, 256, 0, stream>>>(
        p16, sorted, sid, whd, db, bn2g, bn2b, bn2m, bn2v, segS, segM);
    // nf = tanh(concat(sum, max))
    nf_fin_kernel<<<(NBATCH * 128) / 256, 256, 0, stream>>>(segS, segM, nfb);
    // h = relu(nf @ fd0_W + fd0_b)
    fd0_kernel<<<(NBATCH / 64) * 4, 256, 0, stream>>>(nfb, fW, fb, hbuf);
    // logits + softmax
    rd_kernel<<<NBATCH / 32, 384, 0, stream>>>(hbuf, rW, rb, outP, outL);
}

// Round 19
// 1101.914 us; speedup vs baseline: 1.8474x; 1.1499x over previous
//
#include <hip/hip_runtime.h>
#include <hip/hip_fp16.h>
#include <math.h>

namespace {

constexpr int NATOMS = 1000000;
constexpr int NBATCH = 32768;
constexpr int kCounts[11] = {10000,250000,300000,250000,120000,40000,15000,8000,4000,2000,1000};
constexpr int kStarts[11] = {0,10000,260000,560000,810000,930000,970000,985000,993000,997000,999000};
constexpr int X16S = 80;   // padded fp16 row stride for x (75 ch -> 160B rows)

struct AdjPtrs { const int* p[10]; };

typedef _Float16 h2 __attribute__((ext_vector_type(2)));
typedef _Float16 h8 __attribute__((ext_vector_type(8)));
typedef float    f4 __attribute__((ext_vector_type(4)));
union U32H2 { unsigned u; h2 h; };

__device__ __forceinline__ unsigned enc_f32(float x) {
    unsigned u = __float_as_uint(x);
    return (u & 0x80000000u) ? ~u : (u | 0x80000000u);
}
__device__ __forceinline__ float dec_f32(unsigned u) {
    return (u & 0x80000000u) ? __uint_as_float(u & 0x7FFFFFFFu) : __uint_as_float(~u);
}

// fd0 64-wide fp32 tiles (row stride 64 -> bank=col&31):
__device__ __forceinline__ int swzS64d(int row, int k) { return row ^ (((k >> 2) & 7) << 2); }

// ---------------------------------------------------------------------------
// x fp32 [1M][75] -> x16 fp16 [1M][80] (zero-padded). 16 rows per block.
// ---------------------------------------------------------------------------
__global__ __launch_bounds__(256) void cvt_kernel(const float* __restrict__ x,
                                                  __half* __restrict__ x16)
{
    const int row = blockIdx.x * 16 + (threadIdx.x >> 4);
    const int l16 = threadIdx.x & 15;
    if (row >= NATOMS) return;
    const float* __restrict__ xr = x + (size_t)row * 75;
    __half* __restrict__ xo = x16 + (size_t)row * X16S;
    #pragma unroll
    for (int q = 0; q < 5; ++q) {
        const int c = l16 + 16 * q;
        xo[c] = __float2half((c < 75) ? xr[c] : 0.f);
    }
}

// ---------------------------------------------------------------------------
// Pack conv weights into MFMA B-fragment order:
// bp[((deg*4 + ni)*KS + ks)*64 + lane] = 8 halves, element j:
//   k = ks*32 + (lane>>4)*8 + j  (same contiguous-8 k-map as the A fragment,
//   so any HW k-permutation cancels), col = ni*16 + (lane&15).
//   k < GH*8: self weights (W[20] for d0, W[2d-1] else), zero-pad k>=CI.
//   else: rel weights W[2(d-1)] (zero for d0), zero-pad.
// ---------------------------------------------------------------------------
__global__ __launch_bounds__(256) void packB_kernel(const float* __restrict__ W,
                                                    uint4* __restrict__ bp,
                                                    int CI, int GH, int KS)
{
    const int total = 11 * 4 * KS * 64;
    const int idx = blockIdx.x * 256 + threadIdx.x;
    if (idx >= total) return;
    const int lane = idx & 63;
    int q = idx >> 6;
    const int ks = q % KS; q /= KS;
    const int ni = q & 3;
    const int deg = q >> 2;
    const int col = ni * 16 + (lane & 15);
    __half vals[8];
    #pragma unroll
    for (int j = 0; j < 8; ++j) {
        const int k = ks * 32 + (lane >> 4) * 8 + j;
        float v = 0.f;
        if (k < GH * 8) {
            if (k < CI) {
                const int m = (deg == 0) ? 20 : (2 * deg - 1);
                v = W[((size_t)m * CI + k) * 64 + col];
            }
        } else {
            const int kk = k - GH * 8;
            if (deg > 0 && kk < CI)
                v = W[((size_t)(2 * (deg - 1)) * CI + kk) * 64 + col];
        }
        vals[j] = __float2half(v);
    }
    bp[idx] = *reinterpret_cast<const uint4*>(vals);
}

// dense_W fp32 [64][128] -> half2 k-pairs [32][128]
__global__ __launch_bounds__(256) void cvtWd_kernel(const float* __restrict__ Wd,
                                                    unsigned* __restrict__ whd)
{
    const int i = blockIdx.x * 256 + threadIdx.x;   // < 32*128
    if (i >= 32 * 128) return;
    const int k2 = i >> 7, c = i & 127;
    U32H2 u;
    u.h = h2{(_Float16)Wd[(2 * k2) * 128 + c], (_Float16)Wd[(2 * k2 + 1) * 128 + c]};
    whd[i] = u.u;
}

// ---------------------------------------------------------------------------
// rel-staging: 8 lanes/atom; ONE uint4 (8 halves) per lane per neighbor row;
// fp32 accumulate, packed fp16 uint4 store into the MFMA A-tile rel region.
// ---------------------------------------------------------------------------
template<int D, int STRH, int GH>
__device__ __forceinline__ void stage_rel64_m(const __half* __restrict__ xin,
                                              const int* __restrict__ ad,
                                              int j0, int row, int l8,
                                              __half* __restrict__ s_a)
{
    int idxs[D];
    #pragma unroll
    for (int n = 0; n < D; ++n) idxs[n] = ad[(size_t)(j0 + row) * D + n];
    float2 r[4];
    #pragma unroll
    for (int q = 0; q < 4; ++q) r[q] = make_float2(0.f, 0.f);
    for (int n = 0; n < D; ++n) {
        const uint4 f4v = *reinterpret_cast<const uint4*>(xin + (size_t)idxs[n] * 64 + l8 * 8);
        const __half2* hh = reinterpret_cast<const __half2*>(&f4v);
        #pragma unroll
        for (int q = 0; q < 4; ++q) {
            const float2 v = __half22float2(hh[q]);
            r[q].x += v.x; r[q].y += v.y;
        }
    }
    uint4 o;
    unsigned* ou = reinterpret_cast<unsigned*>(&o);
    #pragma unroll
    for (int q = 0; q < 4; ++q) {
        U32H2 u; u.h = h2{(_Float16)r[q].x, (_Float16)r[q].y};
        ou[q] = u.u;
    }
    *reinterpret_cast<uint4*>(&s_a[row * STRH + (GH + l8) * 8]) = o;
}

template<int STRH, int GH>
__device__ __forceinline__ void stage_rel64_rt_m(const __half* __restrict__ xin,
                                                 const int* __restrict__ ad, int d,
                                                 int j0, int row, int l8,
                                                 __half* __restrict__ s_a)
{
    int idxs[10];
    for (int n = 0; n < d; ++n) idxs[n] = ad[(size_t)(j0 + row) * d + n];
    float2 r[4];
    #pragma unroll
    for (int q = 0; q < 4; ++q) r[q] = make_float2(0.f, 0.f);
    for (int n = 0; n < d; ++n) {
        const uint4 f4v = *reinterpret_cast<const uint4*>(xin + (size_t)idxs[n] * 64 + l8 * 8);
        const __half2* hh = reinterpret_cast<const __half2*>(&f4v);
        #pragma unroll
        for (int q = 0; q < 4; ++q) {
            const float2 v = __half22float2(hh[q]);
            r[q].x += v.x; r[q].y += v.y;
        }
    }
    uint4 o;
    unsigned* ou = reinterpret_cast<unsigned*>(&o);
    #pragma unroll
    for (int q = 0; q < 4; ++q) {
        U32H2 u; u.h = h2{(_Float16)r[q].x, (_Float16)r[q].y};
        ou[q] = u.u;
    }
    *reinterpret_cast<uint4*>(&s_a[row * STRH + (GH + l8) * 8]) = o;
}

template<int D, int STRH, int GH>
__device__ __forceinline__ void stage_rel75_m(const __half* __restrict__ xin,
                                              const int* __restrict__ ad,
                                              int j0, int row, int l8,
                                              __half* __restrict__ s_a)
{
    int idxs[D];
    #pragma unroll
    for (int n = 0; n < D; ++n) idxs[n] = ad[(size_t)(j0 + row) * D + n];
    float2 r[4], r2[4];
    #pragma unroll
    for (int q = 0; q < 4; ++q) { r[q] = make_float2(0.f, 0.f); r2[q] = make_float2(0.f, 0.f); }
    for (int n = 0; n < D; ++n) {
        const __half* __restrict__ xr = xin + (size_t)idxs[n] * X16S;
        const uint4 f4v = *reinterpret_cast<const uint4*>(xr + l8 * 8);
        const __half2* hh = reinterpret_cast<const __half2*>(&f4v);
        #pragma unroll
        for (int q = 0; q < 4; ++q) {
            const float2 v = __half22float2(hh[q]);
            r[q].x += v.x; r[q].y += v.y;
        }
        if (l8 < 2) {
            const uint4 g4 = *reinterpret_cast<const uint4*>(xr + 64 + l8 * 8);
            const __half2* t2 = reinterpret_cast<const __half2*>(&g4);
            #pragma unroll
            for (int q = 0; q < 4; ++q) {
                const float2 v = __half22float2(t2[q]);
                r2[q].x += v.x; r2[q].y += v.y;
            }
        }
    }
    uint4 o;
    unsigned* ou = reinterpret_cast<unsigned*>(&o);
    #pragma unroll
    for (int q = 0; q < 4; ++q) {
        U32H2 u; u.h = h2{(_Float16)r[q].x, (_Float16)r[q].y};
        ou[q] = u.u;
    }
    *reinterpret_cast<uint4*>(&s_a[row * STRH + (GH + l8) * 8]) = o;
    if (l8 < 2) {
        uint4 o2;
        unsigned* ou2 = reinterpret_cast<unsigned*>(&o2);
        #pragma unroll
        for (int q = 0; q < 4; ++q) {
            U32H2 u; u.h = h2{(_Float16)r2[q].x, (_Float16)r2[q].y};
            ou2[q] = u.u;
        }
        *reinterpret_cast<uint4*>(&s_a[row * STRH + (GH + 8 + l8) * 8]) = o2;
    }
}

template<int STRH, int GH>
__device__ __forceinline__ void stage_rel75_rt_m(const __half* __restrict__ xin,
                                                 const int* __restrict__ ad, int d,
                                                 int j0, int row, int l8,
                                                 __half* __restrict__ s_a)
{
    int idxs[10];
    for (int n = 0; n < d; ++n) idxs[n] = ad[(size_t)(j0 + row) * d + n];
    float2 r[4], r2[4];
    #pragma unroll
    for (int q = 0; q < 4; ++q) { r[q] = make_float2(0.f, 0.f); r2[q] = make_float2(0.f, 0.f); }
    for (int n = 0; n < d; ++n) {
        const __half* __restrict__ xr = xin + (size_t)idxs[n] * X16S;
        const uint4 f4v = *reinterpret_cast<const uint4*>(xr + l8 * 8);
        const __half2* hh = reinterpret_cast<const __half2*>(&f4v);
        #pragma unroll
        for (int q = 0; q < 4; ++q) {
            const float2 v = __half22float2(hh[q]);
            r[q].x += v.x; r[q].y += v.y;
        }
        if (l8 < 2) {
            const uint4 g4 = *reinterpret_cast<const uint4*>(xr + 64 + l8 * 8);
            const __half2* t2 = reinterpret_cast<const __half2*>(&g4);
            #pragma unroll
            for (int q = 0; q < 4; ++q) {
                const float2 v = __half22float2(t2[q]);
                r2[q].x += v.x; r2[q].y += v.y;
            }
        }
    }
    uint4 o;
    unsigned* ou = reinterpret_cast<unsigned*>(&o);
    #pragma unroll
    for (int q = 0; q < 4; ++q) {
        U32H2 u; u.h = h2{(_Float16)r[q].x, (_Float16)r[q].y};
        ou[q] = u.u;
    }
    *reinterpret_cast<uint4*>(&s_a[row * STRH + (GH + l8) * 8]) = o;
    if (l8 < 2) {
        uint4 o2;
        unsigned* ou2 = reinterpret_cast<unsigned*>(&o2);
        #pragma unroll
        for (int q = 0; q < 4; ++q) {
            U32H2 u; u.h = h2{(_Float16)r2[q].x, (_Float16)r2[q].y};
            ou2[q] = u.u;
        }
        *reinterpret_cast<uint4*>(&s_a[row * STRH + (GH + 8 + l8) * 8]) = o2;
    }
}

// ---------------------------------------------------------------------------
// Merged conv layer, MFMA: A-tile [64 atoms][K] fp16 in LDS (K = self|rel,
// padded 128/160; row stride K+8 halves -> <=2-way banks on fragment reads),
// B pre-packed in fragment order (one coalesced uint4/lane/step). 8 waves x
// 2 16x16 subtiles x KS mfma_f32_16x16x32_f16. Compute moves to the matrix
// pipe (r18: VALUBusy 82% at the fdot2 ceiling); gather (~390MB) remains.
// C/D layout: col=lane&15, row=(lane>>4)*4+reg  [guide m89-verified].
// ---------------------------------------------------------------------------
template<int CI>
__global__ __launch_bounds__(512) void conv_all_kernel(
    const __half* __restrict__ xin, AdjPtrs adj,
    const uint4* __restrict__ bp, const float* __restrict__ B,
    const float* __restrict__ bng, const float* __restrict__ bnb,
    const float* __restrict__ bnm, const float* __restrict__ bnv,
    __half* __restrict__ out)
{
    constexpr int XS   = (CI == 64) ? 64 : X16S;
    constexpr int GH   = (CI == 64) ? 8 : 10;     // groups (8 halves) per half-K
    constexpr int KS   = GH / 2;                  // K/32 mfma steps
    constexpr int STRH = 16 * GH + 8;             // row stride in halves
    __shared__ __align__(16) __half s_a[64 * STRH];

    int d = 0, rem = blockIdx.x;
    for (;;) { const int nb = (kCounts[d] + 63) >> 6; if (rem < nb) break; rem -= nb; ++d; }
    const int j0 = rem << 6;
    const int nA = min(64, kCounts[d] - j0);
    const int a0 = kStarts[d] + j0;
    const int t = threadIdx.x;
    const int row = t >> 3, l8 = t & 7;

    // ---- stage self rows ----
    if (row < nA) {
        const __half* __restrict__ xr = xin + (size_t)(a0 + row) * XS;
        *reinterpret_cast<uint4*>(&s_a[row * STRH + l8 * 8]) =
            *reinterpret_cast<const uint4*>(xr + l8 * 8);
        if (CI == 75 && l8 < 2)
            *reinterpret_cast<uint4*>(&s_a[row * STRH + 64 + l8 * 8]) =
                *reinterpret_cast<const uint4*>(xr + 64 + l8 * 8);
    }

    // ---- stage rel (neighbor sums) or zero for d=0 ----
    if (d > 0) {
        if (row < nA) {
            const int* __restrict__ adp = adj.p[d - 1];
            if constexpr (CI == 64) {
                switch (d) {
                case 1: stage_rel64_m<1, STRH, GH>(xin, adp, j0, row, l8, s_a); break;
                case 2: stage_rel64_m<2, STRH, GH>(xin, adp, j0, row, l8, s_a); break;
                case 3: stage_rel64_m<3, STRH, GH>(xin, adp, j0, row, l8, s_a); break;
                case 4: stage_rel64_m<4, STRH, GH>(xin, adp, j0, row, l8, s_a); break;
                default: stage_rel64_rt_m<STRH, GH>(xin, adp, d, j0, row, l8, s_a); break;
                }
            } else {
                switch (d) {
                case 1: stage_rel75_m<1, STRH, GH>(xin, adp, j0, row, l8, s_a); break;
                case 2: stage_rel75_m<2, STRH, GH>(xin, adp, j0, row, l8, s_a); break;
                case 3: stage_rel75_m<3, STRH, GH>(xin, adp, j0, row, l8, s_a); break;
                case 4: stage_rel75_m<4, STRH, GH>(xin, adp, j0, row, l8, s_a); break;
                default: stage_rel75_rt_m<STRH, GH>(xin, adp, d, j0, row, l8, s_a); break;
                }
            }
        }
    } else {
        const uint4 z4 = make_uint4(0u, 0u, 0u, 0u);
        *reinterpret_cast<uint4*>(&s_a[row * STRH + (GH + l8) * 8]) = z4;
        if (CI == 75 && l8 < 2)
            *reinterpret_cast<uint4*>(&s_a[row * STRH + (GH + 8 + l8) * 8]) = z4;
    }
    __syncthreads();

    // ---- MFMA: wave w -> subtiles 2w, 2w+1 of the 4x4 16x16 grid ----
    const int lane = t & 63, w = t >> 6;
    const int lr = lane & 15, lg = lane >> 4;

    #pragma unroll
    for (int sb = 0; sb < 2; ++sb) {
        const int s = 2 * w + sb;
        const int mi = s >> 2, ni = s & 3;
        f4 acc = {0.f, 0.f, 0.f, 0.f};
        #pragma unroll
        for (int ks = 0; ks < KS; ++ks) {
            const h8 av = *reinterpret_cast<const h8*>(
                &s_a[(mi * 16 + lr) * STRH + (ks * 4 + lg) * 8]);
            uint4 braw = bp[((d * 4 + ni) * KS + ks) * 64 + lane];
            const h8 bv = *reinterpret_cast<const h8*>(&braw);
            acc = __builtin_amdgcn_mfma_f32_16x16x32_f16(av, bv, acc, 0, 0, 0);
        }
        const int ch = ni * 16 + lr;
        const float bias = (d == 0) ? B[20 * 64 + ch]
                                    : (B[(2 * (d - 1)) * 64 + ch] + B[(2 * d - 1) * 64 + ch]);
        const float scl = rsqrtf(bnv[ch] + 1e-3f) * bng[ch];
        const float sht = bnb[ch] - bnm[ch] * scl;
        #pragma unroll
        for (int r = 0; r < 4; ++r) {
            const int atom = mi * 16 + lg * 4 + r;
            if (atom < nA)
                out[(size_t)(a0 + atom) * 64 + ch] =
                    __float2half(fmaf(fmaxf(acc[r] + bias, 0.f), scl, sht));
        }
    }
}

// ---------------------------------------------------------------------------
// Merged pool layer (fp16), conv-style gather: 8 lanes/atom, ONE float4
// per lane per row; 32 atoms per block; packed fp16 stores.
// ---------------------------------------------------------------------------
template<int D>
__device__ __forceinline__ void pool_rows(const __half* __restrict__ z,
                                          const int* __restrict__ ad, int j, int g8,
                                          float2 mx[4])
{
    int idxs[D];
    #pragma unroll
    for (int n = 0; n < D; ++n) idxs[n] = ad[(size_t)j * D + n];
    for (int n = 0; n < D; ++n) {
        const float4 f4v = *reinterpret_cast<const float4*>(z + (size_t)idxs[n] * 64 + g8 * 8);
        const __half2* hh = reinterpret_cast<const __half2*>(&f4v);
        #pragma unroll
        for (int q = 0; q < 4; ++q) {
            const float2 v = __half22float2(hh[q]);
            mx[q].x = fmaxf(mx[q].x, v.x);
            mx[q].y = fmaxf(mx[q].y, v.y);
        }
    }
}

__device__ __forceinline__ void pool_rows_rt(const __half* __restrict__ z,
                                             const int* __restrict__ ad, int d, int j, int g8,
                                             float2 mx[4])
{
    int idxs[10];
    for (int n = 0; n < d; ++n) idxs[n] = ad[(size_t)j * d + n];
    for (int n = 0; n < d; ++n) {
        const float4 f4v = *reinterpret_cast<const float4*>(z + (size_t)idxs[n] * 64 + g8 * 8);
        const __half2* hh = reinterpret_cast<const __half2*>(&f4v);
        #pragma unroll
        for (int q = 0; q < 4; ++q) {
            const float2 v = __half22float2(hh[q]);
            mx[q].x = fmaxf(mx[q].x, v.x);
            mx[q].y = fmaxf(mx[q].y, v.y);
        }
    }
}

__global__ __launch_bounds__(256) void pool_all_kernel(
    const __half* __restrict__ z, AdjPtrs adj, __half* __restrict__ p)
{
    int d = 0, rem = blockIdx.x;
    for (;;) { const int nb = (kCounts[d] + 31) >> 5; if (rem < nb) break; rem -= nb; ++d; }
    const int t = threadIdx.x;
    const int j = rem * 32 + (t >> 3);
    if (j >= kCounts[d]) return;
    const int g8 = t & 7;
    const int a = kStarts[d] + j;

    const float4 s4 = *reinterpret_cast<const float4*>(z + (size_t)a * 64 + g8 * 8);
    const __half2* sh2 = reinterpret_cast<const __half2*>(&s4);
    float2 mx[4];
    #pragma unroll
    for (int q = 0; q < 4; ++q) mx[q] = __half22float2(sh2[q]);

    if (d > 0) {
        const int* __restrict__ ad = adj.p[d - 1];
        switch (d) {
        case 1:  pool_rows<1 >(z, ad, j, g8, mx); break;
        case 2:  pool_rows<2 >(z, ad, j, g8, mx); break;
        case 3:  pool_rows<3 >(z, ad, j, g8, mx); break;
        case 4:  pool_rows<4 >(z, ad, j, g8, mx); break;
        default: pool_rows_rt(z, ad, d, j, g8, mx); break;
        }
    }

    union { __half2 h[4]; float4 f; } u;
    #pragma unroll
    for (int q = 0; q < 4; ++q) u.h[q] = __floats2half2_rn(mx[q].x, mx[q].y);
    *reinterpret_cast<float4*>(p + (size_t)a * 64 + g8 * 8) = u.f;
}

// ---------------------------------------------------------------------------
// Counting sort by membership: hist -> scan -> scatter (+ per-position seg id).
// ---------------------------------------------------------------------------
__global__ __launch_bounds__(256) void hist_kernel(const int* __restrict__ mem,
                                                   int* __restrict__ cnt)
{
    const int a = blockIdx.x * 256 + threadIdx.x;
    if (a < NATOMS) atomicAdd(&cnt[mem[a]], 1);
}

__global__ __launch_bounds__(512) void scan_kernel(const int* __restrict__ cnt,
                                                   int* __restrict__ off,
                                                   int* __restrict__ cur)
{
    __shared__ int part[512];
    const int t = threadIdx.x;
    const int base = t * 64;
    int s = 0;
    #pragma unroll 8
    for (int i = 0; i < 64; ++i) s += cnt[base + i];
    part[t] = s;
    __syncthreads();
    for (int o = 1; o < 512; o <<= 1) {
        int v = (t >= o) ? part[t - o] : 0;
        __syncthreads();
        part[t] += v;
        __syncthreads();
    }
    int run = (t == 0) ? 0 : part[t - 1];
    for (int i = 0; i < 64; ++i) {
        off[base + i] = run;
        cur[base + i] = run;
        run += cnt[base + i];
    }
}

__global__ __launch_bounds__(256) void scatter_kernel(const int* __restrict__ mem,
                                                      int* __restrict__ cur,
                                                      int* __restrict__ sorted,
                                                      int* __restrict__ sid)
{
    const int a = blockIdx.x * 256 + threadIdx.x;
    if (a < NATOMS) {
        const int m = mem[a];
        const int pos = atomicAdd(&cur[m], 1);
        sorted[pos] = a;
        sid[pos] = m;
    }
}

__global__ void seg_init_kernel(float* __restrict__ segS, unsigned* __restrict__ segM)
{
    const int n = NBATCH * 128;
    for (int i = blockIdx.x * blockDim.x + threadIdx.x; i < n; i += gridDim.x * blockDim.x) {
        segS[i] = 0.f;
        segM[i] = 0x007FFFFFu; // enc(-inf)
    }
}

// ---------------------------------------------------------------------------
// Dense 64->128 + ReLU + BN2 over SORTED atoms, fdot2 on fp16 k-pairs
// (r18-proven). LDS: staging [64][36] u32 (9KB), vbuf reuses same buffer.
// ---------------------------------------------------------------------------
__global__ __launch_bounds__(256) void dense_seg_sorted_kernel(
    const __half* __restrict__ p,
    const int* __restrict__ sorted, const int* __restrict__ sid,
    const unsigned* __restrict__ whd, const float* __restrict__ bd,
    const float* __restrict__ bng, const float* __restrict__ bnb,
    const float* __restrict__ bnm, const float* __restrict__ bnv,
    float* __restrict__ segS, unsigned* __restrict__ segM)
{
    __shared__ __align__(16) unsigned s_raw[64 * 64];   // 16KB: staging + vbuf
    __shared__ int s_idx[64];
    __shared__ int s_sid[64];

    unsigned* s_p2 = s_raw;                                        // [64][36] u32
    float (*vbuf)[64] = reinterpret_cast<float(*)[64]>(s_raw);     // [64][64] f32

    const int t = threadIdx.x;
    const int pos0 = blockIdx.x * 64;   // NATOMS = 15625 * 64 exactly

    if (t < 64) {
        s_idx[t] = sorted[pos0 + t];
        s_sid[t] = sid[pos0 + t];
    }
    __syncthreads();

    {
        const int row = t >> 3, l8 = t & 7;   // rows 0..31
        #pragma unroll
        for (int half = 0; half < 2; ++half) {
            const int rr = row + half * 32;
            const uint4 f4v = *reinterpret_cast<const uint4*>(p + (size_t)s_idx[rr] * 64 + l8 * 8);
            *reinterpret_cast<uint4*>(&s_p2[rr * 36 + 4 * l8]) = f4v;
        }
    }
    __syncthreads();

    const int ccol = (t & 31) * 4;   // 4 consecutive output channels
    const int rgrp = t >> 5;         // 8 rows: rgrp*8 .. rgrp*8+7

    float acc[8][4];
    #pragma unroll
    for (int i = 0; i < 8; ++i)
        #pragma unroll
        for (int j = 0; j < 4; ++j) acc[i][j] = 0.f;

    #pragma unroll
    for (int k4 = 0; k4 < 32; k4 += 4) {
        uint4 w[4];
        #pragma unroll
        for (int q = 0; q < 4; ++q)
            w[q] = *reinterpret_cast<const uint4*>(&whd[(k4 + q) * 128 + ccol]);
        #pragma unroll
        for (int i = 0; i < 8; ++i) {
            const int row = rgrp * 8 + i;
            const uint4 rv = *reinterpret_cast<const uint4*>(&s_p2[row * 36 + k4]);
            const unsigned* rvu = reinterpret_cast<const unsigned*>(&rv);
            #pragma unroll
            for (int q = 0; q < 4; ++q) {
                U32H2 xv; xv.u = rvu[q];
                const unsigned* wu = reinterpret_cast<const unsigned*>(&w[q]);
                #pragma unroll
                for (int j = 0; j < 4; ++j) {
                    U32H2 wv; wv.u = wu[j];
                    acc[i][j] = __builtin_amdgcn_fdot2(xv.h, wv.h, acc[i][j], false);
                }
            }
        }
    }

    {
        const float4 bb = *reinterpret_cast<const float4*>(bd + ccol);
        const float4 gg = *reinterpret_cast<const float4*>(bng + ccol);
        const float4 be = *reinterpret_cast<const float4*>(bnb + ccol);
        const float4 mm = *reinterpret_cast<const float4*>(bnm + ccol);
        const float4 vv = *reinterpret_cast<const float4*>(bnv + ccol);
        const float bia[4] = {bb.x, bb.y, bb.z, bb.w};
        float sc[4], sh[4];
        sc[0] = rsqrtf(vv.x + 1e-3f) * gg.x; sh[0] = be.x - mm.x * sc[0];
        sc[1] = rsqrtf(vv.y + 1e-3f) * gg.y; sh[1] = be.y - mm.y * sc[1];
        sc[2] = rsqrtf(vv.z + 1e-3f) * gg.z; sh[2] = be.z - mm.z * sc[2];
        sc[3] = rsqrtf(vv.w + 1e-3f) * gg.w; sh[3] = be.w - mm.w * sc[3];
        #pragma unroll
        for (int i = 0; i < 8; ++i)
            #pragma unroll
            for (int j = 0; j < 4; ++j)
                acc[i][j] = fmaf(fmaxf(acc[i][j] + bia[j], 0.f), sc[j], sh[j]);
    }

    __syncthreads();   // all GEMM reads of s_p2 complete -> safe to overwrite

    const int halfSel = ccol >> 6;
    const int cc = ccol & 63;

    #pragma unroll
    for (int half = 0; half < 2; ++half) {
        if (halfSel == half) {
            #pragma unroll
            for (int i = 0; i < 8; ++i) {
                float4 o = make_float4(acc[i][0], acc[i][1], acc[i][2], acc[i][3]);
                *reinterpret_cast<float4*>(&vbuf[rgrp * 8 + i][cc]) = o;
            }
        }
        __syncthreads();

        const int c = t & 63;
        const int rbase = (t >> 6) * 16;
        const int gch = half * 64 + c;
        int cur = s_sid[rbase];
        float s = 0.f, mx = -INFINITY;
        for (int r = rbase; r < rbase + 16; ++r) {
            const int sd = s_sid[r];
            if (sd != cur) {
                atomicAdd(&segS[(size_t)cur * 128 + gch], s);
                atomicMax(&segM[(size_t)cur * 128 + gch], enc_f32(mx));
                cur = sd; s = 0.f; mx = -INFINITY;
            }
            const float v = vbuf[r][c];
            s += v;
            mx = fmaxf(mx, v);
        }
        atomicAdd(&segS[(size_t)cur * 128 + gch], s);
        atomicMax(&segM[(size_t)cur * 128 + gch], enc_f32(mx));
        __syncthreads();
    }
}

__global__ void nf_fin_kernel(const float* __restrict__ segS,
                              const unsigned* __restrict__ segM,
                              float* __restrict__ nf)
{
    const int i = blockIdx.x * blockDim.x + threadIdx.x; // < NBATCH*128
    const int m = i >> 7, c = i & 127;
    nf[(size_t)m * 256 + c]       = tanhf(segS[i]);
    nf[(size_t)m * 256 + 128 + c] = tanhf(dec_f32(segM[i]));
}

// fd0: h = relu(nf @ W + b), 32768x256 @ 256x256. 64x64 tile per block.
__global__ __launch_bounds__(256) void fd0_kernel(
    const float* __restrict__ nf, const float* __restrict__ W, const float* __restrict__ b,
    float* __restrict__ h)
{
    __shared__ __align__(16) float sx[256][64];
    const int t = threadIdx.x;
    const int r0 = (blockIdx.x >> 2) * 64;
    const int c0 = (blockIdx.x & 3) * 64;
    for (int ch = 0; ch < 4; ++ch) {
        for (int v = t; v < 1024; v += 256) {
            const int row = v >> 4, k0 = (v & 15) * 4 + ch * 64;
            const float4 r = *reinterpret_cast<const float4*>(nf + (size_t)(r0 + row) * 256 + k0);
            sx[k0 + 0][swzS64d(row, k0 + 0)] = r.x;
            sx[k0 + 1][swzS64d(row, k0 + 1)] = r.y;
            sx[k0 + 2][swzS64d(row, k0 + 2)] = r.z;
            sx[k0 + 3][swzS64d(row, k0 + 3)] = r.w;
        }
    }
    __syncthreads();

    const int c4 = (t & 15) * 4;
    const int a4 = (t >> 4) * 4;

    float acc[4][4];
    #pragma unroll
    for (int i = 0; i < 4; ++i)
        #pragma unroll
        for (int j = 0; j < 4; ++j) acc[i][j] = 0.f;

    for (int k = 0; k < 256; ++k) {
        const int sw = ((k >> 2) & 7) << 2;
        const float4 sv = *reinterpret_cast<const float4*>(&sx[k][a4 ^ sw]);
        const float4 w = *reinterpret_cast<const float4*>(W + (size_t)k * 256 + c0 + c4);
        const float ss[4] = {sv.x, sv.y, sv.z, sv.w};
        #pragma unroll
        for (int i = 0; i < 4; ++i) {
            acc[i][0] = fmaf(ss[i], w.x, acc[i][0]);
            acc[i][1] = fmaf(ss[i], w.y, acc[i][1]);
            acc[i][2] = fmaf(ss[i], w.z, acc[i][2]);
            acc[i][3] = fmaf(ss[i], w.w, acc[i][3]);
        }
    }

    const float4 bb = *reinterpret_cast<const float4*>(b + c0 + c4);
    const float bi[4] = {bb.x, bb.y, bb.z, bb.w};
    #pragma unroll
    for (int i = 0; i < 4; ++i) {
        float4 o;
        o.x = fmaxf(acc[i][0] + bi[0], 0.f);
        o.y = fmaxf(acc[i][1] + bi[1], 0.f);
        o.z = fmaxf(acc[i][2] + bi[2], 0.f);
        o.w = fmaxf(acc[i][3] + bi[3], 0.f);
        *reinterpret_cast<float4*>(h + (size_t)(r0 + a4 + i) * 256 + c0 + c4) = o;
    }
}

// rd: logits = h @ W + b (256->24), then pairwise softmax.
__global__ __launch_bounds__(384) void rd_kernel(
    const float* __restrict__ h, const float* __restrict__ W, const float* __restrict__ b,
    float* __restrict__ outP, float* __restrict__ outL)
{
    __shared__ float sh[32][257];
    const int t = threadIdx.x;
    const int r0 = blockIdx.x * 32;
    for (int e = t; e < 32 * 256; e += 384) {
        const int ri = e >> 8, k = e & 255;
        sh[ri][k] = h[(size_t)(r0 + ri) * 256 + k];
    }
    __syncthreads();
    const int r = t / 12, pj = t % 12;
    float a0 = b[2 * pj], a1 = b[2 * pj + 1];
    for (int k = 0; k < 256; ++k) {
        const float hv = sh[r][k];
        a0 = fmaf(hv, W[k * 24 + 2 * pj],     a0);
        a1 = fmaf(hv, W[k * 24 + 2 * pj + 1], a1);
    }
    const size_t m = (size_t)(r0 + r);
    outL[m * 24 + 2 * pj]     = a0;
    outL[m * 24 + 2 * pj + 1] = a1;
    const float mx = fmaxf(a0, a1);
    const float e0 = expf(a0 - mx), e1 = expf(a1 - mx);
    const float inv = 1.f / (e0 + e1);
    outP[m * 24 + 2 * pj]     = e0 * inv;
    outP[m * 24 + 2 * pj + 1] = e1 * inv;
}

} // namespace

extern "C" void kernel_launch(void* const* d_in, const int* in_sizes, int n_in,
                              void* d_out, int out_size, void* d_ws, size_t ws_size,
                              hipStream_t stream)
{
    const float* x       = (const float*)d_in[0];
    const int*   mem     = (const int*)d_in[2];
    AdjPtrs adj;
    for (int d = 0; d < 10; ++d) adj.p[d] = (const int*)d_in[4 + d];
    const float* gc0_W = (const float*)d_in[14];
    const float* gc0_b = (const float*)d_in[15];
    const float* gc1_W = (const float*)d_in[16];
    const float* gc1_b = (const float*)d_in[17];
    const float* bn0g = (const float*)d_in[18], *bn0b = (const float*)d_in[19];
    const float* bn0m = (const float*)d_in[20], *bn0v = (const float*)d_in[21];
    const float* bn1g = (const float*)d_in[22], *bn1b = (const float*)d_in[23];
    const float* bn1m = (const float*)d_in[24], *bn1v = (const float*)d_in[25];
    const float* bn2g = (const float*)d_in[26], *bn2b = (const float*)d_in[27];
    const float* bn2m = (const float*)d_in[28], *bn2v = (const float*)d_in[29];
    const float* dW   = (const float*)d_in[30], *db   = (const float*)d_in[31];
    const float* fW   = (const float*)d_in[32], *fb   = (const float*)d_in[33];
    const float* rW   = (const float*)d_in[34], *rb   = (const float*)d_in[35];

    __half* z16 = (__half*)d_ws;                               // 1M x 64
    __half* p16 = z16 + (size_t)NATOMS * 64;                   // 1M x 64
    __half* x16 = p16 + (size_t)NATOMS * 64;                   // 1M x 80
    float*  hbuf = (float*)(x16 + (size_t)NATOMS * X16S);
    float*  segS = hbuf + (size_t)NBATCH * 256;
    unsigned* segM = (unsigned*)(segS + (size_t)NBATCH * 128);
    int*    cnt    = (int*)(segM + (size_t)NBATCH * 128);
    int*    offp   = cnt + NBATCH;
    int*    cur    = offp + NBATCH;
    int*    sorted = cur + NBATCH;
    int*    sid    = sorted + NATOMS;
    uint4*  bp0    = (uint4*)(sid + NATOMS);                   // 11*4*5*64 uint4
    uint4*  bp1    = bp0 + 11 * 4 * 5 * 64;                    // 11*4*4*64 uint4
    unsigned* whd  = (unsigned*)(bp1 + 11 * 4 * 4 * 64);       // 32*128

    float* outP = (float*)d_out;
    float* outL = outP + (size_t)NBATCH * 24;
    float* nfb  = outL + (size_t)NBATCH * 24;

    int convBlocks = 0, poolBlocks = 0;
    for (int d = 0; d <= 10; ++d) {
        convBlocks += (kCounts[d] + 63) >> 6;
        poolBlocks += (kCounts[d] + 31) >> 5;
    }

    // one-time conversions: x -> fp16 padded; conv weights -> MFMA B-fragments;
    // dense weights -> half2 k-pairs
    cvt_kernel<<<(NATOMS + 15) / 16, 256, 0, stream>>>(x, x16);
    packB_kernel<<<55, 256, 0, stream>>>(gc0_W, bp0, 75, 10, 5);
    packB_kernel<<<44, 256, 0, stream>>>(gc1_W, bp1, 64, 8, 4);
    cvtWd_kernel<<<16, 256, 0, stream>>>(dW, whd);

    // counting sort by membership + segment accumulator init
    hipMemsetAsync(cnt, 0, NBATCH * sizeof(int), stream);
    hist_kernel<<<(NATOMS + 255) / 256, 256, 0, stream>>>(mem, cnt);
    scan_kernel<<<1, 512, 0, stream>>>(cnt, offp, cur);
    scatter_kernel<<<(NATOMS + 255) / 256, 256, 0, stream>>>(mem, cur, sorted, sid);
    seg_init_kernel<<<2048, 256, 0, stream>>>(segS, segM);

    // layer 1: conv(75->64)+relu+bn0 -> pool
    conv_all_kernel<75><<<convBlocks, 512, 0, stream>>>(x16, adj, bp0, gc0_b,
                                                        bn0g, bn0b, bn0m, bn0v, z16);
    pool_all_kernel<<<poolBlocks, 256, 0, stream>>>(z16, adj, p16);

    // layer 2: conv(64->64)+relu+bn1 -> pool
    conv_all_kernel<64><<<convBlocks, 512, 0, stream>>>(p16, adj, bp1, gc1_b,
                                                        bn1g, bn1b, bn1m, bn1v, z16);
    pool_all_kernel<<<poolBlocks, 256, 0, stream>>>(z16, adj, p16);

    // dense+relu+bn2 over sorted atoms with fused segmented sum/max
    dense_seg_sorted_kernel<<<NATOMS / 64, 256, 0, stream>>>(
        p16, sorted, sid, whd, db, bn2g, bn2b, bn2m, bn2v, segS, segM);
    // nf = tanh(concat(sum, max))
    nf_fin_kernel<<<(NBATCH * 128) / 256, 256, 0, stream>>>(segS, segM, nfb);
    // h = relu(nf @ fd0_W + fd0_b)
    fd0_kernel<<<(NBATCH / 64) * 4, 256, 0, stream>>>(nfb, fW, fb, hbuf);
    // logits + softmax
    rd_kernel<<<NBATCH / 32, 384, 0, stream>>>(hbuf, rW, rb, outP, outL);
}

// Round 20
// 1021.159 us; speedup vs baseline: 1.9935x; 1.0791x over previous
//
#include <hip/hip_runtime.h>
#include <hip/hip_fp16.h>
#include <math.h>

namespace {

constexpr int NATOMS = 1000000;
constexpr int NBATCH = 32768;
constexpr int kCounts[11] = {10000,250000,300000,250000,120000,40000,15000,8000,4000,2000,1000};
constexpr int kStarts[11] = {0,10000,260000,560000,810000,930000,970000,985000,993000,997000,999000};
constexpr int X16S = 80;   // padded fp16 row stride for x (75 ch -> 160B rows)

struct AdjPtrs { const int* p[10]; };

typedef _Float16 h2 __attribute__((ext_vector_type(2)));
typedef _Float16 h8 __attribute__((ext_vector_type(8)));
typedef float    f4 __attribute__((ext_vector_type(4)));
union U32H2 { unsigned u; h2 h; };

__device__ __forceinline__ unsigned enc_f32(float x) {
    unsigned u = __float_as_uint(x);
    return (u & 0x80000000u) ? ~u : (u | 0x80000000u);
}
__device__ __forceinline__ float dec_f32(unsigned u) {
    return (u & 0x80000000u) ? __uint_as_float(u & 0x7FFFFFFFu) : __uint_as_float(~u);
}

// fd0 64-wide fp32 tiles (row stride 64 -> bank=col&31):
__device__ __forceinline__ int swzS64d(int row, int k) { return row ^ (((k >> 2) & 7) << 2); }

// ---------------------------------------------------------------------------
// x fp32 [1M][75] -> x16 fp16 [1M][80] (zero-padded). 16 rows per block.
// ---------------------------------------------------------------------------
__global__ __launch_bounds__(256) void cvt_kernel(const float* __restrict__ x,
                                                  __half* __restrict__ x16)
{
    const int row = blockIdx.x * 16 + (threadIdx.x >> 4);
    const int l16 = threadIdx.x & 15;
    if (row >= NATOMS) return;
    const float* __restrict__ xr = x + (size_t)row * 75;
    __half* __restrict__ xo = x16 + (size_t)row * X16S;
    #pragma unroll
    for (int q = 0; q < 5; ++q) {
        const int c = l16 + 16 * q;
        xo[c] = __float2half((c < 75) ? xr[c] : 0.f);
    }
}

// ---------------------------------------------------------------------------
// Pack conv weights into MFMA B-fragment order (k-map matches A fragment).
// ---------------------------------------------------------------------------
__global__ __launch_bounds__(256) void packB_kernel(const float* __restrict__ W,
                                                    uint4* __restrict__ bp,
                                                    int CI, int GH, int KS)
{
    const int total = 11 * 4 * KS * 64;
    const int idx = blockIdx.x * 256 + threadIdx.x;
    if (idx >= total) return;
    const int lane = idx & 63;
    int q = idx >> 6;
    const int ks = q % KS; q /= KS;
    const int ni = q & 3;
    const int deg = q >> 2;
    const int col = ni * 16 + (lane & 15);
    __half vals[8];
    #pragma unroll
    for (int j = 0; j < 8; ++j) {
        const int k = ks * 32 + (lane >> 4) * 8 + j;
        float v = 0.f;
        if (k < GH * 8) {
            if (k < CI) {
                const int m = (deg == 0) ? 20 : (2 * deg - 1);
                v = W[((size_t)m * CI + k) * 64 + col];
            }
        } else {
            const int kk = k - GH * 8;
            if (deg > 0 && kk < CI)
                v = W[((size_t)(2 * (deg - 1)) * CI + kk) * 64 + col];
        }
        vals[j] = __float2half(v);
    }
    bp[idx] = *reinterpret_cast<const uint4*>(vals);
}

// dense_W fp32 [64][128] -> MFMA B-fragments: bpd[(ni*2+ks)*64+lane], ni 0..7
__global__ __launch_bounds__(256) void packBd_kernel(const float* __restrict__ Wd,
                                                     uint4* __restrict__ bpd)
{
    const int idx = blockIdx.x * 256 + threadIdx.x;   // < 8*2*64
    if (idx >= 8 * 2 * 64) return;
    const int lane = idx & 63;
    const int q = idx >> 6;
    const int ks = q & 1, ni = q >> 1;
    const int col = ni * 16 + (lane & 15);
    __half vals[8];
    #pragma unroll
    for (int j = 0; j < 8; ++j) {
        const int k = ks * 32 + (lane >> 4) * 8 + j;
        vals[j] = __float2half(Wd[(size_t)k * 128 + col]);
    }
    bpd[idx] = *reinterpret_cast<const uint4*>(vals);
}

// ---------------------------------------------------------------------------
// rel-staging: 8 lanes/atom; ONE uint4 (8 halves) per lane per neighbor row;
// fp32 accumulate, packed fp16 uint4 store into the MFMA A-tile rel region.
// ---------------------------------------------------------------------------
template<int D, int STRH, int GH>
__device__ __forceinline__ void stage_rel64_m(const __half* __restrict__ xin,
                                              const int* __restrict__ ad,
                                              int j0, int row, int l8,
                                              __half* __restrict__ s_a)
{
    int idxs[D];
    #pragma unroll
    for (int n = 0; n < D; ++n) idxs[n] = ad[(size_t)(j0 + row) * D + n];
    float2 r[4];
    #pragma unroll
    for (int q = 0; q < 4; ++q) r[q] = make_float2(0.f, 0.f);
    for (int n = 0; n < D; ++n) {
        const uint4 f4v = *reinterpret_cast<const uint4*>(xin + (size_t)idxs[n] * 64 + l8 * 8);
        const __half2* hh = reinterpret_cast<const __half2*>(&f4v);
        #pragma unroll
        for (int q = 0; q < 4; ++q) {
            const float2 v = __half22float2(hh[q]);
            r[q].x += v.x; r[q].y += v.y;
        }
    }
    uint4 o;
    unsigned* ou = reinterpret_cast<unsigned*>(&o);
    #pragma unroll
    for (int q = 0; q < 4; ++q) {
        U32H2 u; u.h = h2{(_Float16)r[q].x, (_Float16)r[q].y};
        ou[q] = u.u;
    }
    *reinterpret_cast<uint4*>(&s_a[row * STRH + (GH + l8) * 8]) = o;
}

template<int STRH, int GH>
__device__ __forceinline__ void stage_rel64_rt_m(const __half* __restrict__ xin,
                                                 const int* __restrict__ ad, int d,
                                                 int j0, int row, int l8,
                                                 __half* __restrict__ s_a)
{
    int idxs[10];
    for (int n = 0; n < d; ++n) idxs[n] = ad[(size_t)(j0 + row) * d + n];
    float2 r[4];
    #pragma unroll
    for (int q = 0; q < 4; ++q) r[q] = make_float2(0.f, 0.f);
    for (int n = 0; n < d; ++n) {
        const uint4 f4v = *reinterpret_cast<const uint4*>(xin + (size_t)idxs[n] * 64 + l8 * 8);
        const __half2* hh = reinterpret_cast<const __half2*>(&f4v);
        #pragma unroll
        for (int q = 0; q < 4; ++q) {
            const float2 v = __half22float2(hh[q]);
            r[q].x += v.x; r[q].y += v.y;
        }
    }
    uint4 o;
    unsigned* ou = reinterpret_cast<unsigned*>(&o);
    #pragma unroll
    for (int q = 0; q < 4; ++q) {
        U32H2 u; u.h = h2{(_Float16)r[q].x, (_Float16)r[q].y};
        ou[q] = u.u;
    }
    *reinterpret_cast<uint4*>(&s_a[row * STRH + (GH + l8) * 8]) = o;
}

template<int D, int STRH, int GH>
__device__ __forceinline__ void stage_rel75_m(const __half* __restrict__ xin,
                                              const int* __restrict__ ad,
                                              int j0, int row, int l8,
                                              __half* __restrict__ s_a)
{
    int idxs[D];
    #pragma unroll
    for (int n = 0; n < D; ++n) idxs[n] = ad[(size_t)(j0 + row) * D + n];
    float2 r[4], r2[4];
    #pragma unroll
    for (int q = 0; q < 4; ++q) { r[q] = make_float2(0.f, 0.f); r2[q] = make_float2(0.f, 0.f); }
    for (int n = 0; n < D; ++n) {
        const __half* __restrict__ xr = xin + (size_t)idxs[n] * X16S;
        const uint4 f4v = *reinterpret_cast<const uint4*>(xr + l8 * 8);
        const __half2* hh = reinterpret_cast<const __half2*>(&f4v);
        #pragma unroll
        for (int q = 0; q < 4; ++q) {
            const float2 v = __half22float2(hh[q]);
            r[q].x += v.x; r[q].y += v.y;
        }
        if (l8 < 2) {
            const uint4 g4 = *reinterpret_cast<const uint4*>(xr + 64 + l8 * 8);
            const __half2* t2 = reinterpret_cast<const __half2*>(&g4);
            #pragma unroll
            for (int q = 0; q < 4; ++q) {
                const float2 v = __half22float2(t2[q]);
                r2[q].x += v.x; r2[q].y += v.y;
            }
        }
    }
    uint4 o;
    unsigned* ou = reinterpret_cast<unsigned*>(&o);
    #pragma unroll
    for (int q = 0; q < 4; ++q) {
        U32H2 u; u.h = h2{(_Float16)r[q].x, (_Float16)r[q].y};
        ou[q] = u.u;
    }
    *reinterpret_cast<uint4*>(&s_a[row * STRH + (GH + l8) * 8]) = o;
    if (l8 < 2) {
        uint4 o2;
        unsigned* ou2 = reinterpret_cast<unsigned*>(&o2);
        #pragma unroll
        for (int q = 0; q < 4; ++q) {
            U32H2 u; u.h = h2{(_Float16)r2[q].x, (_Float16)r2[q].y};
            ou2[q] = u.u;
        }
        *reinterpret_cast<uint4*>(&s_a[row * STRH + (GH + 8 + l8) * 8]) = o2;
    }
}

template<int STRH, int GH>
__device__ __forceinline__ void stage_rel75_rt_m(const __half* __restrict__ xin,
                                                 const int* __restrict__ ad, int d,
                                                 int j0, int row, int l8,
                                                 __half* __restrict__ s_a)
{
    int idxs[10];
    for (int n = 0; n < d; ++n) idxs[n] = ad[(size_t)(j0 + row) * d + n];
    float2 r[4], r2[4];
    #pragma unroll
    for (int q = 0; q < 4; ++q) { r[q] = make_float2(0.f, 0.f); r2[q] = make_float2(0.f, 0.f); }
    for (int n = 0; n < d; ++n) {
        const __half* __restrict__ xr = xin + (size_t)idxs[n] * X16S;
        const uint4 f4v = *reinterpret_cast<const uint4*>(xr + l8 * 8);
        const __half2* hh = reinterpret_cast<const __half2*>(&f4v);
        #pragma unroll
        for (int q = 0; q < 4; ++q) {
            const float2 v = __half22float2(hh[q]);
            r[q].x += v.x; r[q].y += v.y;
        }
        if (l8 < 2) {
            const uint4 g4 = *reinterpret_cast<const uint4*>(xr + 64 + l8 * 8);
            const __half2* t2 = reinterpret_cast<const __half2*>(&g4);
            #pragma unroll
            for (int q = 0; q < 4; ++q) {
                const float2 v = __half22float2(t2[q]);
                r2[q].x += v.x; r2[q].y += v.y;
            }
        }
    }
    uint4 o;
    unsigned* ou = reinterpret_cast<unsigned*>(&o);
    #pragma unroll
    for (int q = 0; q < 4; ++q) {
        U32H2 u; u.h = h2{(_Float16)r[q].x, (_Float16)r[q].y};
        ou[q] = u.u;
    }
    *reinterpret_cast<uint4*>(&s_a[row * STRH + (GH + l8) * 8]) = o;
    if (l8 < 2) {
        uint4 o2;
        unsigned* ou2 = reinterpret_cast<unsigned*>(&o2);
        #pragma unroll
        for (int q = 0; q < 4; ++q) {
            U32H2 u; u.h = h2{(_Float16)r2[q].x, (_Float16)r2[q].y};
            ou2[q] = u.u;
        }
        *reinterpret_cast<uint4*>(&s_a[row * STRH + (GH + 8 + l8) * 8]) = o2;
    }
}

// ---------------------------------------------------------------------------
// Merged conv layer, MFMA (r19-proven): A-tile [64][K] fp16 LDS, B pre-packed
// fragments, 8 waves x 2 subtiles x KS mfma_f32_16x16x32_f16.
// ---------------------------------------------------------------------------
template<int CI>
__global__ __launch_bounds__(512) void conv_all_kernel(
    const __half* __restrict__ xin, AdjPtrs adj,
    const uint4* __restrict__ bp, const float* __restrict__ B,
    const float* __restrict__ bng, const float* __restrict__ bnb,
    const float* __restrict__ bnm, const float* __restrict__ bnv,
    __half* __restrict__ out)
{
    constexpr int XS   = (CI == 64) ? 64 : X16S;
    constexpr int GH   = (CI == 64) ? 8 : 10;     // groups (8 halves) per half-K
    constexpr int KS   = GH / 2;                  // K/32 mfma steps
    constexpr int STRH = 16 * GH + 8;             // row stride in halves
    __shared__ __align__(16) __half s_a[64 * STRH];

    int d = 0, rem = blockIdx.x;
    for (;;) { const int nb = (kCounts[d] + 63) >> 6; if (rem < nb) break; rem -= nb; ++d; }
    const int j0 = rem << 6;
    const int nA = min(64, kCounts[d] - j0);
    const int a0 = kStarts[d] + j0;
    const int t = threadIdx.x;
    const int row = t >> 3, l8 = t & 7;

    // ---- stage self rows ----
    if (row < nA) {
        const __half* __restrict__ xr = xin + (size_t)(a0 + row) * XS;
        *reinterpret_cast<uint4*>(&s_a[row * STRH + l8 * 8]) =
            *reinterpret_cast<const uint4*>(xr + l8 * 8);
        if (CI == 75 && l8 < 2)
            *reinterpret_cast<uint4*>(&s_a[row * STRH + 64 + l8 * 8]) =
                *reinterpret_cast<const uint4*>(xr + 64 + l8 * 8);
    }

    // ---- stage rel (neighbor sums) or zero for d=0 ----
    if (d > 0) {
        if (row < nA) {
            const int* __restrict__ adp = adj.p[d - 1];
            if constexpr (CI == 64) {
                switch (d) {
                case 1: stage_rel64_m<1, STRH, GH>(xin, adp, j0, row, l8, s_a); break;
                case 2: stage_rel64_m<2, STRH, GH>(xin, adp, j0, row, l8, s_a); break;
                case 3: stage_rel64_m<3, STRH, GH>(xin, adp, j0, row, l8, s_a); break;
                case 4: stage_rel64_m<4, STRH, GH>(xin, adp, j0, row, l8, s_a); break;
                default: stage_rel64_rt_m<STRH, GH>(xin, adp, d, j0, row, l8, s_a); break;
                }
            } else {
                switch (d) {
                case 1: stage_rel75_m<1, STRH, GH>(xin, adp, j0, row, l8, s_a); break;
                case 2: stage_rel75_m<2, STRH, GH>(xin, adp, j0, row, l8, s_a); break;
                case 3: stage_rel75_m<3, STRH, GH>(xin, adp, j0, row, l8, s_a); break;
                case 4: stage_rel75_m<4, STRH, GH>(xin, adp, j0, row, l8, s_a); break;
                default: stage_rel75_rt_m<STRH, GH>(xin, adp, d, j0, row, l8, s_a); break;
                }
            }
        }
    } else {
        const uint4 z4 = make_uint4(0u, 0u, 0u, 0u);
        *reinterpret_cast<uint4*>(&s_a[row * STRH + (GH + l8) * 8]) = z4;
        if (CI == 75 && l8 < 2)
            *reinterpret_cast<uint4*>(&s_a[row * STRH + (GH + 8 + l8) * 8]) = z4;
    }
    __syncthreads();

    // ---- MFMA: wave w -> subtiles 2w, 2w+1 of the 4x4 16x16 grid ----
    const int lane = t & 63, w = t >> 6;
    const int lr = lane & 15, lg = lane >> 4;

    #pragma unroll
    for (int sb = 0; sb < 2; ++sb) {
        const int s = 2 * w + sb;
        const int mi = s >> 2, ni = s & 3;
        f4 acc = {0.f, 0.f, 0.f, 0.f};
        #pragma unroll
        for (int ks = 0; ks < KS; ++ks) {
            const h8 av = *reinterpret_cast<const h8*>(
                &s_a[(mi * 16 + lr) * STRH + (ks * 4 + lg) * 8]);
            uint4 braw = bp[((d * 4 + ni) * KS + ks) * 64 + lane];
            const h8 bv = *reinterpret_cast<const h8*>(&braw);
            acc = __builtin_amdgcn_mfma_f32_16x16x32_f16(av, bv, acc, 0, 0, 0);
        }
        const int ch = ni * 16 + lr;
        const float bias = (d == 0) ? B[20 * 64 + ch]
                                    : (B[(2 * (d - 1)) * 64 + ch] + B[(2 * d - 1) * 64 + ch]);
        const float scl = rsqrtf(bnv[ch] + 1e-3f) * bng[ch];
        const float sht = bnb[ch] - bnm[ch] * scl;
        #pragma unroll
        for (int r = 0; r < 4; ++r) {
            const int atom = mi * 16 + lg * 4 + r;
            if (atom < nA)
                out[(size_t)(a0 + atom) * 64 + ch] =
                    __float2half(fmaf(fmaxf(acc[r] + bias, 0.f), scl, sht));
        }
    }
}

// ---------------------------------------------------------------------------
// Merged pool layer (fp16), conv-style gather: 8 lanes/atom, ONE float4
// per lane per row; 32 atoms per block; packed fp16 stores.
// ---------------------------------------------------------------------------
template<int D>
__device__ __forceinline__ void pool_rows(const __half* __restrict__ z,
                                          const int* __restrict__ ad, int j, int g8,
                                          float2 mx[4])
{
    int idxs[D];
    #pragma unroll
    for (int n = 0; n < D; ++n) idxs[n] = ad[(size_t)j * D + n];
    for (int n = 0; n < D; ++n) {
        const float4 f4v = *reinterpret_cast<const float4*>(z + (size_t)idxs[n] * 64 + g8 * 8);
        const __half2* hh = reinterpret_cast<const __half2*>(&f4v);
        #pragma unroll
        for (int q = 0; q < 4; ++q) {
            const float2 v = __half22float2(hh[q]);
            mx[q].x = fmaxf(mx[q].x, v.x);
            mx[q].y = fmaxf(mx[q].y, v.y);
        }
    }
}

__device__ __forceinline__ void pool_rows_rt(const __half* __restrict__ z,
                                             const int* __restrict__ ad, int d, int j, int g8,
                                             float2 mx[4])
{
    int idxs[10];
    for (int n = 0; n < d; ++n) idxs[n] = ad[(size_t)j * d + n];
    for (int n = 0; n < d; ++n) {
        const float4 f4v = *reinterpret_cast<const float4*>(z + (size_t)idxs[n] * 64 + g8 * 8);
        const __half2* hh = reinterpret_cast<const __half2*>(&f4v);
        #pragma unroll
        for (int q = 0; q < 4; ++q) {
            const float2 v = __half22float2(hh[q]);
            mx[q].x = fmaxf(mx[q].x, v.x);
            mx[q].y = fmaxf(mx[q].y, v.y);
        }
    }
}

__global__ __launch_bounds__(256) void pool_all_kernel(
    const __half* __restrict__ z, AdjPtrs adj, __half* __restrict__ p)
{
    int d = 0, rem = blockIdx.x;
    for (;;) { const int nb = (kCounts[d] + 31) >> 5; if (rem < nb) break; rem -= nb; ++d; }
    const int t = threadIdx.x;
    const int j = rem * 32 + (t >> 3);
    if (j >= kCounts[d]) return;
    const int g8 = t & 7;
    const int a = kStarts[d] + j;

    const float4 s4 = *reinterpret_cast<const float4*>(z + (size_t)a * 64 + g8 * 8);
    const __half2* sh2 = reinterpret_cast<const __half2*>(&s4);
    float2 mx[4];
    #pragma unroll
    for (int q = 0; q < 4; ++q) mx[q] = __half22float2(sh2[q]);

    if (d > 0) {
        const int* __restrict__ ad = adj.p[d - 1];
        switch (d) {
        case 1:  pool_rows<1 >(z, ad, j, g8, mx); break;
        case 2:  pool_rows<2 >(z, ad, j, g8, mx); break;
        case 3:  pool_rows<3 >(z, ad, j, g8, mx); break;
        case 4:  pool_rows<4 >(z, ad, j, g8, mx); break;
        default: pool_rows_rt(z, ad, d, j, g8, mx); break;
        }
    }

    union { __half2 h[4]; float4 f; } u;
    #pragma unroll
    for (int q = 0; q < 4; ++q) u.h[q] = __floats2half2_rn(mx[q].x, mx[q].y);
    *reinterpret_cast<float4*>(p + (size_t)a * 64 + g8 * 8) = u.f;
}

// ---------------------------------------------------------------------------
// Counting sort by membership: hist -> scan -> scatter (+ per-position seg id).
// ---------------------------------------------------------------------------
__global__ __launch_bounds__(256) void hist_kernel(const int* __restrict__ mem,
                                                   int* __restrict__ cnt)
{
    const int a = blockIdx.x * 256 + threadIdx.x;
    if (a < NATOMS) atomicAdd(&cnt[mem[a]], 1);
}

__global__ __launch_bounds__(512) void scan_kernel(const int* __restrict__ cnt,
                                                   int* __restrict__ off,
                                                   int* __restrict__ cur)
{
    __shared__ int part[512];
    const int t = threadIdx.x;
    const int base = t * 64;
    int s = 0;
    #pragma unroll 8
    for (int i = 0; i < 64; ++i) s += cnt[base + i];
    part[t] = s;
    __syncthreads();
    for (int o = 1; o < 512; o <<= 1) {
        int v = (t >= o) ? part[t - o] : 0;
        __syncthreads();
        part[t] += v;
        __syncthreads();
    }
    int run = (t == 0) ? 0 : part[t - 1];
    for (int i = 0; i < 64; ++i) {
        off[base + i] = run;
        cur[base + i] = run;
        run += cnt[base + i];
    }
}

__global__ __launch_bounds__(256) void scatter_kernel(const int* __restrict__ mem,
                                                      int* __restrict__ cur,
                                                      int* __restrict__ sorted,
                                                      int* __restrict__ sid)
{
    const int a = blockIdx.x * 256 + threadIdx.x;
    if (a < NATOMS) {
        const int m = mem[a];
        const int pos = atomicAdd(&cur[m], 1);
        sorted[pos] = a;
        sid[pos] = m;
    }
}

__global__ void seg_init_kernel(float* __restrict__ segS, unsigned* __restrict__ segM)
{
    const int n = NBATCH * 128;
    for (int i = blockIdx.x * blockDim.x + threadIdx.x; i < n; i += gridDim.x * blockDim.x) {
        segS[i] = 0.f;
        segM[i] = 0x007FFFFFu; // enc(-inf)
    }
}

// ---------------------------------------------------------------------------
// Dense 64->128 + ReLU + BN2 over SORTED atoms, MFMA: A [64x64] fp16 LDS
// (row stride 72 halves, conv-proven fragment pattern), B pre-packed
// fragments. 4 waves x 8 column-subtiles x 2 k-steps = 64 mfma/block
// (replaces r18's 1024 fdot2/thread: 208us VALU-bound). Epilogue: per-half
// vbuf scan + boundary atomics (unchanged).
// ---------------------------------------------------------------------------
__global__ __launch_bounds__(256) void dense_seg_sorted_kernel(
    const __half* __restrict__ p,
    const int* __restrict__ sorted, const int* __restrict__ sid,
    const uint4* __restrict__ bpd, const float* __restrict__ bd,
    const float* __restrict__ bng, const float* __restrict__ bnb,
    const float* __restrict__ bnm, const float* __restrict__ bnv,
    float* __restrict__ segS, unsigned* __restrict__ segM)
{
    __shared__ __align__(16) __half s_a[64 * 72];     // 9.2KB A-tile
    __shared__ __align__(16) float vbuf[64 * 64];     // 16KB half-channel buffer
    __shared__ int s_idx[64];
    __shared__ int s_sid[64];

    const int t = threadIdx.x;
    const int pos0 = blockIdx.x * 64;   // NATOMS = 15625 * 64 exactly

    if (t < 64) {
        s_idx[t] = sorted[pos0 + t];
        s_sid[t] = sid[pos0 + t];
    }
    __syncthreads();

    // stage: 8 lanes/row, one uint4 (8 halves) each, two row-groups of 32
    {
        const int row = t >> 3, l8 = t & 7;   // rows 0..31
        #pragma unroll
        for (int half = 0; half < 2; ++half) {
            const int rr = row + half * 32;
            *reinterpret_cast<uint4*>(&s_a[rr * 72 + l8 * 8]) =
                *reinterpret_cast<const uint4*>(p + (size_t)s_idx[rr] * 64 + l8 * 8);
        }
    }
    __syncthreads();

    // MFMA: wave w owns atom-rows w*16..w*16+15, all 8 column subtiles
    const int lane = t & 63, w = t >> 6;
    const int lr = lane & 15, lg = lane >> 4;

    h8 av[2];
    #pragma unroll
    for (int ks = 0; ks < 2; ++ks)
        av[ks] = *reinterpret_cast<const h8*>(&s_a[(w * 16 + lr) * 72 + (ks * 4 + lg) * 8]);

    f4 acc[8];
    #pragma unroll
    for (int ni = 0; ni < 8; ++ni) {
        acc[ni] = f4{0.f, 0.f, 0.f, 0.f};
        #pragma unroll
        for (int ks = 0; ks < 2; ++ks) {
            uint4 braw = bpd[(ni * 2 + ks) * 64 + lane];
            const h8 bv = *reinterpret_cast<const h8*>(&braw);
            acc[ni] = __builtin_amdgcn_mfma_f32_16x16x32_f16(av[ks], bv, acc[ni], 0, 0, 0);
        }
    }

    // epilogue per 64-channel half: BN -> vbuf -> segmented scan + atomics
    #pragma unroll
    for (int half = 0; half < 2; ++half) {
        #pragma unroll
        for (int q = 0; q < 4; ++q) {
            const int ni = half * 4 + q;
            const int ch = ni * 16 + lr;
            const float bias = bd[ch];
            const float scl = rsqrtf(bnv[ch] + 1e-3f) * bng[ch];
            const float sht = bnb[ch] - bnm[ch] * scl;
            #pragma unroll
            for (int r = 0; r < 4; ++r) {
                const int atom = w * 16 + lg * 4 + r;
                vbuf[atom * 64 + (ch & 63)] =
                    fmaf(fmaxf(acc[ni][r] + bias, 0.f), scl, sht);
            }
        }
        __syncthreads();

        const int c = t & 63;
        const int rbase = (t >> 6) * 16;
        const int gch = half * 64 + c;
        int cur = s_sid[rbase];
        float s = 0.f, mx = -INFINITY;
        for (int r = rbase; r < rbase + 16; ++r) {
            const int sd = s_sid[r];
            if (sd != cur) {
                atomicAdd(&segS[(size_t)cur * 128 + gch], s);
                atomicMax(&segM[(size_t)cur * 128 + gch], enc_f32(mx));
                cur = sd; s = 0.f; mx = -INFINITY;
            }
            const float v = vbuf[r * 64 + c];
            s += v;
            mx = fmaxf(mx, v);
        }
        atomicAdd(&segS[(size_t)cur * 128 + gch], s);
        atomicMax(&segM[(size_t)cur * 128 + gch], enc_f32(mx));
        __syncthreads();
    }
}

__global__ void nf_fin_kernel(const float* __restrict__ segS,
                              const unsigned* __restrict__ segM,
                              float* __restrict__ nf)
{
    const int i = blockIdx.x * blockDim.x + threadIdx.x; // < NBATCH*128
    const int m = i >> 7, c = i & 127;
    nf[(size_t)m * 256 + c]       = tanhf(segS[i]);
    nf[(size_t)m * 256 + 128 + c] = tanhf(dec_f32(segM[i]));
}

// fd0: h = relu(nf @ W + b), 32768x256 @ 256x256. 64x64 tile per block.
__global__ __launch_bounds__(256) void fd0_kernel(
    const float* __restrict__ nf, const float* __restrict__ W, const float* __restrict__ b,
    float* __restrict__ h)
{
    __shared__ __align__(16) float sx[256][64];
    const int t = threadIdx.x;
    const int r0 = (blockIdx.x >> 2) * 64;
    const int c0 = (blockIdx.x & 3) * 64;
    for (int ch = 0; ch < 4; ++ch) {
        for (int v = t; v < 1024; v += 256) {
            const int row = v >> 4, k0 = (v & 15) * 4 + ch * 64;
            const float4 r = *reinterpret_cast<const float4*>(nf + (size_t)(r0 + row) * 256 + k0);
            sx[k0 + 0][swzS64d(row, k0 + 0)] = r.x;
            sx[k0 + 1][swzS64d(row, k0 + 1)] = r.y;
            sx[k0 + 2][swzS64d(row, k0 + 2)] = r.z;
            sx[k0 + 3][swzS64d(row, k0 + 3)] = r.w;
        }
    }
    __syncthreads();

    const int c4 = (t & 15) * 4;
    const int a4 = (t >> 4) * 4;

    float acc[4][4];
    #pragma unroll
    for (int i = 0; i < 4; ++i)
        #pragma unroll
        for (int j = 0; j < 4; ++j) acc[i][j] = 0.f;

    for (int k = 0; k < 256; ++k) {
        const int sw = ((k >> 2) & 7) << 2;
        const float4 sv = *reinterpret_cast<const float4*>(&sx[k][a4 ^ sw]);
        const float4 w = *reinterpret_cast<const float4*>(W + (size_t)k * 256 + c0 + c4);
        const float ss[4] = {sv.x, sv.y, sv.z, sv.w};
        #pragma unroll
        for (int i = 0; i < 4; ++i) {
            acc[i][0] = fmaf(ss[i], w.x, acc[i][0]);
            acc[i][1] = fmaf(ss[i], w.y, acc[i][1]);
            acc[i][2] = fmaf(ss[i], w.z, acc[i][2]);
            acc[i][3] = fmaf(ss[i], w.w, acc[i][3]);
        }
    }

    const float4 bb = *reinterpret_cast<const float4*>(b + c0 + c4);
    const float bi[4] = {bb.x, bb.y, bb.z, bb.w};
    #pragma unroll
    for (int i = 0; i < 4; ++i) {
        float4 o;
        o.x = fmaxf(acc[i][0] + bi[0], 0.f);
        o.y = fmaxf(acc[i][1] + bi[1], 0.f);
        o.z = fmaxf(acc[i][2] + bi[2], 0.f);
        o.w = fmaxf(acc[i][3] + bi[3], 0.f);
        *reinterpret_cast<float4*>(h + (size_t)(r0 + a4 + i) * 256 + c0 + c4) = o;
    }
}

// rd: logits = h @ W + b (256->24), then pairwise softmax.
__global__ __launch_bounds__(384) void rd_kernel(
    const float* __restrict__ h, const float* __restrict__ W, const float* __restrict__ b,
    float* __restrict__ outP, float* __restrict__ outL)
{
    __shared__ float sh[32][257];
    const int t = threadIdx.x;
    const int r0 = blockIdx.x * 32;
    for (int e = t; e < 32 * 256; e += 384) {
        const int ri = e >> 8, k = e & 255;
        sh[ri][k] = h[(size_t)(r0 + ri) * 256 + k];
    }
    __syncthreads();
    const int r = t / 12, pj = t % 12;
    float a0 = b[2 * pj], a1 = b[2 * pj + 1];
    for (int k = 0; k < 256; ++k) {
        const float hv = sh[r][k];
        a0 = fmaf(hv, W[k * 24 + 2 * pj],     a0);
        a1 = fmaf(hv, W[k * 24 + 2 * pj + 1], a1);
    }
    const size_t m = (size_t)(r0 + r);
    outL[m * 24 + 2 * pj]     = a0;
    outL[m * 24 + 2 * pj + 1] = a1;
    const float mx = fmaxf(a0, a1);
    const float e0 = expf(a0 - mx), e1 = expf(a1 - mx);
    const float inv = 1.f / (e0 + e1);
    outP[m * 24 + 2 * pj]     = e0 * inv;
    outP[m * 24 + 2 * pj + 1] = e1 * inv;
}

} // namespace

extern "C" void kernel_launch(void* const* d_in, const int* in_sizes, int n_in,
                              void* d_out, int out_size, void* d_ws, size_t ws_size,
                              hipStream_t stream)
{
    const float* x       = (const float*)d_in[0];
    const int*   mem     = (const int*)d_in[2];
    AdjPtrs adj;
    for (int d = 0; d < 10; ++d) adj.p[d] = (const int*)d_in[4 + d];
    const float* gc0_W = (const float*)d_in[14];
    const float* gc0_b = (const float*)d_in[15];
    const float* gc1_W = (const float*)d_in[16];
    const float* gc1_b = (const float*)d_in[17];
    const float* bn0g = (const float*)d_in[18], *bn0b = (const float*)d_in[19];
    const float* bn0m = (const float*)d_in[20], *bn0v = (const float*)d_in[21];
    const float* bn1g = (const float*)d_in[22], *bn1b = (const float*)d_in[23];
    const float* bn1m = (const float*)d_in[24], *bn1v = (const float*)d_in[25];
    const float* bn2g = (const float*)d_in[26], *bn2b = (const float*)d_in[27];
    const float* bn2m = (const float*)d_in[28], *bn2v = (const float*)d_in[29];
    const float* dW   = (const float*)d_in[30], *db   = (const float*)d_in[31];
    const float* fW   = (const float*)d_in[32], *fb   = (const float*)d_in[33];
    const float* rW   = (const float*)d_in[34], *rb   = (const float*)d_in[35];

    __half* z16 = (__half*)d_ws;                               // 1M x 64
    __half* p16 = z16 + (size_t)NATOMS * 64;                   // 1M x 64
    __half* x16 = p16 + (size_t)NATOMS * 64;                   // 1M x 80
    float*  hbuf = (float*)(x16 + (size_t)NATOMS * X16S);
    float*  segS = hbuf + (size_t)NBATCH * 256;
    unsigned* segM = (unsigned*)(segS + (size_t)NBATCH * 128);
    int*    cnt    = (int*)(segM + (size_t)NBATCH * 128);
    int*    offp   = cnt + NBATCH;
    int*    cur    = offp + NBATCH;
    int*    sorted = cur + NBATCH;
    int*    sid    = sorted + NATOMS;
    uint4*  bp0    = (uint4*)(sid + NATOMS);                   // 11*4*5*64 uint4
    uint4*  bp1    = bp0 + 11 * 4 * 5 * 64;                    // 11*4*4*64 uint4
    uint4*  bpd    = bp1 + 11 * 4 * 4 * 64;                    // 8*2*64 uint4

    float* outP = (float*)d_out;
    float* outL = outP + (size_t)NBATCH * 24;
    float* nfb  = outL + (size_t)NBATCH * 24;

    int convBlocks = 0, poolBlocks = 0;
    for (int d = 0; d <= 10; ++d) {
        convBlocks += (kCounts[d] + 63) >> 6;
        poolBlocks += (kCounts[d] + 31) >> 5;
    }

    // one-time conversions: x -> fp16 padded; weights -> MFMA B-fragments
    cvt_kernel<<<(NATOMS + 15) / 16, 256, 0, stream>>>(x, x16);
    packB_kernel<<<55, 256, 0, stream>>>(gc0_W, bp0, 75, 10, 5);
    packB_kernel<<<44, 256, 0, stream>>>(gc1_W, bp1, 64, 8, 4);
    packBd_kernel<<<4, 256, 0, stream>>>(dW, bpd);

    // counting sort by membership + segment accumulator init
    hipMemsetAsync(cnt, 0, NBATCH * sizeof(int), stream);
    hist_kernel<<<(NATOMS + 255) / 256, 256, 0, stream>>>(mem, cnt);
    scan_kernel<<<1, 512, 0, stream>>>(cnt, offp, cur);
    scatter_kernel<<<(NATOMS + 255) / 256, 256, 0, stream>>>(mem, cur, sorted, sid);
    seg_init_kernel<<<2048, 256, 0, stream>>>(segS, segM);

    // layer 1: conv(75->64)+relu+bn0 -> pool
    conv_all_kernel<75><<<convBlocks, 512, 0, stream>>>(x16, adj, bp0, gc0_b,
                                                        bn0g, bn0b, bn0m, bn0v, z16);
    pool_all_kernel<<<poolBlocks, 256, 0, stream>>>(z16, adj, p16);

    // layer 2: conv(64->64)+relu+bn1 -> pool
    conv_all_kernel<64><<<convBlocks, 512, 0, stream>>>(p16, adj, bp1, gc1_b,
                                                        bn1g, bn1b, bn1m, bn1v, z16);
    pool_all_kernel<<<poolBlocks, 256, 0, stream>>>(z16, adj, p16);

    // dense+relu+bn2 over sorted atoms with fused segmented sum/max (MFMA)
    dense_seg_sorted_kernel<<<NATOMS / 64, 256, 0, stream>>>(
        p16, sorted, sid, bpd, db, bn2g, bn2b, bn2m, bn2v, segS, segM);
    // nf = tanh(concat(sum, max))
    nf_fin_kernel<<<(NBATCH * 128) / 256, 256, 0, stream>>>(segS, segM, nfb);
    // h = relu(nf @ fd0_W + fd0_b)
    fd0_kernel<<<(NBATCH / 64) * 4, 256, 0, stream>>>(nfb, fW, fb, hbuf);
    // logits + softmax
    rd_kernel<<<NBATCH / 32, 384, 0, stream>>>(hbuf, rW, rb, outP, outL);
}

// Round 21
// 979.703 us; speedup vs baseline: 2.0779x; 1.0423x over previous
//
#include <hip/hip_runtime.h>
#include <hip/hip_fp16.h>
#include <math.h>

namespace {

constexpr int NATOMS = 1000000;
constexpr int NBATCH = 32768;
constexpr int kCounts[11] = {10000,250000,300000,250000,120000,40000,15000,8000,4000,2000,1000};
constexpr int kStarts[11] = {0,10000,260000,560000,810000,930000,970000,985000,993000,997000,999000};
constexpr int X16S = 80;   // padded fp16 row stride for x (75 ch -> 160B rows)

struct AdjPtrs { const int* p[10]; };

typedef _Float16 h2 __attribute__((ext_vector_type(2)));
typedef _Float16 h8 __attribute__((ext_vector_type(8)));
typedef float    f4 __attribute__((ext_vector_type(4)));
union U32H2 { unsigned u; h2 h; };

__device__ __forceinline__ unsigned enc_f32(float x) {
    unsigned u = __float_as_uint(x);
    return (u & 0x80000000u) ? ~u : (u | 0x80000000u);
}
__device__ __forceinline__ float dec_f32(unsigned u) {
    return (u & 0x80000000u) ? __uint_as_float(u & 0x7FFFFFFFu) : __uint_as_float(~u);
}

// ---------------------------------------------------------------------------
// x fp32 [1M][75] -> x16 fp16 [1M][80] (zero-padded). 16 rows per block.
// ---------------------------------------------------------------------------
__global__ __launch_bounds__(256) void cvt_kernel(const float* __restrict__ x,
                                                  __half* __restrict__ x16)
{
    const int row = blockIdx.x * 16 + (threadIdx.x >> 4);
    const int l16 = threadIdx.x & 15;
    if (row >= NATOMS) return;
    const float* __restrict__ xr = x + (size_t)row * 75;
    __half* __restrict__ xo = x16 + (size_t)row * X16S;
    #pragma unroll
    for (int q = 0; q < 5; ++q) {
        const int c = l16 + 16 * q;
        xo[c] = __float2half((c < 75) ? xr[c] : 0.f);
    }
}

// ---------------------------------------------------------------------------
// Pack conv weights into MFMA B-fragment order (k-map matches A fragment).
// ---------------------------------------------------------------------------
__global__ __launch_bounds__(256) void packB_kernel(const float* __restrict__ W,
                                                    uint4* __restrict__ bp,
                                                    int CI, int GH, int KS)
{
    const int total = 11 * 4 * KS * 64;
    const int idx = blockIdx.x * 256 + threadIdx.x;
    if (idx >= total) return;
    const int lane = idx & 63;
    int q = idx >> 6;
    const int ks = q % KS; q /= KS;
    const int ni = q & 3;
    const int deg = q >> 2;
    const int col = ni * 16 + (lane & 15);
    __half vals[8];
    #pragma unroll
    for (int j = 0; j < 8; ++j) {
        const int k = ks * 32 + (lane >> 4) * 8 + j;
        float v = 0.f;
        if (k < GH * 8) {
            if (k < CI) {
                const int m = (deg == 0) ? 20 : (2 * deg - 1);
                v = W[((size_t)m * CI + k) * 64 + col];
            }
        } else {
            const int kk = k - GH * 8;
            if (deg > 0 && kk < CI)
                v = W[((size_t)(2 * (deg - 1)) * CI + kk) * 64 + col];
        }
        vals[j] = __float2half(v);
    }
    bp[idx] = *reinterpret_cast<const uint4*>(vals);
}

// dense_W fp32 [64][128] -> MFMA B-fragments: bpd[(ni*2+ks)*64+lane], ni 0..7
__global__ __launch_bounds__(256) void packBd_kernel(const float* __restrict__ Wd,
                                                     uint4* __restrict__ bpd)
{
    const int idx = blockIdx.x * 256 + threadIdx.x;   // < 8*2*64
    if (idx >= 8 * 2 * 64) return;
    const int lane = idx & 63;
    const int q = idx >> 6;
    const int ks = q & 1, ni = q >> 1;
    const int col = ni * 16 + (lane & 15);
    __half vals[8];
    #pragma unroll
    for (int j = 0; j < 8; ++j) {
        const int k = ks * 32 + (lane >> 4) * 8 + j;
        vals[j] = __float2half(Wd[(size_t)k * 128 + col]);
    }
    bpd[idx] = *reinterpret_cast<const uint4*>(vals);
}

// fd0_W fp32 [256][256] -> MFMA B-fragments: bpf[(ni*8+ks)*64+lane], ni 0..15
__global__ __launch_bounds__(256) void packBf_kernel(const float* __restrict__ Wf,
                                                     uint4* __restrict__ bpf)
{
    const int idx = blockIdx.x * 256 + threadIdx.x;   // < 16*8*64
    if (idx >= 16 * 8 * 64) return;
    const int lane = idx & 63;
    const int q = idx >> 6;
    const int ks = q & 7, ni = q >> 3;
    const int col = ni * 16 + (lane & 15);
    __half vals[8];
    #pragma unroll
    for (int j = 0; j < 8; ++j) {
        const int k = ks * 32 + (lane >> 4) * 8 + j;
        vals[j] = __float2half(Wf[(size_t)k * 256 + col]);
    }
    bpf[idx] = *reinterpret_cast<const uint4*>(vals);
}

// ---------------------------------------------------------------------------
// rel-staging: 8 lanes/atom; ONE uint4 (8 halves) per lane per neighbor row;
// fp32 accumulate, packed fp16 uint4 store into the MFMA A-tile rel region.
// ---------------------------------------------------------------------------
template<int D, int STRH, int GH>
__device__ __forceinline__ void stage_rel64_m(const __half* __restrict__ xin,
                                              const int* __restrict__ ad,
                                              int j0, int row, int l8,
                                              __half* __restrict__ s_a)
{
    int idxs[D];
    #pragma unroll
    for (int n = 0; n < D; ++n) idxs[n] = ad[(size_t)(j0 + row) * D + n];
    float2 r[4];
    #pragma unroll
    for (int q = 0; q < 4; ++q) r[q] = make_float2(0.f, 0.f);
    for (int n = 0; n < D; ++n) {
        const uint4 f4v = *reinterpret_cast<const uint4*>(xin + (size_t)idxs[n] * 64 + l8 * 8);
        const __half2* hh = reinterpret_cast<const __half2*>(&f4v);
        #pragma unroll
        for (int q = 0; q < 4; ++q) {
            const float2 v = __half22float2(hh[q]);
            r[q].x += v.x; r[q].y += v.y;
        }
    }
    uint4 o;
    unsigned* ou = reinterpret_cast<unsigned*>(&o);
    #pragma unroll
    for (int q = 0; q < 4; ++q) {
        U32H2 u; u.h = h2{(_Float16)r[q].x, (_Float16)r[q].y};
        ou[q] = u.u;
    }
    *reinterpret_cast<uint4*>(&s_a[row * STRH + (GH + l8) * 8]) = o;
}

template<int STRH, int GH>
__device__ __forceinline__ void stage_rel64_rt_m(const __half* __restrict__ xin,
                                                 const int* __restrict__ ad, int d,
                                                 int j0, int row, int l8,
                                                 __half* __restrict__ s_a)
{
    int idxs[10];
    for (int n = 0; n < d; ++n) idxs[n] = ad[(size_t)(j0 + row) * d + n];
    float2 r[4];
    #pragma unroll
    for (int q = 0; q < 4; ++q) r[q] = make_float2(0.f, 0.f);
    for (int n = 0; n < d; ++n) {
        const uint4 f4v = *reinterpret_cast<const uint4*>(xin + (size_t)idxs[n] * 64 + l8 * 8);
        const __half2* hh = reinterpret_cast<const __half2*>(&f4v);
        #pragma unroll
        for (int q = 0; q < 4; ++q) {
            const float2 v = __half22float2(hh[q]);
            r[q].x += v.x; r[q].y += v.y;
        }
    }
    uint4 o;
    unsigned* ou = reinterpret_cast<unsigned*>(&o);
    #pragma unroll
    for (int q = 0; q < 4; ++q) {
        U32H2 u; u.h = h2{(_Float16)r[q].x, (_Float16)r[q].y};
        ou[q] = u.u;
    }
    *reinterpret_cast<uint4*>(&s_a[row * STRH + (GH + l8) * 8]) = o;
}

template<int D, int STRH, int GH>
__device__ __forceinline__ void stage_rel75_m(const __half* __restrict__ xin,
                                              const int* __restrict__ ad,
                                              int j0, int row, int l8,
                                              __half* __restrict__ s_a)
{
    int idxs[D];
    #pragma unroll
    for (int n = 0; n < D; ++n) idxs[n] = ad[(size_t)(j0 + row) * D + n];
    float2 r[4], r2[4];
    #pragma unroll
    for (int q = 0; q < 4; ++q) { r[q] = make_float2(0.f, 0.f); r2[q] = make_float2(0.f, 0.f); }
    for (int n = 0; n < D; ++n) {
        const __half* __restrict__ xr = xin + (size_t)idxs[n] * X16S;
        const uint4 f4v = *reinterpret_cast<const uint4*>(xr + l8 * 8);
        const __half2* hh = reinterpret_cast<const __half2*>(&f4v);
        #pragma unroll
        for (int q = 0; q < 4; ++q) {
            const float2 v = __half22float2(hh[q]);
            r[q].x += v.x; r[q].y += v.y;
        }
        if (l8 < 2) {
            const uint4 g4 = *reinterpret_cast<const uint4*>(xr + 64 + l8 * 8);
            const __half2* t2 = reinterpret_cast<const __half2*>(&g4);
            #pragma unroll
            for (int q = 0; q < 4; ++q) {
                const float2 v = __half22float2(t2[q]);
                r2[q].x += v.x; r2[q].y += v.y;
            }
        }
    }
    uint4 o;
    unsigned* ou = reinterpret_cast<unsigned*>(&o);
    #pragma unroll
    for (int q = 0; q < 4; ++q) {
        U32H2 u; u.h = h2{(_Float16)r[q].x, (_Float16)r[q].y};
        ou[q] = u.u;
    }
    *reinterpret_cast<uint4*>(&s_a[row * STRH + (GH + l8) * 8]) = o;
    if (l8 < 2) {
        uint4 o2;
        unsigned* ou2 = reinterpret_cast<unsigned*>(&o2);
        #pragma unroll
        for (int q = 0; q < 4; ++q) {
            U32H2 u; u.h = h2{(_Float16)r2[q].x, (_Float16)r2[q].y};
            ou2[q] = u.u;
        }
        *reinterpret_cast<uint4*>(&s_a[row * STRH + (GH + 8 + l8) * 8]) = o2;
    }
}

template<int STRH, int GH>
__device__ __forceinline__ void stage_rel75_rt_m(const __half* __restrict__ xin,
                                                 const int* __restrict__ ad, int d,
                                                 int j0, int row, int l8,
                                                 __half* __restrict__ s_a)
{
    int idxs[10];
    for (int n = 0; n < d; ++n) idxs[n] = ad[(size_t)(j0 + row) * d + n];
    float2 r[4], r2[4];
    #pragma unroll
    for (int q = 0; q < 4; ++q) { r[q] = make_float2(0.f, 0.f); r2[q] = make_float2(0.f, 0.f); }
    for (int n = 0; n < d; ++n) {
        const __half* __restrict__ xr = xin + (size_t)idxs[n] * X16S;
        const uint4 f4v = *reinterpret_cast<const uint4*>(xr + l8 * 8);
        const __half2* hh = reinterpret_cast<const __half2*>(&f4v);
        #pragma unroll
        for (int q = 0; q < 4; ++q) {
            const float2 v = __half22float2(hh[q]);
            r[q].x += v.x; r[q].y += v.y;
        }
        if (l8 < 2) {
            const uint4 g4 = *reinterpret_cast<const uint4*>(xr + 64 + l8 * 8);
            const __half2* t2 = reinterpret_cast<const __half2*>(&g4);
            #pragma unroll
            for (int q = 0; q < 4; ++q) {
                const float2 v = __half22float2(t2[q]);
                r2[q].x += v.x; r2[q].y += v.y;
            }
        }
    }
    uint4 o;
    unsigned* ou = reinterpret_cast<unsigned*>(&o);
    #pragma unroll
    for (int q = 0; q < 4; ++q) {
        U32H2 u; u.h = h2{(_Float16)r[q].x, (_Float16)r[q].y};
        ou[q] = u.u;
    }
    *reinterpret_cast<uint4*>(&s_a[row * STRH + (GH + l8) * 8]) = o;
    if (l8 < 2) {
        uint4 o2;
        unsigned* ou2 = reinterpret_cast<unsigned*>(&o2);
        #pragma unroll
        for (int q = 0; q < 4; ++q) {
            U32H2 u; u.h = h2{(_Float16)r2[q].x, (_Float16)r2[q].y};
            ou2[q] = u.u;
        }
        *reinterpret_cast<uint4*>(&s_a[row * STRH + (GH + 8 + l8) * 8]) = o2;
    }
}

// ---------------------------------------------------------------------------
// Merged conv layer, MFMA (r19-proven): A-tile [64][K] fp16 LDS, B pre-packed
// fragments, 8 waves x 2 subtiles x KS mfma_f32_16x16x32_f16.
// ---------------------------------------------------------------------------
template<int CI>
__global__ __launch_bounds__(512) void conv_all_kernel(
    const __half* __restrict__ xin, AdjPtrs adj,
    const uint4* __restrict__ bp, const float* __restrict__ B,
    const float* __restrict__ bng, const float* __restrict__ bnb,
    const float* __restrict__ bnm, const float* __restrict__ bnv,
    __half* __restrict__ out)
{
    constexpr int XS   = (CI == 64) ? 64 : X16S;
    constexpr int GH   = (CI == 64) ? 8 : 10;     // groups (8 halves) per half-K
    constexpr int KS   = GH / 2;                  // K/32 mfma steps
    constexpr int STRH = 16 * GH + 8;             // row stride in halves
    __shared__ __align__(16) __half s_a[64 * STRH];

    int d = 0, rem = blockIdx.x;
    for (;;) { const int nb = (kCounts[d] + 63) >> 6; if (rem < nb) break; rem -= nb; ++d; }
    const int j0 = rem << 6;
    const int nA = min(64, kCounts[d] - j0);
    const int a0 = kStarts[d] + j0;
    const int t = threadIdx.x;
    const int row = t >> 3, l8 = t & 7;

    // ---- stage self rows ----
    if (row < nA) {
        const __half* __restrict__ xr = xin + (size_t)(a0 + row) * XS;
        *reinterpret_cast<uint4*>(&s_a[row * STRH + l8 * 8]) =
            *reinterpret_cast<const uint4*>(xr + l8 * 8);
        if (CI == 75 && l8 < 2)
            *reinterpret_cast<uint4*>(&s_a[row * STRH + 64 + l8 * 8]) =
                *reinterpret_cast<const uint4*>(xr + 64 + l8 * 8);
    }

    // ---- stage rel (neighbor sums) or zero for d=0 ----
    if (d > 0) {
        if (row < nA) {
            const int* __restrict__ adp = adj.p[d - 1];
            if constexpr (CI == 64) {
                switch (d) {
                case 1: stage_rel64_m<1, STRH, GH>(xin, adp, j0, row, l8, s_a); break;
                case 2: stage_rel64_m<2, STRH, GH>(xin, adp, j0, row, l8, s_a); break;
                case 3: stage_rel64_m<3, STRH, GH>(xin, adp, j0, row, l8, s_a); break;
                case 4: stage_rel64_m<4, STRH, GH>(xin, adp, j0, row, l8, s_a); break;
                default: stage_rel64_rt_m<STRH, GH>(xin, adp, d, j0, row, l8, s_a); break;
                }
            } else {
                switch (d) {
                case 1: stage_rel75_m<1, STRH, GH>(xin, adp, j0, row, l8, s_a); break;
                case 2: stage_rel75_m<2, STRH, GH>(xin, adp, j0, row, l8, s_a); break;
                case 3: stage_rel75_m<3, STRH, GH>(xin, adp, j0, row, l8, s_a); break;
                case 4: stage_rel75_m<4, STRH, GH>(xin, adp, j0, row, l8, s_a); break;
                default: stage_rel75_rt_m<STRH, GH>(xin, adp, d, j0, row, l8, s_a); break;
                }
            }
        }
    } else {
        const uint4 z4 = make_uint4(0u, 0u, 0u, 0u);
        *reinterpret_cast<uint4*>(&s_a[row * STRH + (GH + l8) * 8]) = z4;
        if (CI == 75 && l8 < 2)
            *reinterpret_cast<uint4*>(&s_a[row * STRH + (GH + 8 + l8) * 8]) = z4;
    }
    __syncthreads();

    // ---- MFMA: wave w -> subtiles 2w, 2w+1 of the 4x4 16x16 grid ----
    const int lane = t & 63, w = t >> 6;
    const int lr = lane & 15, lg = lane >> 4;

    #pragma unroll
    for (int sb = 0; sb < 2; ++sb) {
        const int s = 2 * w + sb;
        const int mi = s >> 2, ni = s & 3;
        f4 acc = {0.f, 0.f, 0.f, 0.f};
        #pragma unroll
        for (int ks = 0; ks < KS; ++ks) {
            const h8 av = *reinterpret_cast<const h8*>(
                &s_a[(mi * 16 + lr) * STRH + (ks * 4 + lg) * 8]);
            uint4 braw = bp[((d * 4 + ni) * KS + ks) * 64 + lane];
            const h8 bv = *reinterpret_cast<const h8*>(&braw);
            acc = __builtin_amdgcn_mfma_f32_16x16x32_f16(av, bv, acc, 0, 0, 0);
        }
        const int ch = ni * 16 + lr;
        const float bias = (d == 0) ? B[20 * 64 + ch]
                                    : (B[(2 * (d - 1)) * 64 + ch] + B[(2 * d - 1) * 64 + ch]);
        const float scl = rsqrtf(bnv[ch] + 1e-3f) * bng[ch];
        const float sht = bnb[ch] - bnm[ch] * scl;
        #pragma unroll
        for (int r = 0; r < 4; ++r) {
            const int atom = mi * 16 + lg * 4 + r;
            if (atom < nA)
                out[(size_t)(a0 + atom) * 64 + ch] =
                    __float2half(fmaf(fmaxf(acc[r] + bias, 0.f), scl, sht));
        }
    }
}

// ---------------------------------------------------------------------------
// Merged pool layer (fp16), conv-style gather: 8 lanes/atom, ONE float4
// per lane per row; 32 atoms per block; packed fp16 stores.
// ---------------------------------------------------------------------------
template<int D>
__device__ __forceinline__ void pool_rows(const __half* __restrict__ z,
                                          const int* __restrict__ ad, int j, int g8,
                                          float2 mx[4])
{
    int idxs[D];
    #pragma unroll
    for (int n = 0; n < D; ++n) idxs[n] = ad[(size_t)j * D + n];
    for (int n = 0; n < D; ++n) {
        const float4 f4v = *reinterpret_cast<const float4*>(z + (size_t)idxs[n] * 64 + g8 * 8);
        const __half2* hh = reinterpret_cast<const __half2*>(&f4v);
        #pragma unroll
        for (int q = 0; q < 4; ++q) {
            const float2 v = __half22float2(hh[q]);
            mx[q].x = fmaxf(mx[q].x, v.x);
            mx[q].y = fmaxf(mx[q].y, v.y);
        }
    }
}

__device__ __forceinline__ void pool_rows_rt(const __half* __restrict__ z,
                                             const int* __restrict__ ad, int d, int j, int g8,
                                             float2 mx[4])
{
    int idxs[10];
    for (int n = 0; n < d; ++n) idxs[n] = ad[(size_t)j * d + n];
    for (int n = 0; n < d; ++n) {
        const float4 f4v = *reinterpret_cast<const float4*>(z + (size_t)idxs[n] * 64 + g8 * 8);
        const __half2* hh = reinterpret_cast<const __half2*>(&f4v);
        #pragma unroll
        for (int q = 0; q < 4; ++q) {
            const float2 v = __half22float2(hh[q]);
            mx[q].x = fmaxf(mx[q].x, v.x);
            mx[q].y = fmaxf(mx[q].y, v.y);
        }
    }
}

__global__ __launch_bounds__(256) void pool_all_kernel(
    const __half* __restrict__ z, AdjPtrs adj, __half* __restrict__ p)
{
    int d = 0, rem = blockIdx.x;
    for (;;) { const int nb = (kCounts[d] + 31) >> 5; if (rem < nb) break; rem -= nb; ++d; }
    const int t = threadIdx.x;
    const int j = rem * 32 + (t >> 3);
    if (j >= kCounts[d]) return;
    const int g8 = t & 7;
    const int a = kStarts[d] + j;

    const float4 s4 = *reinterpret_cast<const float4*>(z + (size_t)a * 64 + g8 * 8);
    const __half2* sh2 = reinterpret_cast<const __half2*>(&s4);
    float2 mx[4];
    #pragma unroll
    for (int q = 0; q < 4; ++q) mx[q] = __half22float2(sh2[q]);

    if (d > 0) {
        const int* __restrict__ ad = adj.p[d - 1];
        switch (d) {
        case 1:  pool_rows<1 >(z, ad, j, g8, mx); break;
        case 2:  pool_rows<2 >(z, ad, j, g8, mx); break;
        case 3:  pool_rows<3 >(z, ad, j, g8, mx); break;
        case 4:  pool_rows<4 >(z, ad, j, g8, mx); break;
        default: pool_rows_rt(z, ad, d, j, g8, mx); break;
        }
    }

    union { __half2 h[4]; float4 f; } u;
    #pragma unroll
    for (int q = 0; q < 4; ++q) u.h[q] = __floats2half2_rn(mx[q].x, mx[q].y);
    *reinterpret_cast<float4*>(p + (size_t)a * 64 + g8 * 8) = u.f;
}

// ---------------------------------------------------------------------------
// Counting sort by membership: hist -> scan -> scatter (+ per-position seg id).
// ---------------------------------------------------------------------------
__global__ __launch_bounds__(256) void hist_kernel(const int* __restrict__ mem,
                                                   int* __restrict__ cnt)
{
    const int a = blockIdx.x * 256 + threadIdx.x;
    if (a < NATOMS) atomicAdd(&cnt[mem[a]], 1);
}

__global__ __launch_bounds__(512) void scan_kernel(const int* __restrict__ cnt,
                                                   int* __restrict__ off,
                                                   int* __restrict__ cur)
{
    __shared__ int part[512];
    const int t = threadIdx.x;
    const int base = t * 64;
    int s = 0;
    #pragma unroll 8
    for (int i = 0; i < 64; ++i) s += cnt[base + i];
    part[t] = s;
    __syncthreads();
    for (int o = 1; o < 512; o <<= 1) {
        int v = (t >= o) ? part[t - o] : 0;
        __syncthreads();
        part[t] += v;
        __syncthreads();
    }
    int run = (t == 0) ? 0 : part[t - 1];
    for (int i = 0; i < 64; ++i) {
        off[base + i] = run;
        cur[base + i] = run;
        run += cnt[base + i];
    }
}

__global__ __launch_bounds__(256) void scatter_kernel(const int* __restrict__ mem,
                                                      int* __restrict__ cur,
                                                      int* __restrict__ sorted,
                                                      int* __restrict__ sid)
{
    const int a = blockIdx.x * 256 + threadIdx.x;
    if (a < NATOMS) {
        const int m = mem[a];
        const int pos = atomicAdd(&cur[m], 1);
        sorted[pos] = a;
        sid[pos] = m;
    }
}

__global__ void seg_init_kernel(float* __restrict__ segS, unsigned* __restrict__ segM)
{
    const int n = NBATCH * 128;
    for (int i = blockIdx.x * blockDim.x + threadIdx.x; i < n; i += gridDim.x * blockDim.x) {
        segS[i] = 0.f;
        segM[i] = 0x007FFFFFu; // enc(-inf)
    }
}

// ---------------------------------------------------------------------------
// Dense 64->128 + ReLU + BN2 over SORTED atoms, MFMA (r20-proven).
// ---------------------------------------------------------------------------
__global__ __launch_bounds__(256) void dense_seg_sorted_kernel(
    const __half* __restrict__ p,
    const int* __restrict__ sorted, const int* __restrict__ sid,
    const uint4* __restrict__ bpd, const float* __restrict__ bd,
    const float* __restrict__ bng, const float* __restrict__ bnb,
    const float* __restrict__ bnm, const float* __restrict__ bnv,
    float* __restrict__ segS, unsigned* __restrict__ segM)
{
    __shared__ __align__(16) __half s_a[64 * 72];     // 9.2KB A-tile
    __shared__ __align__(16) float vbuf[64 * 64];     // 16KB half-channel buffer
    __shared__ int s_idx[64];
    __shared__ int s_sid[64];

    const int t = threadIdx.x;
    const int pos0 = blockIdx.x * 64;   // NATOMS = 15625 * 64 exactly

    if (t < 64) {
        s_idx[t] = sorted[pos0 + t];
        s_sid[t] = sid[pos0 + t];
    }
    __syncthreads();

    {
        const int row = t >> 3, l8 = t & 7;   // rows 0..31
        #pragma unroll
        for (int half = 0; half < 2; ++half) {
            const int rr = row + half * 32;
            *reinterpret_cast<uint4*>(&s_a[rr * 72 + l8 * 8]) =
                *reinterpret_cast<const uint4*>(p + (size_t)s_idx[rr] * 64 + l8 * 8);
        }
    }
    __syncthreads();

    const int lane = t & 63, w = t >> 6;
    const int lr = lane & 15, lg = lane >> 4;

    h8 av[2];
    #pragma unroll
    for (int ks = 0; ks < 2; ++ks)
        av[ks] = *reinterpret_cast<const h8*>(&s_a[(w * 16 + lr) * 72 + (ks * 4 + lg) * 8]);

    f4 acc[8];
    #pragma unroll
    for (int ni = 0; ni < 8; ++ni) {
        acc[ni] = f4{0.f, 0.f, 0.f, 0.f};
        #pragma unroll
        for (int ks = 0; ks < 2; ++ks) {
            uint4 braw = bpd[(ni * 2 + ks) * 64 + lane];
            const h8 bv = *reinterpret_cast<const h8*>(&braw);
            acc[ni] = __builtin_amdgcn_mfma_f32_16x16x32_f16(av[ks], bv, acc[ni], 0, 0, 0);
        }
    }

    #pragma unroll
    for (int half = 0; half < 2; ++half) {
        #pragma unroll
        for (int q = 0; q < 4; ++q) {
            const int ni = half * 4 + q;
            const int ch = ni * 16 + lr;
            const float bias = bd[ch];
            const float scl = rsqrtf(bnv[ch] + 1e-3f) * bng[ch];
            const float sht = bnb[ch] - bnm[ch] * scl;
            #pragma unroll
            for (int r = 0; r < 4; ++r) {
                const int atom = w * 16 + lg * 4 + r;
                vbuf[atom * 64 + (ch & 63)] =
                    fmaf(fmaxf(acc[ni][r] + bias, 0.f), scl, sht);
            }
        }
        __syncthreads();

        const int c = t & 63;
        const int rbase = (t >> 6) * 16;
        const int gch = half * 64 + c;
        int cur = s_sid[rbase];
        float s = 0.f, mx = -INFINITY;
        for (int r = rbase; r < rbase + 16; ++r) {
            const int sd = s_sid[r];
            if (sd != cur) {
                atomicAdd(&segS[(size_t)cur * 128 + gch], s);
                atomicMax(&segM[(size_t)cur * 128 + gch], enc_f32(mx));
                cur = sd; s = 0.f; mx = -INFINITY;
            }
            const float v = vbuf[r * 64 + c];
            s += v;
            mx = fmaxf(mx, v);
        }
        atomicAdd(&segS[(size_t)cur * 128 + gch], s);
        atomicMax(&segM[(size_t)cur * 128 + gch], enc_f32(mx));
        __syncthreads();
    }
}

// ---------------------------------------------------------------------------
// fd0 + nf fusion, MFMA: one block per 64 segments. Staging computes
// nf = tanh(concat(segS, dec(segM))) in fp32 (written exact to d_out),
// packs fp16 into A-tile [64][264]; 4 waves x 16 col-subtiles x 8 k-steps
// of mfma_f32_16x16x32_f16 vs pre-packed fd0_W fragments; h = relu(.+b).
// Replaces the fp32 VALU fd0 (~4x inst overhead/FMA) + nf_fin round-trip.
// ---------------------------------------------------------------------------
__global__ __launch_bounds__(256) void fd0_mfma_kernel(
    const float* __restrict__ segS, const unsigned* __restrict__ segM,
    const uint4* __restrict__ bpf, const float* __restrict__ fb,
    float* __restrict__ nf, float* __restrict__ h)
{
    __shared__ __align__(16) __half s_a[64 * 264];    // 33.8KB A-tile
    const int t = threadIdx.x;
    const int m0 = blockIdx.x * 64;
    const int lane = t & 63, w = t >> 6;

    // staging: lane owns 4 cols (c4 = lane*4), wave w owns rows w*16..+15
    {
        const int c4 = lane * 4;
        #pragma unroll
        for (int r = 0; r < 16; ++r) {
            const int row = w * 16 + r;
            const int m = m0 + row;
            float v[4];
            if (c4 < 128) {
                const float4 sv = *reinterpret_cast<const float4*>(&segS[(size_t)m * 128 + c4]);
                v[0] = tanhf(sv.x); v[1] = tanhf(sv.y); v[2] = tanhf(sv.z); v[3] = tanhf(sv.w);
            } else {
                const uint4 mv = *reinterpret_cast<const uint4*>(&segM[(size_t)m * 128 + c4 - 128]);
                v[0] = tanhf(dec_f32(mv.x)); v[1] = tanhf(dec_f32(mv.y));
                v[2] = tanhf(dec_f32(mv.z)); v[3] = tanhf(dec_f32(mv.w));
            }
            *reinterpret_cast<float4*>(&nf[(size_t)m * 256 + c4]) =
                make_float4(v[0], v[1], v[2], v[3]);
            __half hv[4];
            #pragma unroll
            for (int j = 0; j < 4; ++j) hv[j] = __float2half(v[j]);
            *reinterpret_cast<uint2*>(&s_a[row * 264 + c4]) =
                *reinterpret_cast<const uint2*>(hv);
        }
    }
    __syncthreads();

    const int lr = lane & 15, lg = lane >> 4;

    h8 av[8];
    #pragma unroll
    for (int ks = 0; ks < 8; ++ks)
        av[ks] = *reinterpret_cast<const h8*>(&s_a[(w * 16 + lr) * 264 + (ks * 4 + lg) * 8]);

    #pragma unroll
    for (int ni = 0; ni < 16; ++ni) {
        f4 acc = {0.f, 0.f, 0.f, 0.f};
        #pragma unroll
        for (int ks = 0; ks < 8; ++ks) {
            uint4 braw = bpf[(ni * 8 + ks) * 64 + lane];
            const h8 bv = *reinterpret_cast<const h8*>(&braw);
            acc = __builtin_amdgcn_mfma_f32_16x16x32_f16(av[ks], bv, acc, 0, 0, 0);
        }
        const int ch = ni * 16 + lr;
        const float bb = fb[ch];
        #pragma unroll
        for (int r = 0; r < 4; ++r) {
            const int row = w * 16 + lg * 4 + r;
            h[(size_t)(m0 + row) * 256 + ch] = fmaxf(acc[r] + bb, 0.f);
        }
    }
}

// rd: logits = h @ W + b (256->24), then pairwise softmax.
__global__ __launch_bounds__(384) void rd_kernel(
    const float* __restrict__ h, const float* __restrict__ W, const float* __restrict__ b,
    float* __restrict__ outP, float* __restrict__ outL)
{
    __shared__ float sh[32][257];
    const int t = threadIdx.x;
    const int r0 = blockIdx.x * 32;
    for (int e = t; e < 32 * 256; e += 384) {
        const int ri = e >> 8, k = e & 255;
        sh[ri][k] = h[(size_t)(r0 + ri) * 256 + k];
    }
    __syncthreads();
    const int r = t / 12, pj = t % 12;
    float a0 = b[2 * pj], a1 = b[2 * pj + 1];
    for (int k = 0; k < 256; ++k) {
        const float hv = sh[r][k];
        a0 = fmaf(hv, W[k * 24 + 2 * pj],     a0);
        a1 = fmaf(hv, W[k * 24 + 2 * pj + 1], a1);
    }
    const size_t m = (size_t)(r0 + r);
    outL[m * 24 + 2 * pj]     = a0;
    outL[m * 24 + 2 * pj + 1] = a1;
    const float mx = fmaxf(a0, a1);
    const float e0 = expf(a0 - mx), e1 = expf(a1 - mx);
    const float inv = 1.f / (e0 + e1);
    outP[m * 24 + 2 * pj]     = e0 * inv;
    outP[m * 24 + 2 * pj + 1] = e1 * inv;
}

} // namespace

extern "C" void kernel_launch(void* const* d_in, const int* in_sizes, int n_in,
                              void* d_out, int out_size, void* d_ws, size_t ws_size,
                              hipStream_t stream)
{
    const float* x       = (const float*)d_in[0];
    const int*   mem     = (const int*)d_in[2];
    AdjPtrs adj;
    for (int d = 0; d < 10; ++d) adj.p[d] = (const int*)d_in[4 + d];
    const float* gc0_W = (const float*)d_in[14];
    const float* gc0_b = (const float*)d_in[15];
    const float* gc1_W = (const float*)d_in[16];
    const float* gc1_b = (const float*)d_in[17];
    const float* bn0g = (const float*)d_in[18], *bn0b = (const float*)d_in[19];
    const float* bn0m = (const float*)d_in[20], *bn0v = (const float*)d_in[21];
    const float* bn1g = (const float*)d_in[22], *bn1b = (const float*)d_in[23];
    const float* bn1m = (const float*)d_in[24], *bn1v = (const float*)d_in[25];
    const float* bn2g = (const float*)d_in[26], *bn2b = (const float*)d_in[27];
    const float* bn2m = (const float*)d_in[28], *bn2v = (const float*)d_in[29];
    const float* dW   = (const float*)d_in[30], *db   = (const float*)d_in[31];
    const float* fW   = (const float*)d_in[32], *fb   = (const float*)d_in[33];
    const float* rW   = (const float*)d_in[34], *rb   = (const float*)d_in[35];

    __half* z16 = (__half*)d_ws;                               // 1M x 64
    __half* p16 = z16 + (size_t)NATOMS * 64;                   // 1M x 64
    __half* x16 = p16 + (size_t)NATOMS * 64;                   // 1M x 80
    float*  hbuf = (float*)(x16 + (size_t)NATOMS * X16S);
    float*  segS = hbuf + (size_t)NBATCH * 256;
    unsigned* segM = (unsigned*)(segS + (size_t)NBATCH * 128);
    int*    cnt    = (int*)(segM + (size_t)NBATCH * 128);
    int*    offp   = cnt + NBATCH;
    int*    cur    = offp + NBATCH;
    int*    sorted = cur + NBATCH;
    int*    sid    = sorted + NATOMS;
    uint4*  bp0    = (uint4*)(sid + NATOMS);                   // 11*4*5*64 uint4
    uint4*  bp1    = bp0 + 11 * 4 * 5 * 64;                    // 11*4*4*64 uint4
    uint4*  bpd    = bp1 + 11 * 4 * 4 * 64;                    // 8*2*64 uint4
    uint4*  bpf    = bpd + 8 * 2 * 64;                         // 16*8*64 uint4

    float* outP = (float*)d_out;
    float* outL = outP + (size_t)NBATCH * 24;
    float* nfb  = outL + (size_t)NBATCH * 24;

    int convBlocks = 0, poolBlocks = 0;
    for (int d = 0; d <= 10; ++d) {
        convBlocks += (kCounts[d] + 63) >> 6;
        poolBlocks += (kCounts[d] + 31) >> 5;
    }

    // one-time conversions: x -> fp16 padded; weights -> MFMA B-fragments
    cvt_kernel<<<(NATOMS + 15) / 16, 256, 0, stream>>>(x, x16);
    packB_kernel<<<55, 256, 0, stream>>>(gc0_W, bp0, 75, 10, 5);
    packB_kernel<<<44, 256, 0, stream>>>(gc1_W, bp1, 64, 8, 4);
    packBd_kernel<<<4, 256, 0, stream>>>(dW, bpd);
    packBf_kernel<<<32, 256, 0, stream>>>(fW, bpf);

    // counting sort by membership + segment accumulator init
    hipMemsetAsync(cnt, 0, NBATCH * sizeof(int), stream);
    hist_kernel<<<(NATOMS + 255) / 256, 256, 0, stream>>>(mem, cnt);
    scan_kernel<<<1, 512, 0, stream>>>(cnt, offp, cur);
    scatter_kernel<<<(NATOMS + 255) / 256, 256, 0, stream>>>(mem, cur, sorted, sid);
    seg_init_kernel<<<2048, 256, 0, stream>>>(segS, segM);

    // layer 1: conv(75->64)+relu+bn0 -> pool
    conv_all_kernel<75><<<convBlocks, 512, 0, stream>>>(x16, adj, bp0, gc0_b,
                                                        bn0g, bn0b, bn0m, bn0v, z16);
    pool_all_kernel<<<poolBlocks, 256, 0, stream>>>(z16, adj, p16);

    // layer 2: conv(64->64)+relu+bn1 -> pool
    conv_all_kernel<64><<<convBlocks, 512, 0, stream>>>(p16, adj, bp1, gc1_b,
                                                        bn1g, bn1b, bn1m, bn1v, z16);
    pool_all_kernel<<<poolBlocks, 256, 0, stream>>>(z16, adj, p16);

    // dense+relu+bn2 over sorted atoms with fused segmented sum/max (MFMA)
    dense_seg_sorted_kernel<<<NATOMS / 64, 256, 0, stream>>>(
        p16, sorted, sid, bpd, db, bn2g, bn2b, bn2m, bn2v, segS, segM);
    // fused nf = tanh(concat(sum,max)) + h = relu(nf @ fd0_W + fd0_b) (MFMA)
    fd0_mfma_kernel<<<NBATCH / 64, 256, 0, stream>>>(segS, segM, bpf, fb, nfb, hbuf);
    // logits + softmax
    rd_kernel<<<NBATCH / 32, 384, 0, stream>>>(hbuf, rW, rb, outP, outL);
}